// Round 2
// baseline (4535.384 us; speedup 1.0000x reference)
//
#include <hip/hip_runtime.h>
#include <stdint.h>

#define DEV __device__ __forceinline__

typedef short bf16x8 __attribute__((ext_vector_type(8)));
typedef float f32x4 __attribute__((ext_vector_type(4)));

DEV unsigned short f2bf(float f) {
  union { float f; uint32_t u; } v; v.f = f;
  return (unsigned short)((v.u + 0x7fffu + ((v.u >> 16) & 1u)) >> 16);
}

DEV float fsig(float x) { return 1.f / (1.f + __expf(-x)); }
DEV float ftanh(float x) { float e = __expf(2.f * x); return 1.f - 2.f / (e + 1.f); }

DEV void gload16(const void* g, void* lds) {
  __builtin_amdgcn_global_load_lds(
      (const __attribute__((address_space(1))) int*)(uintptr_t)g,
      (__attribute__((address_space(3))) int*)(uintptr_t)lds, 16, 0, 0);
}

// ================= generic NT GEMM: C[M,N] = A[M,K] * B[N,K]^T + bias =================
// 128x128 tile, BK=32, 4 waves each 64x64. MODE: 0=f32 C, 1=bf16 C (+C2), 2=xpr layout,
// 3=init (4 col-segments -> h1 bf16, c1 f32, h2 bf16, c2 f32).
template <int MODE>
__global__ __launch_bounds__(256) void gemm_nt(
    const unsigned short* __restrict__ A, int lda,
    const unsigned short* __restrict__ B, int ldb,
    void* __restrict__ P0, void* __restrict__ P1,
    void* __restrict__ P2, void* __restrict__ P3,
    int ldc, int ldc2,
    const float* __restrict__ bias,
    int K, int Nreal)
{
  __shared__ alignas(16) unsigned short Asm[128 * 32];
  __shared__ alignas(16) unsigned short Bsm[128 * 32];
  const int tid = threadIdx.x;
  const int wave = tid >> 6, lane = tid & 63;

  // bijective XCD swizzle on linear block id (m204 variant)
  const int gx = gridDim.x;
  const int lin = blockIdx.y * gx + blockIdx.x;
  const int nwg = gx * gridDim.y;
  const int q = nwg >> 3, r = nwg & 7;
  const int xcd = lin & 7, i2 = lin >> 3;
  const int wg = (xcd < r ? xcd * (q + 1) : r * (q + 1) + (xcd - r) * q) + i2;
  const int m0 = (wg % gx) * 128, n0 = (wg / gx) * 128;

  const int wr = wave >> 1, wc = wave & 1;
  f32x4 acc[4][4] = {};

  const int q0 = tid, q1 = tid + 256;
  const unsigned short* Ag0 = A + (size_t)(m0 + (q0 >> 2)) * lda + (q0 & 3) * 8;
  const unsigned short* Ag1 = A + (size_t)(m0 + (q1 >> 2)) * lda + (q1 & 3) * 8;
  const unsigned short* Bg0 = B + (size_t)(n0 + (q0 >> 2)) * ldb + (q0 & 3) * 8;
  const unsigned short* Bg1 = B + (size_t)(n0 + (q1 >> 2)) * ldb + (q1 & 3) * 8;
  char* As0 = (char*)Asm + wave * 1024;  char* As1 = As0 + 4096;
  char* Bs0 = (char*)Bsm + wave * 1024;  char* Bs1 = Bs0 + 4096;

  const int ra = wr * 64 + (lane & 15);
  const int rb = wc * 64 + (lane & 15);
  const int kb = (lane >> 4) * 16;

  for (int k0 = 0; k0 < K; k0 += 32) {
    gload16(Ag0 + k0, As0);
    gload16(Ag1 + k0, As1);
    gload16(Bg0 + k0, Bs0);
    gload16(Bg1 + k0, Bs1);
    __syncthreads();
    bf16x8 af[4], bfr[4];
#pragma unroll
    for (int i = 0; i < 4; ++i)
      af[i] = *(const bf16x8*)((const char*)Asm + (ra + i * 16) * 64 + kb);
#pragma unroll
    for (int i = 0; i < 4; ++i)
      bfr[i] = *(const bf16x8*)((const char*)Bsm + (rb + i * 16) * 64 + kb);
#pragma unroll
    for (int mi = 0; mi < 4; ++mi)
#pragma unroll
      for (int ni = 0; ni < 4; ++ni)
        acc[mi][ni] = __builtin_amdgcn_mfma_f32_16x16x32_bf16(af[mi], bfr[ni], acc[mi][ni], 0, 0, 0);
    __syncthreads();
  }

  const int row0 = m0 + wr * 64 + (lane >> 4) * 4;
  const int col0 = n0 + wc * 64 + (lane & 15);
#pragma unroll
  for (int mi = 0; mi < 4; ++mi) {
#pragma unroll
    for (int ni = 0; ni < 4; ++ni) {
      const int col = col0 + ni * 16;
      if (col >= Nreal) continue;
      const float bs = bias ? bias[col] : 0.f;
#pragma unroll
      for (int rr = 0; rr < 4; ++rr) {
        const int row = row0 + mi * 16 + rr;
        const float v = acc[mi][ni][rr] + bs;
        if constexpr (MODE == 0) {
          ((float*)P0)[(size_t)row * ldc + col] = v;
        } else if constexpr (MODE == 1) {
          ((unsigned short*)P0)[(size_t)row * ldc + col] = f2bf(v);
          if (P1) ((unsigned short*)P1)[(size_t)row * ldc2 + col] = f2bf(v);
        } else if constexpr (MODE == 2) {
          // xpr layout for lstm_persist: thread-vectorized gate quads
          const int t = row & 63, b = row >> 6;
          const int g = col >> 9, d = col & 511;
          const int jj = d >> 5, ww = (d >> 3) & 3, kq2 = d & 3, mi2 = (d >> 2) & 1;
          const int tidp = ww * 64 + kq2 * 16 + (b & 15);
          const int pp = mi2 * 8 + (b >> 4);
          ((float*)P0)[((((size_t)t * 16 + jj) * 256 + tidp) * 16 + pp) * 4 + g] = v;
        } else {  // MODE 3: init states
          const int seg = col >> 9, cc = col & 511;
          if (seg == 0)      ((unsigned short*)P0)[(size_t)row * 512 + cc] = f2bf(v);
          else if (seg == 1) ((float*)P1)[(size_t)row * 512 + cc] = v;
          else if (seg == 2) ((unsigned short*)P2)[(size_t)row * 512 + cc] = f2bf(v);
          else               ((float*)P3)[(size_t)row * 512 + cc] = v;
        }
      }
    }
  }
}

// ================= persistent LSTM: all 64 timesteps in one launch =================
// 16 WGs, WG j owns d in [j*32,(j+1)*32). Computes G[m,b] = W'[m,:]·h[b,:], m in [0,128)
// with m -> (gate = m&3, d = j*32 + (m>>2)), so acc[mi][nj] (f32x4) = (i,f,g,o) for one
// (b,d). W' slice resident in LDS (XOR-swizzled, conflict-free). c state in registers.
// Grid sync between steps via agent-scope release/acquire atomics on `flag`.
__global__ __launch_bounds__(256) void lstm_persist(
    const unsigned short* __restrict__ Whh,   // [2048,512] bf16
    const unsigned short* __restrict__ h0,    // [128,512] bf16
    const float* __restrict__ c0,             // [128,512] f32
    const float* __restrict__ xpr,            // [64][16][256][16][4] f32
    unsigned short* __restrict__ hout,        // h output base
    int ldho, int tstride,                    // element strides: per-b, per-t
    int* __restrict__ flag)
{
  __shared__ unsigned short Wsm[8][128][64];  // [k-block][m][128B swizzled row]
  const int tid = threadIdx.x, j = blockIdx.x;
  const int w = tid >> 6, lane = tid & 63, fr = lane & 15, kq = lane >> 4;

  // --- one-time W staging: reg -> LDS, slot s = c ^ (m&7) within 128B rows ---
  {
    const int m = tid >> 1;
    const int Wrow = (m & 3) * 512 + j * 32 + (m >> 2);
    const unsigned short* src = Whh + (size_t)Wrow * 512 + (tid & 1) * 256;
#pragma unroll 4
    for (int cc = 0; cc < 32; ++cc) {
      const int k = (tid & 1) * 256 + cc * 8;
      uint4 v = *(const uint4*)(src + cc * 8);
      const int kblk = k >> 6, c = (k & 63) >> 3, s = c ^ (m & 7);
      *(uint4*)((char*)&Wsm[kblk][m][0] + s * 16) = v;
    }
  }
  // --- c0 into registers (thread owns same (b,d) set every step) ---
  float creg[2][8];
#pragma unroll
  for (int mi = 0; mi < 2; ++mi)
#pragma unroll
    for (int nj = 0; nj < 8; ++nj) {
      const int b = nj * 16 + fr, d = j * 32 + w * 8 + mi * 4 + kq;
      creg[mi][nj] = c0[b * 512 + d];
    }
  __syncthreads();

  for (int t = 0; t < 64; ++t) {
    const unsigned short* hb = t ? hout + (size_t)(t - 1) * tstride : h0;
    const int ldh = t ? ldho : 512;
    const unsigned short* hrow[8];
#pragma unroll
    for (int nj = 0; nj < 8; ++nj)
      hrow[nj] = hb + (size_t)(nj * 16 + fr) * ldh + kq * 8;

    f32x4 acc[2][8] = {};
#pragma unroll 2
    for (int kk = 0; kk < 16; ++kk) {
      const int k0 = kk * 32;
      bf16x8 bf[8];
#pragma unroll
      for (int nj = 0; nj < 8; ++nj)
        bf[nj] = *(const bf16x8*)(hrow[nj] + k0);
      bf16x8 af[2];
      const int kblk = k0 >> 6, cbase = ((k0 & 32) >> 3) + kq;
#pragma unroll
      for (int mi = 0; mi < 2; ++mi) {
        const int m = w * 32 + mi * 16 + fr;
        const int s = cbase ^ (m & 7);
        af[mi] = *(const bf16x8*)((const char*)&Wsm[kblk][m][0] + s * 16);
      }
#pragma unroll
      for (int mi = 0; mi < 2; ++mi)
#pragma unroll
        for (int nj = 0; nj < 8; ++nj)
          acc[mi][nj] = __builtin_amdgcn_mfma_f32_16x16x32_bf16(af[mi], bf[nj], acc[mi][nj], 0, 0, 0);
    }

    // epilogue: gates fully lane-local
    const float4* xv = (const float4*)(xpr + (((size_t)t * 16 + j) * 256 + tid) * 64);
    unsigned short* ho = hout + (size_t)t * tstride;
#pragma unroll
    for (int mi = 0; mi < 2; ++mi)
#pragma unroll
      for (int nj = 0; nj < 8; ++nj) {
        const float4 xg = xv[mi * 8 + nj];
        const float iv = acc[mi][nj][0] + xg.x;
        const float fv = acc[mi][nj][1] + xg.y;
        const float gv = acc[mi][nj][2] + xg.z;
        const float ov = acc[mi][nj][3] + xg.w;
        float c = fsig(fv) * creg[mi][nj] + fsig(iv) * ftanh(gv);
        creg[mi][nj] = c;
        const float hn = fsig(ov) * ftanh(c);
        const int b = nj * 16 + fr, d = j * 32 + w * 8 + mi * 4 + kq;
        ho[(size_t)b * ldho + d] = f2bf(hn);
      }

    // grid sync: release own XCD's writes, acquire others'
    __syncthreads();
    if (tid == 0) {
      __hip_atomic_fetch_add(flag, 1, __ATOMIC_ACQ_REL, __HIP_MEMORY_SCOPE_AGENT);
      const int target = 16 * (t + 1);
      while (__hip_atomic_load(flag, __ATOMIC_ACQUIRE, __HIP_MEMORY_SCOPE_AGENT) < target)
        __builtin_amdgcn_s_sleep(1);
    }
    __syncthreads();
  }
}

// ================= small helpers =================
struct CastJobs {
  const float* src[15];
  unsigned short* dst[15];
  long nreal[15];
  long cum[16];
  int n;
};

__global__ void cast_multi(CastJobs J) {
  const long total = J.cum[J.n];
  for (long i = (long)blockIdx.x * blockDim.x + threadIdx.x; i < total;
       i += (long)gridDim.x * blockDim.x) {
    int s = 0;
    while (i >= J.cum[s + 1]) ++s;
    const long off = i - J.cum[s];
    J.dst[s][off] = (off < J.nreal[s]) ? f2bf(J.src[s][off]) : (unsigned short)0;
  }
}

__global__ void concat_bias(const float* a, const float* b, const float* c, const float* d,
                            float* o) {
  const int i = blockIdx.x * blockDim.x + threadIdx.x;  // 2048
  const float* s[4] = {a, b, c, d};
  o[i] = s[i >> 9][i & 511];
}

__global__ void gather_rows(const int* __restrict__ ix, const unsigned short* __restrict__ emb,
                            unsigned short* __restrict__ x) {
  const int row = blockIdx.x;
  const int e = ix[row];
  const uint4* s = (const uint4*)(emb + (size_t)e * 512);
  uint4* d = (uint4*)(x + (size_t)row * 512);
  d[threadIdx.x] = s[threadIdx.x];
}

// ================= host =================
extern "C" void kernel_launch(void* const* d_in, const int* in_sizes, int n_in,
                              void* d_out, int out_size, void* d_ws, size_t ws_size,
                              hipStream_t stream) {
  (void)in_sizes; (void)n_in; (void)out_size; (void)ws_size;
  const float* img    = (const float*)d_in[0];
  const int*   ix     = (const int*)d_in[1];
  const float* emb    = (const float*)d_in[2];
  const float* Wih1f  = (const float*)d_in[3];
  const float* bih1   = (const float*)d_in[4];
  const float* Wic1f  = (const float*)d_in[5];
  const float* bic1   = (const float*)d_in[6];
  const float* Wih2f  = (const float*)d_in[7];
  const float* bih2   = (const float*)d_in[8];
  const float* Wic2f  = (const float*)d_in[9];
  const float* bic2   = (const float*)d_in[10];
  const float* Wihl1  = (const float*)d_in[11];
  const float* Whhl1  = (const float*)d_in[12];
  const float* b1     = (const float*)d_in[13];
  const float* Wihl2  = (const float*)d_in[14];
  const float* Whhl2  = (const float*)d_in[15];
  const float* b2     = (const float*)d_in[16];
  const float* Wv1    = (const float*)d_in[17];
  const float* bv1    = (const float*)d_in[18];
  const float* Wo1    = (const float*)d_in[19];
  const float* bo1    = (const float*)d_in[20];
  const float* Wv2    = (const float*)d_in[21];
  const float* bv2    = (const float*)d_in[22];
  const float* Wo2    = (const float*)d_in[23];
  const float* bo2    = (const float*)d_in[24];
  const float* Wlog   = (const float*)d_in[25];
  const float* blog   = (const float*)d_in[26];
  float* out = (float*)d_out;

  char* p = (char*)d_ws;
  auto al = [&](size_t bytes) { char* r = p; p += (bytes + 255) & ~(size_t)255; return r; };
  unsigned short* emb_b  = (unsigned short*)al((size_t)10000 * 512 * 2);
  unsigned short* Wih1_b = (unsigned short*)al((size_t)2048 * 512 * 2);
  unsigned short* Whh1_b = (unsigned short*)al((size_t)2048 * 512 * 2);
  unsigned short* Wih2_b = (unsigned short*)al((size_t)2048 * 1024 * 2);
  unsigned short* Whh2_b = (unsigned short*)al((size_t)2048 * 512 * 2);
  unsigned short* Wv1_b  = (unsigned short*)al((size_t)512 * 512 * 2);
  unsigned short* Wo1_b  = (unsigned short*)al((size_t)512 * 512 * 2);
  unsigned short* Wv2_b  = (unsigned short*)al((size_t)512 * 512 * 2);
  unsigned short* Wo2_b  = (unsigned short*)al((size_t)512 * 512 * 2);
  unsigned short* Wlog_b = (unsigned short*)al((size_t)10112 * 1536 * 2);
  unsigned short* Wh1i_b = (unsigned short*)al((size_t)512 * 2048 * 2);  // these four are
  unsigned short* Wc1i_b = (unsigned short*)al((size_t)512 * 2048 * 2);  // contiguous:
  unsigned short* Wh2i_b = (unsigned short*)al((size_t)512 * 2048 * 2);  // [2048,2048] concat
  unsigned short* Wc2i_b = (unsigned short*)al((size_t)512 * 2048 * 2);
  unsigned short* img_b  = (unsigned short*)al((size_t)128 * 2048 * 2);
  unsigned short* x_b    = (unsigned short*)al((size_t)8192 * 512 * 2);
  float*          xpr    = (float*)al((size_t)64 * 16 * 256 * 64 * 4);   // 67 MB
  unsigned short* cat1   = (unsigned short*)al((size_t)8192 * 1024 * 2); // [h1s | attn1]
  unsigned short* out3   = (unsigned short*)al((size_t)8192 * 1536 * 2); // [h2s | attn1 | attn2]
  unsigned short* vtmp   = (unsigned short*)al((size_t)8192 * 512 * 2);
  unsigned short* h01    = (unsigned short*)al((size_t)128 * 512 * 2);
  unsigned short* h02    = (unsigned short*)al((size_t)128 * 512 * 2);
  float*          c1st   = (float*)al((size_t)128 * 512 * 4);
  float*          c2st   = (float*)al((size_t)128 * 512 * 4);
  float*          bcat   = (float*)al((size_t)2048 * 4);
  int*            flags  = (int*)al(256);

  hipMemsetAsync(flags, 0, 256, stream);

  // ---- all f32->bf16 casts in one kernel ----
  CastJobs J = {};
  auto addjob = [&](const float* s, unsigned short* d, long nreal, long ntot) {
    J.src[J.n] = s; J.dst[J.n] = d; J.nreal[J.n] = nreal;
    J.cum[J.n + 1] = J.cum[J.n] + ntot; ++J.n;
  };
  addjob(img,   img_b,  (long)128 * 2048,   (long)128 * 2048);
  addjob(emb,   emb_b,  (long)10000 * 512,  (long)10000 * 512);
  addjob(Wihl1, Wih1_b, (long)2048 * 512,   (long)2048 * 512);
  addjob(Whhl1, Whh1_b, (long)2048 * 512,   (long)2048 * 512);
  addjob(Wihl2, Wih2_b, (long)2048 * 1024,  (long)2048 * 1024);
  addjob(Whhl2, Whh2_b, (long)2048 * 512,   (long)2048 * 512);
  addjob(Wv1,   Wv1_b,  (long)512 * 512,    (long)512 * 512);
  addjob(Wo1,   Wo1_b,  (long)512 * 512,    (long)512 * 512);
  addjob(Wv2,   Wv2_b,  (long)512 * 512,    (long)512 * 512);
  addjob(Wo2,   Wo2_b,  (long)512 * 512,    (long)512 * 512);
  addjob(Wih1f, Wh1i_b, (long)512 * 2048,   (long)512 * 2048);
  addjob(Wic1f, Wc1i_b, (long)512 * 2048,   (long)512 * 2048);
  addjob(Wih2f, Wh2i_b, (long)512 * 2048,   (long)512 * 2048);
  addjob(Wic2f, Wc2i_b, (long)512 * 2048,   (long)512 * 2048);
  addjob(Wlog,  Wlog_b, (long)10000 * 1536, (long)10112 * 1536);
  cast_multi<<<2048, 256, 0, stream>>>(J);

  concat_bias<<<8, 256, 0, stream>>>(bih1, bic1, bih2, bic2, bcat);

  // ---- fused init states: [h1 | c1 | h2 | c2] = img @ [W..]^T + bcat ----
  gemm_nt<3><<<dim3(1, 16), 256, 0, stream>>>(
      img_b, 2048, Wh1i_b, 2048, h01, c1st, h02, c2st, 0, 0, bcat, 2048, 2048);

  // ---- x = emb[captions_ix] ----
  gather_rows<<<8192, 64, 0, stream>>>(ix, emb_b, x_b);

  // ---- xp1 = x @ W_ih1^T + b1, written in xpr layout ----
  gemm_nt<2><<<dim3(64, 16), 256, 0, stream>>>(
      x_b, 512, Wih1_b, 512, xpr, nullptr, nullptr, nullptr, 0, 0, b1, 512, 2048);

  // ---- LSTM1 (persistent) -> h1s into cat1 cols [0,512) ----
  lstm_persist<<<16, 256, 0, stream>>>(Whh1_b, h01, c1st, xpr, cat1, 65536, 1024, flags);

  // ---- attn1 -> cat1 cols [512,1024) and out3 cols [512,1024) ----
  gemm_nt<1><<<dim3(64, 4), 256, 0, stream>>>(
      cat1, 1024, Wv1_b, 512, vtmp, nullptr, nullptr, nullptr, 512, 0, bv1, 512, 512);
  gemm_nt<1><<<dim3(64, 4), 256, 0, stream>>>(
      vtmp, 512, Wo1_b, 512, cat1 + 512, out3 + 512, nullptr, nullptr, 1024, 1536, bo1, 512, 512);

  // ---- xp2 = [h1s|attn1] @ W_ih2^T + b2, xpr layout ----
  gemm_nt<2><<<dim3(64, 16), 256, 0, stream>>>(
      cat1, 1024, Wih2_b, 1024, xpr, nullptr, nullptr, nullptr, 0, 0, b2, 1024, 2048);

  // ---- LSTM2 (persistent) -> h2s into out3 cols [0,512) ----
  lstm_persist<<<16, 256, 0, stream>>>(Whh2_b, h02, c2st, xpr, out3, 98304, 1536, flags + 16);

  // ---- attn2 -> out3 cols [1024,1536) ----
  gemm_nt<1><<<dim3(64, 4), 256, 0, stream>>>(
      out3, 1536, Wv2_b, 512, vtmp, nullptr, nullptr, nullptr, 512, 0, bv2, 512, 512);
  gemm_nt<1><<<dim3(64, 4), 256, 0, stream>>>(
      vtmp, 512, Wo2_b, 512, out3 + 1024, nullptr, nullptr, nullptr, 1536, 0, bo2, 512, 512);

  // ---- logits = out3 @ W_logits^T + b_logits ----
  gemm_nt<0><<<dim3(64, 79), 256, 0, stream>>>(
      out3, 1536, Wlog_b, 1536, out, nullptr, nullptr, nullptr, 10000, 0, blog, 1536, 10000);
}

// Round 3
// 1769.167 us; speedup vs baseline: 2.5636x; 2.5636x over previous
//
#include <hip/hip_runtime.h>
#include <stdint.h>

#define DEV __device__ __forceinline__

typedef short bf16x8 __attribute__((ext_vector_type(8)));
typedef float f32x4 __attribute__((ext_vector_type(4)));

DEV unsigned short f2bf(float f) {
  union { float f; uint32_t u; } v; v.f = f;
  return (unsigned short)((v.u + 0x7fffu + ((v.u >> 16) & 1u)) >> 16);
}

DEV float fsig(float x) { return 1.f / (1.f + __expf(-x)); }
DEV float ftanh(float x) { float e = __expf(2.f * x); return 1.f - 2.f / (e + 1.f); }

DEV void gload16(const void* g, void* lds) {
  __builtin_amdgcn_global_load_lds(
      (const __attribute__((address_space(1))) int*)(uintptr_t)g,
      (__attribute__((address_space(3))) int*)(uintptr_t)lds, 16, 0, 0);
}

// ================= generic NT GEMM: C[M,N] = A[M,K] * B[N,K]^T + bias =================
// 128x128 tile, BK=32, 4 waves each 64x64. MODE: 0=f32 C, 1=bf16 C (+C2), 2=xpr layout,
// 3=init (4 col-segments -> h1 bf16, c1 f32(custom), h2 bf16, c2 f32(custom)).
template <int MODE>
__global__ __launch_bounds__(256) void gemm_nt(
    const unsigned short* __restrict__ A, int lda,
    const unsigned short* __restrict__ B, int ldb,
    void* __restrict__ P0, void* __restrict__ P1,
    void* __restrict__ P2, void* __restrict__ P3,
    int ldc, int ldc2,
    const float* __restrict__ bias,
    int K, int Nreal)
{
  __shared__ alignas(16) unsigned short Asm[128 * 32];
  __shared__ alignas(16) unsigned short Bsm[128 * 32];
  const int tid = threadIdx.x;
  const int wave = tid >> 6, lane = tid & 63;

  // bijective XCD swizzle on linear block id (m204 variant)
  const int gx = gridDim.x;
  const int lin = blockIdx.y * gx + blockIdx.x;
  const int nwg = gx * gridDim.y;
  const int q = nwg >> 3, r = nwg & 7;
  const int xcd = lin & 7, i2 = lin >> 3;
  const int wg = (xcd < r ? xcd * (q + 1) : r * (q + 1) + (xcd - r) * q) + i2;
  const int m0 = (wg % gx) * 128, n0 = (wg / gx) * 128;

  const int wr = wave >> 1, wc = wave & 1;
  f32x4 acc[4][4] = {};

  const int q0 = tid, q1 = tid + 256;
  const unsigned short* Ag0 = A + (size_t)(m0 + (q0 >> 2)) * lda + (q0 & 3) * 8;
  const unsigned short* Ag1 = A + (size_t)(m0 + (q1 >> 2)) * lda + (q1 & 3) * 8;
  const unsigned short* Bg0 = B + (size_t)(n0 + (q0 >> 2)) * ldb + (q0 & 3) * 8;
  const unsigned short* Bg1 = B + (size_t)(n0 + (q1 >> 2)) * ldb + (q1 & 3) * 8;
  char* As0 = (char*)Asm + wave * 1024;  char* As1 = As0 + 4096;
  char* Bs0 = (char*)Bsm + wave * 1024;  char* Bs1 = Bs0 + 4096;

  const int ra = wr * 64 + (lane & 15);
  const int rb = wc * 64 + (lane & 15);
  const int kb = (lane >> 4) * 16;

  for (int k0 = 0; k0 < K; k0 += 32) {
    gload16(Ag0 + k0, As0);
    gload16(Ag1 + k0, As1);
    gload16(Bg0 + k0, Bs0);
    gload16(Bg1 + k0, Bs1);
    __syncthreads();
    bf16x8 af[4], bfr[4];
#pragma unroll
    for (int i = 0; i < 4; ++i)
      af[i] = *(const bf16x8*)((const char*)Asm + (ra + i * 16) * 64 + kb);
#pragma unroll
    for (int i = 0; i < 4; ++i)
      bfr[i] = *(const bf16x8*)((const char*)Bsm + (rb + i * 16) * 64 + kb);
#pragma unroll
    for (int mi = 0; mi < 4; ++mi)
#pragma unroll
      for (int ni = 0; ni < 4; ++ni)
        acc[mi][ni] = __builtin_amdgcn_mfma_f32_16x16x32_bf16(af[mi], bfr[ni], acc[mi][ni], 0, 0, 0);
    __syncthreads();
  }

  const int row0 = m0 + wr * 64 + (lane >> 4) * 4;
  const int col0 = n0 + wc * 64 + (lane & 15);
#pragma unroll
  for (int mi = 0; mi < 4; ++mi) {
#pragma unroll
    for (int ni = 0; ni < 4; ++ni) {
      const int col = col0 + ni * 16;
      if (col >= Nreal) continue;
      const float bs = bias ? bias[col] : 0.f;
#pragma unroll
      for (int rr = 0; rr < 4; ++rr) {
        const int row = row0 + mi * 16 + rr;
        const float v = acc[mi][ni][rr] + bs;
        if constexpr (MODE == 0) {
          ((float*)P0)[(size_t)row * ldc + col] = v;
        } else if constexpr (MODE == 1) {
          ((unsigned short*)P0)[(size_t)row * ldc + col] = f2bf(v);
          if (P1) ((unsigned short*)P1)[(size_t)row * ldc2 + col] = f2bf(v);
        } else if constexpr (MODE == 2) {
          // xpr layout for lstm_step: [t][wg(128)][lane(64)][nj(8)][g(4)] f32
          const int t = row & 63, b = row >> 6;
          const int g = col >> 9, d = col & 511;
          const int wg2 = d >> 2;
          const int ln = (d & 3) * 16 + (b & 15);
          const int nj = b >> 4;
          ((float*)P0)[((((size_t)t * 128 + wg2) * 64 + ln) * 8 + nj) * 4 + g] = v;
        } else {  // MODE 3: init states
          const int seg = col >> 9, cc = col & 511;
          if (seg == 0)      ((unsigned short*)P0)[(size_t)row * 512 + cc] = f2bf(v);
          else if (seg == 2) ((unsigned short*)P2)[(size_t)row * 512 + cc] = f2bf(v);
          else {
            // c layout: [wg(128)][nj(8)][lane(64)] f32
            float* cb = (seg == 1) ? (float*)P1 : (float*)P3;
            cb[((cc >> 2) * 8 + (row >> 4)) * 64 + (cc & 3) * 16 + (row & 15)] = v;
          }
        }
      }
    }
  }
}

// ================= one LSTM timestep: 256 single-wave WGs, no LDS, no barriers ========
// Block b: wg = b>>1 owns d-slice [4wg,4wg+4) (16 m-rows, gates interleaved
// r = 4*dq + g), half = b&1 owns batch rows [64*half, 64*half+64) as 4 nj frags.
// W pre-reordered to the exact A-frag stream (Wr). Gate math lane-local in C-frag.
__global__ __launch_bounds__(64) void lstm_step(
    const unsigned short* __restrict__ Wr,    // [128][16][64][8] bf16
    const unsigned short* __restrict__ hprev, int ldh,
    const float* __restrict__ xpt,            // this step's [128][64][8][4] f32 slab
    float* __restrict__ cbuf,                 // [128][8][64] f32
    unsigned short* __restrict__ hout, int ldho)
{
  const int wg = blockIdx.x >> 1, half = blockIdx.x & 1;
  const int lane = threadIdx.x, fr = lane & 15, q = lane >> 4;

  // prefetch epilogue operands (independent of the K-loop)
  float4 xg[4];
  const float4* xv = (const float4*)xpt + ((size_t)(wg * 64 + lane) * 8 + half * 4);
#pragma unroll
  for (int nj = 0; nj < 4; ++nj) xg[nj] = xv[nj];
  float cold[4];
#pragma unroll
  for (int nj = 0; nj < 4; ++nj) cold[nj] = cbuf[(wg * 8 + half * 4 + nj) * 64 + lane];

  const unsigned short* hbase = hprev + (size_t)(half * 64 + fr) * ldh + q * 8;
  const bf16x8* wv = (const bf16x8*)Wr + (size_t)wg * 16 * 64 + lane;

  f32x4 acc[4] = {};
#pragma unroll
  for (int kk = 0; kk < 16; ++kk) {
    const bf16x8 af = wv[kk * 64];
    bf16x8 hf[4];
#pragma unroll
    for (int nj = 0; nj < 4; ++nj)
      hf[nj] = *(const bf16x8*)(hbase + (size_t)nj * 16 * ldh + kk * 32);
#pragma unroll
    for (int nj = 0; nj < 4; ++nj)
      acc[nj] = __builtin_amdgcn_mfma_f32_16x16x32_bf16(af, hf[nj], acc[nj], 0, 0, 0);
  }

  const int d = wg * 4 + q;
#pragma unroll
  for (int nj = 0; nj < 4; ++nj) {
    const int b = half * 64 + nj * 16 + fr;
    const float iv = acc[nj][0] + xg[nj].x;
    const float fv = acc[nj][1] + xg[nj].y;
    const float gv = acc[nj][2] + xg[nj].z;
    const float ov = acc[nj][3] + xg[nj].w;
    const float c = fsig(fv) * cold[nj] + fsig(iv) * ftanh(gv);
    cbuf[(wg * 8 + half * 4 + nj) * 64 + lane] = c;
    hout[(size_t)b * ldho + d] = f2bf(fsig(ov) * ftanh(c));
  }
}

// Reorder W_hh [2048,512] f32 -> A-frag stream [128][16][64][8] bf16.
// Chunk t: lane=t&63, kk=(t>>6)&15, wg=t>>10; r=lane&15, kc=lane>>4;
// src row = (r&3)*512 + 4*wg + (r>>2), k = kk*32 + kc*8.
__global__ void reorder_whh(const float* __restrict__ W1, const float* __restrict__ W2,
                            unsigned short* __restrict__ R1, unsigned short* __restrict__ R2) {
  const int id = blockIdx.x * blockDim.x + threadIdx.x;  // 262144 total
  const float* W = (id >> 17) ? W2 : W1;
  unsigned short* R = (id >> 17) ? R2 : R1;
  const int t = id & 131071;
  const int lane = t & 63, kk = (t >> 6) & 15, wg = t >> 10;
  const int r = lane & 15, kc = lane >> 4;
  const float* s = W + (size_t)((r & 3) * 512 + wg * 4 + (r >> 2)) * 512 + kk * 32 + kc * 8;
  bf16x8 v;
#pragma unroll
  for (int e = 0; e < 8; ++e) v[e] = (short)f2bf(s[e]);
  *((bf16x8*)R + t) = v;
}

// ================= small helpers =================
struct CastJobs {
  const float* src[15];
  unsigned short* dst[15];
  long nreal[15];
  long cum[16];
  int n;
};

__global__ void cast_multi(CastJobs J) {
  const long total = J.cum[J.n];
  for (long i = (long)blockIdx.x * blockDim.x + threadIdx.x; i < total;
       i += (long)gridDim.x * blockDim.x) {
    int s = 0;
    while (i >= J.cum[s + 1]) ++s;
    const long off = i - J.cum[s];
    J.dst[s][off] = (off < J.nreal[s]) ? f2bf(J.src[s][off]) : (unsigned short)0;
  }
}

__global__ void concat_bias(const float* a, const float* b, const float* c, const float* d,
                            float* o) {
  const int i = blockIdx.x * blockDim.x + threadIdx.x;  // 2048
  const float* s[4] = {a, b, c, d};
  o[i] = s[i >> 9][i & 511];
}

__global__ void gather_rows(const int* __restrict__ ix, const unsigned short* __restrict__ emb,
                            unsigned short* __restrict__ x) {
  const int row = blockIdx.x;
  const int e = ix[row];
  const uint4* s = (const uint4*)(emb + (size_t)e * 512);
  uint4* d = (uint4*)(x + (size_t)row * 512);
  d[threadIdx.x] = s[threadIdx.x];
}

// ================= host =================
extern "C" void kernel_launch(void* const* d_in, const int* in_sizes, int n_in,
                              void* d_out, int out_size, void* d_ws, size_t ws_size,
                              hipStream_t stream) {
  (void)in_sizes; (void)n_in; (void)out_size; (void)ws_size;
  const float* img    = (const float*)d_in[0];
  const int*   ix     = (const int*)d_in[1];
  const float* emb    = (const float*)d_in[2];
  const float* Wih1f  = (const float*)d_in[3];
  const float* bih1   = (const float*)d_in[4];
  const float* Wic1f  = (const float*)d_in[5];
  const float* bic1   = (const float*)d_in[6];
  const float* Wih2f  = (const float*)d_in[7];
  const float* bih2   = (const float*)d_in[8];
  const float* Wic2f  = (const float*)d_in[9];
  const float* bic2   = (const float*)d_in[10];
  const float* Wihl1  = (const float*)d_in[11];
  const float* Whhl1  = (const float*)d_in[12];
  const float* b1     = (const float*)d_in[13];
  const float* Wihl2  = (const float*)d_in[14];
  const float* Whhl2  = (const float*)d_in[15];
  const float* b2     = (const float*)d_in[16];
  const float* Wv1    = (const float*)d_in[17];
  const float* bv1    = (const float*)d_in[18];
  const float* Wo1    = (const float*)d_in[19];
  const float* bo1    = (const float*)d_in[20];
  const float* Wv2    = (const float*)d_in[21];
  const float* bv2    = (const float*)d_in[22];
  const float* Wo2    = (const float*)d_in[23];
  const float* bo2    = (const float*)d_in[24];
  const float* Wlog   = (const float*)d_in[25];
  const float* blog   = (const float*)d_in[26];
  float* out = (float*)d_out;

  char* p = (char*)d_ws;
  auto al = [&](size_t bytes) { char* r = p; p += (bytes + 255) & ~(size_t)255; return r; };
  unsigned short* emb_b  = (unsigned short*)al((size_t)10000 * 512 * 2);
  unsigned short* Wih1_b = (unsigned short*)al((size_t)2048 * 512 * 2);
  unsigned short* Wr1    = (unsigned short*)al((size_t)2048 * 512 * 2);   // reordered W_hh1
  unsigned short* Wih2_b = (unsigned short*)al((size_t)2048 * 1024 * 2);
  unsigned short* Wr2    = (unsigned short*)al((size_t)2048 * 512 * 2);   // reordered W_hh2
  unsigned short* Wv1_b  = (unsigned short*)al((size_t)512 * 512 * 2);
  unsigned short* Wo1_b  = (unsigned short*)al((size_t)512 * 512 * 2);
  unsigned short* Wv2_b  = (unsigned short*)al((size_t)512 * 512 * 2);
  unsigned short* Wo2_b  = (unsigned short*)al((size_t)512 * 512 * 2);
  unsigned short* Wlog_b = (unsigned short*)al((size_t)10112 * 1536 * 2);
  unsigned short* Wh1i_b = (unsigned short*)al((size_t)512 * 2048 * 2);  // these four are
  unsigned short* Wc1i_b = (unsigned short*)al((size_t)512 * 2048 * 2);  // contiguous:
  unsigned short* Wh2i_b = (unsigned short*)al((size_t)512 * 2048 * 2);  // [2048,2048] concat
  unsigned short* Wc2i_b = (unsigned short*)al((size_t)512 * 2048 * 2);
  unsigned short* img_b  = (unsigned short*)al((size_t)128 * 2048 * 2);
  unsigned short* x_b    = (unsigned short*)al((size_t)8192 * 512 * 2);
  float*          xpr    = (float*)al((size_t)64 * 128 * 64 * 32 * 4);   // 67 MB
  unsigned short* cat1   = (unsigned short*)al((size_t)8192 * 1024 * 2); // [b][t][h1s|attn1]
  unsigned short* out3   = (unsigned short*)al((size_t)8192 * 1536 * 2); // [b][t][h2s|attn1|attn2]
  unsigned short* vtmp   = (unsigned short*)al((size_t)8192 * 512 * 2);
  unsigned short* h01    = (unsigned short*)al((size_t)128 * 512 * 2);
  unsigned short* h02    = (unsigned short*)al((size_t)128 * 512 * 2);
  float*          c1st   = (float*)al((size_t)128 * 512 * 4);
  float*          c2st   = (float*)al((size_t)128 * 512 * 4);
  float*          bcat   = (float*)al((size_t)2048 * 4);

  // ---- all f32->bf16 casts in one kernel (W_hh handled by reorder_whh) ----
  CastJobs J = {};
  auto addjob = [&](const float* s, unsigned short* d, long nreal, long ntot) {
    J.src[J.n] = s; J.dst[J.n] = d; J.nreal[J.n] = nreal;
    J.cum[J.n + 1] = J.cum[J.n] + ntot; ++J.n;
  };
  addjob(img,   img_b,  (long)128 * 2048,   (long)128 * 2048);
  addjob(emb,   emb_b,  (long)10000 * 512,  (long)10000 * 512);
  addjob(Wihl1, Wih1_b, (long)2048 * 512,   (long)2048 * 512);
  addjob(Wihl2, Wih2_b, (long)2048 * 1024,  (long)2048 * 1024);
  addjob(Wv1,   Wv1_b,  (long)512 * 512,    (long)512 * 512);
  addjob(Wo1,   Wo1_b,  (long)512 * 512,    (long)512 * 512);
  addjob(Wv2,   Wv2_b,  (long)512 * 512,    (long)512 * 512);
  addjob(Wo2,   Wo2_b,  (long)512 * 512,    (long)512 * 512);
  addjob(Wih1f, Wh1i_b, (long)512 * 2048,   (long)512 * 2048);
  addjob(Wic1f, Wc1i_b, (long)512 * 2048,   (long)512 * 2048);
  addjob(Wih2f, Wh2i_b, (long)512 * 2048,   (long)512 * 2048);
  addjob(Wic2f, Wc2i_b, (long)512 * 2048,   (long)512 * 2048);
  addjob(Wlog,  Wlog_b, (long)10000 * 1536, (long)10112 * 1536);
  cast_multi<<<2048, 256, 0, stream>>>(J);

  reorder_whh<<<1024, 256, 0, stream>>>(Whhl1, Whhl2, Wr1, Wr2);
  concat_bias<<<8, 256, 0, stream>>>(bih1, bic1, bih2, bic2, bcat);

  // ---- fused init states: [h1 | c1 | h2 | c2] = img @ [W..]^T + bcat ----
  gemm_nt<3><<<dim3(1, 16), 256, 0, stream>>>(
      img_b, 2048, Wh1i_b, 2048, h01, c1st, h02, c2st, 0, 0, bcat, 2048, 2048);

  // ---- x = emb[captions_ix] ----
  gather_rows<<<8192, 64, 0, stream>>>(ix, emb_b, x_b);

  // ---- xp1 = x @ W_ih1^T + b1, written in xpr layout ----
  gemm_nt<2><<<dim3(64, 16), 256, 0, stream>>>(
      x_b, 512, Wih1_b, 512, xpr, nullptr, nullptr, nullptr, 0, 0, b1, 512, 2048);

  // ---- LSTM1: 64 per-step launches -> h1s into cat1 cols [0,512) ----
  for (int t = 0; t < 64; ++t)
    lstm_step<<<256, 64, 0, stream>>>(
        Wr1, t ? cat1 + (size_t)(t - 1) * 1024 : h01, t ? 65536 : 512,
        xpr + (size_t)t * 262144, c1st, cat1 + (size_t)t * 1024, 65536);

  // ---- attn1 -> cat1 cols [512,1024) and out3 cols [512,1024) ----
  gemm_nt<1><<<dim3(64, 4), 256, 0, stream>>>(
      cat1, 1024, Wv1_b, 512, vtmp, nullptr, nullptr, nullptr, 512, 0, bv1, 512, 512);
  gemm_nt<1><<<dim3(64, 4), 256, 0, stream>>>(
      vtmp, 512, Wo1_b, 512, cat1 + 512, out3 + 512, nullptr, nullptr, 1024, 1536, bo1, 512, 512);

  // ---- xp2 = [h1s|attn1] @ W_ih2^T + b2, xpr layout ----
  gemm_nt<2><<<dim3(64, 16), 256, 0, stream>>>(
      cat1, 1024, Wih2_b, 1024, xpr, nullptr, nullptr, nullptr, 0, 0, b2, 1024, 2048);

  // ---- LSTM2: 64 per-step launches -> h2s into out3 cols [0,512) ----
  for (int t = 0; t < 64; ++t)
    lstm_step<<<256, 64, 0, stream>>>(
        Wr2, t ? out3 + (size_t)(t - 1) * 1536 : h02, t ? 98304 : 512,
        xpr + (size_t)t * 262144, c2st, out3 + (size_t)t * 1536, 98304);

  // ---- attn2 -> out3 cols [1024,1536) ----
  gemm_nt<1><<<dim3(64, 4), 256, 0, stream>>>(
      out3, 1536, Wv2_b, 512, vtmp, nullptr, nullptr, nullptr, 512, 0, bv2, 512, 512);
  gemm_nt<1><<<dim3(64, 4), 256, 0, stream>>>(
      vtmp, 512, Wo2_b, 512, out3 + 1024, nullptr, nullptr, nullptr, 1536, 0, bo2, 512, 512);

  // ---- logits = out3 @ W_logits^T + b_logits ----
  gemm_nt<0><<<dim3(64, 79), 256, 0, stream>>>(
      out3, 1536, Wlog_b, 1536, out, nullptr, nullptr, nullptr, 10000, 0, blog, 1536, 10000);
}

// Round 4
// 1439.048 us; speedup vs baseline: 3.1517x; 1.2294x over previous
//
#include <hip/hip_runtime.h>
#include <stdint.h>

#define DEV __device__ __forceinline__

typedef short bf16x8 __attribute__((ext_vector_type(8)));
typedef float f32x4 __attribute__((ext_vector_type(4)));

DEV unsigned short f2bf(float f) {
  union { float f; uint32_t u; } v; v.f = f;
  return (unsigned short)((v.u + 0x7fffu + ((v.u >> 16) & 1u)) >> 16);
}

DEV float fsig(float x) { return 1.f / (1.f + __expf(-x)); }
DEV float ftanh(float x) { float e = __expf(2.f * x); return 1.f - 2.f / (e + 1.f); }

DEV void gload16(const void* g, void* lds) {
  __builtin_amdgcn_global_load_lds(
      (const __attribute__((address_space(1))) int*)(uintptr_t)g,
      (__attribute__((address_space(3))) int*)(uintptr_t)lds, 16, 0, 0);
}

// ================= generic NT GEMM: C[M,N] = A[M,K] * B[N,K]^T + bias =================
// 128x128 tile, BK=32, 4 waves each 64x64.
// MODE 0: f32 C.  MODE 1: bf16 C (+optional C2).
// MODE 2: xpr layout (A = gate-interleaved W_ih, bias per ROW, float4 stores).
// MODE 3: init states (4 col-segments -> h1 bf16, c1 f32, h2 bf16, c2 f32; plain [128][512]).
template <int MODE>
__global__ __launch_bounds__(256) void gemm_nt(
    const unsigned short* __restrict__ A, int lda,
    const unsigned short* __restrict__ B, int ldb,
    void* __restrict__ P0, void* __restrict__ P1,
    void* __restrict__ P2, void* __restrict__ P3,
    int ldc, int ldc2,
    const float* __restrict__ bias,
    int K, int Nreal)
{
  __shared__ alignas(16) unsigned short Asm[128 * 32];
  __shared__ alignas(16) unsigned short Bsm[128 * 32];
  const int tid = threadIdx.x;
  const int wave = tid >> 6, lane = tid & 63;

  // bijective XCD swizzle on linear block id (m204 variant)
  const int gx = gridDim.x;
  const int lin = blockIdx.y * gx + blockIdx.x;
  const int nwg = gx * gridDim.y;
  const int q = nwg >> 3, r = nwg & 7;
  const int xcd = lin & 7, i2 = lin >> 3;
  const int wg = (xcd < r ? xcd * (q + 1) : r * (q + 1) + (xcd - r) * q) + i2;
  const int m0 = (wg % gx) * 128, n0 = (wg / gx) * 128;

  const int wr = wave >> 1, wc = wave & 1;
  f32x4 acc[4][4] = {};

  const int q0 = tid, q1 = tid + 256;
  const unsigned short* Ag0 = A + (size_t)(m0 + (q0 >> 2)) * lda + (q0 & 3) * 8;
  const unsigned short* Ag1 = A + (size_t)(m0 + (q1 >> 2)) * lda + (q1 & 3) * 8;
  const unsigned short* Bg0 = B + (size_t)(n0 + (q0 >> 2)) * ldb + (q0 & 3) * 8;
  const unsigned short* Bg1 = B + (size_t)(n0 + (q1 >> 2)) * ldb + (q1 & 3) * 8;
  char* As0 = (char*)Asm + wave * 1024;  char* As1 = As0 + 4096;
  char* Bs0 = (char*)Bsm + wave * 1024;  char* Bs1 = Bs0 + 4096;

  const int ra = wr * 64 + (lane & 15);
  const int rb = wc * 64 + (lane & 15);
  const int kb = (lane >> 4) * 16;

  for (int k0 = 0; k0 < K; k0 += 32) {
    gload16(Ag0 + k0, As0);
    gload16(Ag1 + k0, As1);
    gload16(Bg0 + k0, Bs0);
    gload16(Bg1 + k0, Bs1);
    __syncthreads();
    bf16x8 af[4], bfr[4];
#pragma unroll
    for (int i = 0; i < 4; ++i)
      af[i] = *(const bf16x8*)((const char*)Asm + (ra + i * 16) * 64 + kb);
#pragma unroll
    for (int i = 0; i < 4; ++i)
      bfr[i] = *(const bf16x8*)((const char*)Bsm + (rb + i * 16) * 64 + kb);
#pragma unroll
    for (int mi = 0; mi < 4; ++mi)
#pragma unroll
      for (int ni = 0; ni < 4; ++ni)
        acc[mi][ni] = __builtin_amdgcn_mfma_f32_16x16x32_bf16(af[mi], bfr[ni], acc[mi][ni], 0, 0, 0);
    __syncthreads();
  }

  const int row0 = m0 + wr * 64 + (lane >> 4) * 4;
  const int col0 = n0 + wc * 64 + (lane & 15);

  if constexpr (MODE == 2) {
    // rows = gate-interleaved m (4d+g), cols = bt (b*64+t). acc regs r=0..3 are 4
    // consecutive rows = the 4 gates of one d -> float4 store into xpr layout
    // [t][wgid(128)][w(4)][mi(2)][lane(64)][4].
#pragma unroll
    for (int mi = 0; mi < 4; ++mi) {
      const int rowb = row0 + mi * 16;       // multiple of 4
      const int dd = rowb >> 2;
      const float4 b4 = *(const float4*)&bias[rowb];
#pragma unroll
      for (int ni = 0; ni < 4; ++ni) {
        const int col = col0 + ni * 16;
        const int tt = col & 63, bb = col >> 6;
        float4 v;
        v.x = acc[mi][ni][0] + b4.x;
        v.y = acc[mi][ni][1] + b4.y;
        v.z = acc[mi][ni][2] + b4.z;
        v.w = acc[mi][ni][3] + b4.w;
        const int wgid = (bb >> 4) * 16 + (dd >> 5);
        const int ww = (dd >> 3) & 3, mi2 = (dd >> 2) & 1, ln = (dd & 3) * 16 + (bb & 15);
        ((float4*)P0)[((((size_t)tt * 128 + wgid) * 4 + ww) * 2 + mi2) * 64 + ln] = v;
      }
    }
    return;
  }

#pragma unroll
  for (int mi = 0; mi < 4; ++mi) {
#pragma unroll
    for (int ni = 0; ni < 4; ++ni) {
      const int col = col0 + ni * 16;
      if (col >= Nreal) continue;
      const float bs = bias ? bias[col] : 0.f;
#pragma unroll
      for (int rr = 0; rr < 4; ++rr) {
        const int row = row0 + mi * 16 + rr;
        const float v = acc[mi][ni][rr] + bs;
        if constexpr (MODE == 0) {
          ((float*)P0)[(size_t)row * ldc + col] = v;
        } else if constexpr (MODE == 1) {
          ((unsigned short*)P0)[(size_t)row * ldc + col] = f2bf(v);
          if (P1) ((unsigned short*)P1)[(size_t)row * ldc2 + col] = f2bf(v);
        } else {  // MODE 3
          const int seg = col >> 9, cc = col & 511;
          if (seg == 0)      ((unsigned short*)P0)[(size_t)row * 512 + cc] = f2bf(v);
          else if (seg == 1) ((float*)P1)[(size_t)row * 512 + cc] = v;
          else if (seg == 2) ((unsigned short*)P2)[(size_t)row * 512 + cc] = f2bf(v);
          else               ((float*)P3)[(size_t)row * 512 + cc] = v;
        }
      }
    }
  }
}

// ================= persistent LSTM, batch-parallel + LLC exchange =================
// 128 WGs of 256 thr: group g = wgid>>4 owns 16 batch samples; slice s = wgid&15 owns
// d in [32s, 32s+32) (128 gate-rows, gates interleaved m=4*dl+gate). W slice in LDS
// (XOR-swizzled, staged once). c in registers. Per step: gates = Wsm @ h_g[16x512];
// h exchange via per-step region hx[t] (system-scope stores -> LLC; plain first-touch
// reads) + per-group system-scope counter. No cache invalidation anywhere.
__global__ __launch_bounds__(256) void lstm_seq(
    const unsigned short* __restrict__ Whh,   // [2048,512] bf16
    const unsigned short* __restrict__ h0,    // [128,512] bf16
    const float* __restrict__ c0,             // [128,512] f32
    const float* __restrict__ xpr,            // [64][128][4][2][64][4] f32
    unsigned short* __restrict__ hx,          // [64][128][512] exchange
    unsigned short* __restrict__ hout,        // strided output base (rows b*64+t)
    int ldho,
    int* __restrict__ cnt)                    // per-group counters, stride 16 ints
{
  __shared__ unsigned short Wsm[8][128][64];  // [k-block(64k)][m][128B row, 8 swz slots]
  const int tid = threadIdx.x;
  const int g = blockIdx.x >> 4, s = blockIdx.x & 15;
  const int w = tid >> 6, lane = tid & 63, fr = lane & 15, kq = lane >> 4;

  // ---- stage W slice into LDS (slot = c ^ (m&7) within 128B rows) ----
  {
    const int m = tid >> 1;
    const int row = (m & 3) * 512 + s * 32 + (m >> 2);
    const unsigned short* src = Whh + (size_t)row * 512 + (tid & 1) * 256;
#pragma unroll 4
    for (int cc = 0; cc < 32; ++cc) {
      const int k = (tid & 1) * 256 + cc * 8;
      uint4 v = *(const uint4*)(src + cc * 8);
      const int kblk = k >> 6, c = (k & 63) >> 3, sl = c ^ (m & 7);
      *(uint4*)((char*)&Wsm[kblk][m][0] + sl * 16) = v;
    }
  }

  const int b = g * 16 + fr;                  // global batch row
  const int d0 = s * 32 + w * 8 + kq;         // global d for mi=0 (mi=1: +4)
  float c_r[2];
  c_r[0] = c0[b * 512 + d0];
  c_r[1] = c0[b * 512 + d0 + 4];
  __syncthreads();

  int* ctr = cnt + g * 16;
  const float4* xv = (const float4*)xpr + ((size_t)(blockIdx.x * 4 + w) * 2) * 64 + lane;

  for (int t = 0; t < 64; ++t) {
    // xp prefetch (independent of exchange)
    const float4 xg0 = xv[(size_t)t * 65536];
    const float4 xg1 = xv[(size_t)t * 65536 + 64];

    // wait for group's previous-step producers
    if (t) {
      if (tid == 0) {
        while (__hip_atomic_load(ctr, __ATOMIC_RELAXED, __HIP_MEMORY_SCOPE_SYSTEM) < 16 * t)
          __builtin_amdgcn_s_sleep(2);
      }
      __syncthreads();
    }

    // h fragments: 16 KB of fresh lines (LLC hit, first touch in this dispatch)
    const unsigned short* hsrc = t ? hx + (size_t)(t - 1) * 65536 : h0;
    const unsigned short* hb = hsrc + (size_t)b * 512 + kq * 8;
    bf16x8 hf[16];
#pragma unroll
    for (int kk = 0; kk < 16; ++kk)
      hf[kk] = *(const bf16x8*)(hb + kk * 32);

    f32x4 acc[2] = {};
#pragma unroll
    for (int kk = 0; kk < 16; ++kk) {
      const int kblk = kk >> 1, cbase = (kk & 1) * 4 + kq;
#pragma unroll
      for (int mi = 0; mi < 2; ++mi) {
        const int m = w * 32 + mi * 16 + fr;
        const int sl = cbase ^ (m & 7);
        const bf16x8 af = *(const bf16x8*)((const char*)&Wsm[kblk][m][0] + sl * 16);
        acc[mi] = __builtin_amdgcn_mfma_f32_16x16x32_bf16(af, hf[kk], acc[mi], 0, 0, 0);
      }
    }

    // gates lane-local: regs 0..3 = i,f,g,o for (b, d)
#pragma unroll
    for (int mi = 0; mi < 2; ++mi) {
      const int d = d0 + mi * 4;
      const float4 xg = mi ? xg1 : xg0;
      const float iv = acc[mi][0] + xg.x;
      const float fv = acc[mi][1] + xg.y;
      const float gv = acc[mi][2] + xg.z;
      const float ov = acc[mi][3] + xg.w;
      const float c = fsig(fv) * c_r[mi] + fsig(iv) * ftanh(gv);
      c_r[mi] = c;
      const unsigned short hn = f2bf(fsig(ov) * ftanh(c));
      // exchange store: bypass L2 so other XCDs' first-touch reads hit it in LLC
      __hip_atomic_store(&hx[(size_t)t * 65536 + b * 512 + d], hn,
                         __ATOMIC_RELAXED, __HIP_MEMORY_SCOPE_SYSTEM);
      // strided output for later GEMMs (plain; kernel-boundary coherence)
      hout[((size_t)b * 64 + t) * ldho + d] = hn;
    }

    asm volatile("s_waitcnt vmcnt(0)" ::: "memory");
    __syncthreads();
    if (tid == 0)
      __hip_atomic_fetch_add(ctr, 1, __ATOMIC_RELAXED, __HIP_MEMORY_SCOPE_SYSTEM);
  }
}

// ================= small helpers =================
struct CastJobs {
  const float* src[15];
  unsigned short* dst[15];
  long nreal[15];
  long cum[16];
  int n;
};

__global__ void cast_multi(CastJobs J) {
  const long total = J.cum[J.n];
  for (long i = (long)blockIdx.x * blockDim.x + threadIdx.x; i < total;
       i += (long)gridDim.x * blockDim.x) {
    int s = 0;
    while (i >= J.cum[s + 1]) ++s;
    const long off = i - J.cum[s];
    J.dst[s][off] = (off < J.nreal[s]) ? f2bf(J.src[s][off]) : (unsigned short)0;
  }
}

// gate-interleaved row permutation of W_ih (+ biases): dst row m = 4d+g <- src row g*512+d
__global__ void perm_wih(const float* __restrict__ W1, const float* __restrict__ W2,
                         const float* __restrict__ b1, const float* __restrict__ b2,
                         unsigned short* __restrict__ R1, unsigned short* __restrict__ R2,
                         float* __restrict__ bp1, float* __restrict__ bp2) {
  const long id = (long)blockIdx.x * blockDim.x + threadIdx.x;  // 3145728 total
  const long n1 = (long)2048 * 512;
  if (id < n1) {
    const int m = (int)(id >> 9), k = (int)(id & 511);
    R1[id] = f2bf(W1[(size_t)((m & 3) * 512 + (m >> 2)) * 512 + k]);
  } else {
    const long j = id - n1;
    const int m = (int)(j >> 10), k = (int)(j & 1023);
    R2[j] = f2bf(W2[(size_t)((m & 3) * 512 + (m >> 2)) * 1024 + k]);
  }
  if (id < 2048) bp1[id] = b1[(id & 3) * 512 + (id >> 2)];
  else if (id < 4096) { const int m = (int)id - 2048; bp2[m] = b2[(m & 3) * 512 + (m >> 2)]; }
}

__global__ void concat_bias(const float* a, const float* b, const float* c, const float* d,
                            float* o) {
  const int i = blockIdx.x * blockDim.x + threadIdx.x;  // 2048
  const float* s[4] = {a, b, c, d};
  o[i] = s[i >> 9][i & 511];
}

__global__ void gather_rows(const int* __restrict__ ix, const unsigned short* __restrict__ emb,
                            unsigned short* __restrict__ x) {
  const int row = blockIdx.x;
  const int e = ix[row];
  const uint4* s = (const uint4*)(emb + (size_t)e * 512);
  uint4* d = (uint4*)(x + (size_t)row * 512);
  d[threadIdx.x] = s[threadIdx.x];
}

// ================= host =================
extern "C" void kernel_launch(void* const* d_in, const int* in_sizes, int n_in,
                              void* d_out, int out_size, void* d_ws, size_t ws_size,
                              hipStream_t stream) {
  (void)in_sizes; (void)n_in; (void)out_size; (void)ws_size;
  const float* img    = (const float*)d_in[0];
  const int*   ix     = (const int*)d_in[1];
  const float* emb    = (const float*)d_in[2];
  const float* Wih1f  = (const float*)d_in[3];
  const float* bih1   = (const float*)d_in[4];
  const float* Wic1f  = (const float*)d_in[5];
  const float* bic1   = (const float*)d_in[6];
  const float* Wih2f  = (const float*)d_in[7];
  const float* bih2   = (const float*)d_in[8];
  const float* Wic2f  = (const float*)d_in[9];
  const float* bic2   = (const float*)d_in[10];
  const float* Wihl1  = (const float*)d_in[11];
  const float* Whhl1  = (const float*)d_in[12];
  const float* b1     = (const float*)d_in[13];
  const float* Wihl2  = (const float*)d_in[14];
  const float* Whhl2  = (const float*)d_in[15];
  const float* b2     = (const float*)d_in[16];
  const float* Wv1    = (const float*)d_in[17];
  const float* bv1    = (const float*)d_in[18];
  const float* Wo1    = (const float*)d_in[19];
  const float* bo1    = (const float*)d_in[20];
  const float* Wv2    = (const float*)d_in[21];
  const float* bv2    = (const float*)d_in[22];
  const float* Wo2    = (const float*)d_in[23];
  const float* bo2    = (const float*)d_in[24];
  const float* Wlog   = (const float*)d_in[25];
  const float* blog   = (const float*)d_in[26];
  float* out = (float*)d_out;

  char* p = (char*)d_ws;
  auto al = [&](size_t bytes) { char* r = p; p += (bytes + 255) & ~(size_t)255; return r; };
  unsigned short* emb_b  = (unsigned short*)al((size_t)10000 * 512 * 2);
  unsigned short* Wp1    = (unsigned short*)al((size_t)2048 * 512 * 2);   // perm W_ih1
  unsigned short* Whh1_b = (unsigned short*)al((size_t)2048 * 512 * 2);
  unsigned short* Wp2    = (unsigned short*)al((size_t)2048 * 1024 * 2);  // perm W_ih2
  unsigned short* Whh2_b = (unsigned short*)al((size_t)2048 * 512 * 2);
  unsigned short* Wv1_b  = (unsigned short*)al((size_t)512 * 512 * 2);
  unsigned short* Wo1_b  = (unsigned short*)al((size_t)512 * 512 * 2);
  unsigned short* Wv2_b  = (unsigned short*)al((size_t)512 * 512 * 2);
  unsigned short* Wo2_b  = (unsigned short*)al((size_t)512 * 512 * 2);
  unsigned short* Wlog_b = (unsigned short*)al((size_t)10112 * 1536 * 2);
  unsigned short* Wh1i_b = (unsigned short*)al((size_t)512 * 2048 * 2);  // contiguous 4x:
  unsigned short* Wc1i_b = (unsigned short*)al((size_t)512 * 2048 * 2);  // [2048,2048]
  unsigned short* Wh2i_b = (unsigned short*)al((size_t)512 * 2048 * 2);
  unsigned short* Wc2i_b = (unsigned short*)al((size_t)512 * 2048 * 2);
  unsigned short* img_b  = (unsigned short*)al((size_t)128 * 2048 * 2);
  unsigned short* x_b    = (unsigned short*)al((size_t)8192 * 512 * 2);
  float*          xpr    = (float*)al((size_t)8192 * 2048 * 4);          // 67 MB
  unsigned short* cat1   = (unsigned short*)al((size_t)8192 * 1024 * 2); // [h1s | attn1]
  unsigned short* out3   = (unsigned short*)al((size_t)8192 * 1536 * 2); // [h2s | attn1 | attn2]
  unsigned short* vtmp   = (unsigned short*)al((size_t)8192 * 512 * 2);
  unsigned short* hx1    = (unsigned short*)al((size_t)64 * 128 * 512 * 2);
  unsigned short* hx2    = (unsigned short*)al((size_t)64 * 128 * 512 * 2);
  unsigned short* h01    = (unsigned short*)al((size_t)128 * 512 * 2);
  unsigned short* h02    = (unsigned short*)al((size_t)128 * 512 * 2);
  float*          c1st   = (float*)al((size_t)128 * 512 * 4);
  float*          c2st   = (float*)al((size_t)128 * 512 * 4);
  float*          bcat   = (float*)al((size_t)2048 * 4);
  float*          bp1    = (float*)al((size_t)2048 * 4);
  float*          bp2    = (float*)al((size_t)2048 * 4);
  int*            cnt    = (int*)al(1024);

  hipMemsetAsync(cnt, 0, 1024, stream);

  // ---- f32->bf16 casts ----
  CastJobs J = {};
  auto addjob = [&](const float* s, unsigned short* d, long nreal, long ntot) {
    J.src[J.n] = s; J.dst[J.n] = d; J.nreal[J.n] = nreal;
    J.cum[J.n + 1] = J.cum[J.n] + ntot; ++J.n;
  };
  addjob(img,   img_b,  (long)128 * 2048,   (long)128 * 2048);
  addjob(emb,   emb_b,  (long)10000 * 512,  (long)10000 * 512);
  addjob(Whhl1, Whh1_b, (long)2048 * 512,   (long)2048 * 512);
  addjob(Whhl2, Whh2_b, (long)2048 * 512,   (long)2048 * 512);
  addjob(Wv1,   Wv1_b,  (long)512 * 512,    (long)512 * 512);
  addjob(Wo1,   Wo1_b,  (long)512 * 512,    (long)512 * 512);
  addjob(Wv2,   Wv2_b,  (long)512 * 512,    (long)512 * 512);
  addjob(Wo2,   Wo2_b,  (long)512 * 512,    (long)512 * 512);
  addjob(Wih1f, Wh1i_b, (long)512 * 2048,   (long)512 * 2048);
  addjob(Wic1f, Wc1i_b, (long)512 * 2048,   (long)512 * 2048);
  addjob(Wih2f, Wh2i_b, (long)512 * 2048,   (long)512 * 2048);
  addjob(Wic2f, Wc2i_b, (long)512 * 2048,   (long)512 * 2048);
  addjob(Wlog,  Wlog_b, (long)10000 * 1536, (long)10112 * 1536);
  cast_multi<<<2048, 256, 0, stream>>>(J);

  perm_wih<<<12288, 256, 0, stream>>>(Wihl1, Wihl2, b1, b2, Wp1, Wp2, bp1, bp2);
  concat_bias<<<8, 256, 0, stream>>>(bih1, bic1, bih2, bic2, bcat);

  // ---- fused init states ----
  gemm_nt<3><<<dim3(1, 16), 256, 0, stream>>>(
      img_b, 2048, Wh1i_b, 2048, h01, c1st, h02, c2st, 0, 0, bcat, 2048, 2048);

  // ---- x = emb[captions_ix] ----
  gather_rows<<<8192, 64, 0, stream>>>(ix, emb_b, x_b);

  // ---- xp1 = Wp1 @ x^T (+bp1), straight into xpr layout ----
  gemm_nt<2><<<dim3(16, 64), 256, 0, stream>>>(
      Wp1, 512, x_b, 512, xpr, nullptr, nullptr, nullptr, 0, 0, bp1, 512, 8192);

  // ---- LSTM1 (one kernel) -> h1s into cat1 cols [0,512) ----
  lstm_seq<<<128, 256, 0, stream>>>(Whh1_b, h01, c1st, xpr, hx1, cat1, 1024, cnt);

  // ---- attn1 -> cat1 cols [512,1024) and out3 cols [512,1024) ----
  gemm_nt<1><<<dim3(64, 4), 256, 0, stream>>>(
      cat1, 1024, Wv1_b, 512, vtmp, nullptr, nullptr, nullptr, 512, 0, bv1, 512, 512);
  gemm_nt<1><<<dim3(64, 4), 256, 0, stream>>>(
      vtmp, 512, Wo1_b, 512, cat1 + 512, out3 + 512, nullptr, nullptr, 1024, 1536, bo1, 512, 512);

  // ---- xp2 = Wp2 @ [h1s|attn1]^T (+bp2) ----
  gemm_nt<2><<<dim3(16, 64), 256, 0, stream>>>(
      Wp2, 1024, cat1, 1024, xpr, nullptr, nullptr, nullptr, 0, 0, bp2, 1024, 8192);

  // ---- LSTM2 -> h2s into out3 cols [0,512) ----
  lstm_seq<<<128, 256, 0, stream>>>(Whh2_b, h02, c2st, xpr, hx2, out3, 1536, cnt + 128);

  // ---- attn2 -> out3 cols [1024,1536) ----
  gemm_nt<1><<<dim3(64, 4), 256, 0, stream>>>(
      out3, 1536, Wv2_b, 512, vtmp, nullptr, nullptr, nullptr, 512, 0, bv2, 512, 512);
  gemm_nt<1><<<dim3(64, 4), 256, 0, stream>>>(
      vtmp, 512, Wo2_b, 512, out3 + 1024, nullptr, nullptr, nullptr, 1536, 0, bo2, 512, 512);

  // ---- logits ----
  gemm_nt<0><<<dim3(64, 79), 256, 0, stream>>>(
      out3, 1536, Wlog_b, 1536, out, nullptr, nullptr, nullptr, 10000, 0, blog, 1536, 10000);
}

// Round 5
// 1357.818 us; speedup vs baseline: 3.3402x; 1.0598x over previous
//
#include <hip/hip_runtime.h>
#include <stdint.h>

#define DEV __device__ __forceinline__

typedef short bf16x8 __attribute__((ext_vector_type(8)));
typedef float f32x4 __attribute__((ext_vector_type(4)));

DEV unsigned short f2bf(float f) {
  union { float f; uint32_t u; } v; v.f = f;
  return (unsigned short)((v.u + 0x7fffu + ((v.u >> 16) & 1u)) >> 16);
}

DEV float fsig(float x) { return 1.f / (1.f + __expf(-x)); }
DEV float ftanh(float x) { float e = __expf(2.f * x); return 1.f - 2.f / (e + 1.f); }

DEV void gload16(const void* g, void* lds) {
  __builtin_amdgcn_global_load_lds(
      (const __attribute__((address_space(1))) int*)(uintptr_t)g,
      (__attribute__((address_space(3))) int*)(uintptr_t)lds, 16, 0, 0);
}

// ================= generic NT GEMM: C[M,N] = A[M,K] * B[N,K]^T + bias =================
// 128x128 tile, BK=32, 4 waves each 64x64.
// MODE 0: f32 C.  MODE 1: bf16 C (+optional C2).
// MODE 2: xpr layout (A = gate-interleaved W_ih, bias per ROW, float4 stores).
// MODE 3: init states (4 col-segments -> h1 bf16, c1 f32, h2 bf16, c2 f32).
template <int MODE>
__global__ __launch_bounds__(256) void gemm_nt(
    const unsigned short* __restrict__ A, int lda,
    const unsigned short* __restrict__ B, int ldb,
    void* __restrict__ P0, void* __restrict__ P1,
    void* __restrict__ P2, void* __restrict__ P3,
    int ldc, int ldc2,
    const float* __restrict__ bias,
    int K, int Nreal)
{
  __shared__ alignas(16) unsigned short Asm[128 * 32];
  __shared__ alignas(16) unsigned short Bsm[128 * 32];
  const int tid = threadIdx.x;
  const int wave = tid >> 6, lane = tid & 63;

  // bijective XCD swizzle on linear block id (m204 variant)
  const int gx = gridDim.x;
  const int lin = blockIdx.y * gx + blockIdx.x;
  const int nwg = gx * gridDim.y;
  const int q = nwg >> 3, r = nwg & 7;
  const int xcd = lin & 7, i2 = lin >> 3;
  const int wg = (xcd < r ? xcd * (q + 1) : r * (q + 1) + (xcd - r) * q) + i2;
  const int m0 = (wg % gx) * 128, n0 = (wg / gx) * 128;

  const int wr = wave >> 1, wc = wave & 1;
  f32x4 acc[4][4] = {};

  const int q0 = tid, q1 = tid + 256;
  const unsigned short* Ag0 = A + (size_t)(m0 + (q0 >> 2)) * lda + (q0 & 3) * 8;
  const unsigned short* Ag1 = A + (size_t)(m0 + (q1 >> 2)) * lda + (q1 & 3) * 8;
  const unsigned short* Bg0 = B + (size_t)(n0 + (q0 >> 2)) * ldb + (q0 & 3) * 8;
  const unsigned short* Bg1 = B + (size_t)(n0 + (q1 >> 2)) * ldb + (q1 & 3) * 8;
  char* As0 = (char*)Asm + wave * 1024;  char* As1 = As0 + 4096;
  char* Bs0 = (char*)Bsm + wave * 1024;  char* Bs1 = Bs0 + 4096;

  const int ra = wr * 64 + (lane & 15);
  const int rb = wc * 64 + (lane & 15);
  const int kb = (lane >> 4) * 16;

  for (int k0 = 0; k0 < K; k0 += 32) {
    gload16(Ag0 + k0, As0);
    gload16(Ag1 + k0, As1);
    gload16(Bg0 + k0, Bs0);
    gload16(Bg1 + k0, Bs1);
    __syncthreads();
    bf16x8 af[4], bfr[4];
#pragma unroll
    for (int i = 0; i < 4; ++i)
      af[i] = *(const bf16x8*)((const char*)Asm + (ra + i * 16) * 64 + kb);
#pragma unroll
    for (int i = 0; i < 4; ++i)
      bfr[i] = *(const bf16x8*)((const char*)Bsm + (rb + i * 16) * 64 + kb);
#pragma unroll
    for (int mi = 0; mi < 4; ++mi)
#pragma unroll
      for (int ni = 0; ni < 4; ++ni)
        acc[mi][ni] = __builtin_amdgcn_mfma_f32_16x16x32_bf16(af[mi], bfr[ni], acc[mi][ni], 0, 0, 0);
    __syncthreads();
  }

  const int row0 = m0 + wr * 64 + (lane >> 4) * 4;
  const int col0 = n0 + wc * 64 + (lane & 15);

  if constexpr (MODE == 2) {
#pragma unroll
    for (int mi = 0; mi < 4; ++mi) {
      const int rowb = row0 + mi * 16;       // multiple of 4
      const int dd = rowb >> 2;
      const float4 b4 = *(const float4*)&bias[rowb];
#pragma unroll
      for (int ni = 0; ni < 4; ++ni) {
        const int col = col0 + ni * 16;
        const int tt = col & 63, bb = col >> 6;
        float4 v;
        v.x = acc[mi][ni][0] + b4.x;
        v.y = acc[mi][ni][1] + b4.y;
        v.z = acc[mi][ni][2] + b4.z;
        v.w = acc[mi][ni][3] + b4.w;
        const int wgid = (bb >> 4) * 16 + (dd >> 5);
        const int ww = (dd >> 3) & 3, mi2 = (dd >> 2) & 1, ln = (dd & 3) * 16 + (bb & 15);
        ((float4*)P0)[((((size_t)tt * 128 + wgid) * 4 + ww) * 2 + mi2) * 64 + ln] = v;
      }
    }
    return;
  }

#pragma unroll
  for (int mi = 0; mi < 4; ++mi) {
#pragma unroll
    for (int ni = 0; ni < 4; ++ni) {
      const int col = col0 + ni * 16;
      if (col >= Nreal) continue;
      const float bs = bias ? bias[col] : 0.f;
#pragma unroll
      for (int rr = 0; rr < 4; ++rr) {
        const int row = row0 + mi * 16 + rr;
        const float v = acc[mi][ni][rr] + bs;
        if constexpr (MODE == 0) {
          ((float*)P0)[(size_t)row * ldc + col] = v;
        } else if constexpr (MODE == 1) {
          ((unsigned short*)P0)[(size_t)row * ldc + col] = f2bf(v);
          if (P1) ((unsigned short*)P1)[(size_t)row * ldc2 + col] = f2bf(v);
        } else {  // MODE 3
          const int seg = col >> 9, cc = col & 511;
          if (seg == 0)      ((unsigned short*)P0)[(size_t)row * 512 + cc] = f2bf(v);
          else if (seg == 1) ((float*)P1)[(size_t)row * 512 + cc] = v;
          else if (seg == 2) ((unsigned short*)P2)[(size_t)row * 512 + cc] = f2bf(v);
          else               ((float*)P3)[(size_t)row * 512 + cc] = v;
        }
      }
    }
  }
}

// ============ 256x256 tile GEMM, BK=64, counted vmcnt pipeline (T2+T3+T4+T5) ============
// 8 waves (2M x 4N), each owns 128x64 out. 2 LDS buffers (128 KiB), 2-tile-ahead
// prefetch, vmcnt(8) per K-tile (never 0 in loop), raw s_barrier, XOR-swizzled LDS
// (slot = chunk ^ (row&7), applied via pre-swizzled global SOURCE + swizzled read).
__global__ __launch_bounds__(512, 2) void gemm256(
    const unsigned short* __restrict__ A, int lda,
    const unsigned short* __restrict__ B, int ldb,
    float* __restrict__ C, int ldc,
    const float* __restrict__ bias, int K, int Nreal)
{
  __shared__ alignas(16) unsigned short Lds[2][2][16384];  // [buf][A/B][256*64]
  const int tid = threadIdx.x;
  const int wave = tid >> 6, lane = tid & 63;
  const int fr = lane & 15, kq = lane >> 4;

  const int gx = gridDim.x;
  const int lin = blockIdx.y * gx + blockIdx.x;
  const int nwg = gx * gridDim.y;
  const int q8 = nwg >> 3, r8 = nwg & 7;
  const int xcd = lin & 7, i2 = lin >> 3;
  const int wg = (xcd < r8 ? xcd * (q8 + 1) : r8 * (q8 + 1) + (xcd - r8) * q8) + i2;
  const int m0 = (wg % gx) * 256, n0 = (wg / gx) * 256;

  const int wr = wave >> 2, wc = wave & 3;

  const unsigned short* srcA[4];
  const unsigned short* srcB[4];
  int dstO[4];
#pragma unroll
  for (int s = 0; s < 4; ++s) {
    const int c = tid + s * 512;
    const int row = c >> 3, qp = (c & 7) ^ (row & 7);   // inverse-swizzled source chunk
    srcA[s] = A + (size_t)(m0 + row) * lda + qp * 8;
    srcB[s] = B + (size_t)(n0 + row) * ldb + qp * 8;
    dstO[s] = (wave * 64 + s * 512) * 16;               // linear LDS dest (wave-uniform base)
  }

  const int NT = K >> 6;
#define STAGE256(kt, buf)                                            \
  {                                                                  \
    _Pragma("unroll")                                                \
    for (int s = 0; s < 4; ++s)                                      \
      gload16(srcA[s] + (kt) * 64, (char*)&Lds[buf][0][0] + dstO[s]);\
    _Pragma("unroll")                                                \
    for (int s = 0; s < 4; ++s)                                      \
      gload16(srcB[s] + (kt) * 64, (char*)&Lds[buf][1][0] + dstO[s]);\
  }
  STAGE256(0, 0);
  STAGE256(1, 1);

  f32x4 acc[8][4] = {};
  const int slot0 = (kq ^ (fr & 7)) * 16;  // kk=0 chunk byte offset (2-way-free banks)
  // kk=1 chunk = slot0 ^ 64

  for (int kt = 0; kt < NT; ++kt) {
    asm volatile("s_waitcnt vmcnt(8)" ::: "memory");   // tile kt landed; kt+1 in flight
    __builtin_amdgcn_sched_barrier(0);
    __builtin_amdgcn_s_barrier();
    __builtin_amdgcn_sched_barrier(0);
    const char* bufA = (const char*)&Lds[kt & 1][0][0];
    const char* bufB = (const char*)&Lds[kt & 1][1][0];
    bf16x8 Bf[4][2];
#pragma unroll
    for (int n = 0; n < 4; ++n) {
      const char* bb = bufB + (wc * 64 + n * 16 + fr) * 128;
      Bf[n][0] = *(const bf16x8*)(bb + slot0);
      Bf[n][1] = *(const bf16x8*)(bb + (slot0 ^ 64));
    }
#pragma unroll
    for (int q = 0; q < 4; ++q) {
      bf16x8 Af[2][2];
#pragma unroll
      for (int m2 = 0; m2 < 2; ++m2) {
        const char* ab = bufA + (wr * 128 + q * 32 + m2 * 16 + fr) * 128;
        Af[m2][0] = *(const bf16x8*)(ab + slot0);
        Af[m2][1] = *(const bf16x8*)(ab + (slot0 ^ 64));
      }
      __builtin_amdgcn_s_setprio(1);
#pragma unroll
      for (int m2 = 0; m2 < 2; ++m2)
#pragma unroll
        for (int n = 0; n < 4; ++n) {
          acc[q * 2 + m2][n] = __builtin_amdgcn_mfma_f32_16x16x32_bf16(
              Af[m2][0], Bf[n][0], acc[q * 2 + m2][n], 0, 0, 0);
          acc[q * 2 + m2][n] = __builtin_amdgcn_mfma_f32_16x16x32_bf16(
              Af[m2][1], Bf[n][1], acc[q * 2 + m2][n], 0, 0, 0);
        }
      __builtin_amdgcn_s_setprio(0);
    }
    __builtin_amdgcn_sched_barrier(0);
    __builtin_amdgcn_s_barrier();     // all waves done reading buf[kt&1]
    __builtin_amdgcn_sched_barrier(0);
    const int kn = (kt + 2 < NT) ? kt + 2 : 0;   // tail: reload tile0 (unused, keeps vmcnt math)
    STAGE256(kn, kt & 1);
  }

#pragma unroll
  for (int mf = 0; mf < 8; ++mf) {
    const int row = m0 + wr * 128 + mf * 16 + kq * 4;
#pragma unroll
    for (int n = 0; n < 4; ++n) {
      const int col = n0 + wc * 64 + n * 16 + fr;
      if (col < Nreal) {
        const float bs = bias[col];
#pragma unroll
        for (int rr = 0; rr < 4; ++rr)
          C[(size_t)(row + rr) * ldc + col] = acc[mf][n][rr] + bs;
      }
    }
  }
#undef STAGE256
}

// ================= persistent LSTM, batch-parallel + LLC exchange =================
__global__ __launch_bounds__(256) void lstm_seq(
    const unsigned short* __restrict__ Whh,   // [2048,512] bf16
    const unsigned short* __restrict__ h0,    // [128,512] bf16
    const float* __restrict__ c0,             // [128,512] f32
    const float* __restrict__ xpr,            // [64][128][4][2][64][4] f32
    unsigned short* __restrict__ hx,          // [64][128][512] exchange
    unsigned short* __restrict__ hout,        // strided output base (rows b*64+t)
    int ldho,
    int* __restrict__ cnt)                    // per-group counters, stride 16 ints
{
  __shared__ unsigned short Wsm[8][128][64];  // [k-block(64k)][m][128B row, 8 swz slots]
  const int tid = threadIdx.x;
  const int g = blockIdx.x >> 4, s = blockIdx.x & 15;
  const int w = tid >> 6, lane = tid & 63, fr = lane & 15, kq = lane >> 4;

  {
    const int m = tid >> 1;
    const int row = (m & 3) * 512 + s * 32 + (m >> 2);
    const unsigned short* src = Whh + (size_t)row * 512 + (tid & 1) * 256;
#pragma unroll 4
    for (int cc = 0; cc < 32; ++cc) {
      const int k = (tid & 1) * 256 + cc * 8;
      uint4 v = *(const uint4*)(src + cc * 8);
      const int kblk = k >> 6, c = (k & 63) >> 3, sl = c ^ (m & 7);
      *(uint4*)((char*)&Wsm[kblk][m][0] + sl * 16) = v;
    }
  }

  const int b = g * 16 + fr;
  const int d0 = s * 32 + w * 8 + kq;
  float c_r[2];
  c_r[0] = c0[b * 512 + d0];
  c_r[1] = c0[b * 512 + d0 + 4];
  __syncthreads();

  int* ctr = cnt + g * 16;
  const float4* xv = (const float4*)xpr + ((size_t)(blockIdx.x * 4 + w) * 2) * 64 + lane;

  for (int t = 0; t < 64; ++t) {
    const float4 xg0 = xv[(size_t)t * 65536];
    const float4 xg1 = xv[(size_t)t * 65536 + 64];

    if (t) {
      if (tid == 0) {
        while (__hip_atomic_load(ctr, __ATOMIC_RELAXED, __HIP_MEMORY_SCOPE_SYSTEM) < 16 * t)
          __builtin_amdgcn_s_sleep(2);
      }
      __syncthreads();
    }

    const unsigned short* hsrc = t ? hx + (size_t)(t - 1) * 65536 : h0;
    const unsigned short* hb = hsrc + (size_t)b * 512 + kq * 8;
    bf16x8 hf[16];
#pragma unroll
    for (int kk = 0; kk < 16; ++kk)
      hf[kk] = *(const bf16x8*)(hb + kk * 32);

    f32x4 acc[2] = {};
#pragma unroll
    for (int kk = 0; kk < 16; ++kk) {
      const int kblk = kk >> 1, cbase = (kk & 1) * 4 + kq;
#pragma unroll
      for (int mi = 0; mi < 2; ++mi) {
        const int m = w * 32 + mi * 16 + fr;
        const int sl = cbase ^ (m & 7);
        const bf16x8 af = *(const bf16x8*)((const char*)&Wsm[kblk][m][0] + sl * 16);
        acc[mi] = __builtin_amdgcn_mfma_f32_16x16x32_bf16(af, hf[kk], acc[mi], 0, 0, 0);
      }
    }

#pragma unroll
    for (int mi = 0; mi < 2; ++mi) {
      const int d = d0 + mi * 4;
      const float4 xg = mi ? xg1 : xg0;
      const float iv = acc[mi][0] + xg.x;
      const float fv = acc[mi][1] + xg.y;
      const float gv = acc[mi][2] + xg.z;
      const float ov = acc[mi][3] + xg.w;
      const float c = fsig(fv) * c_r[mi] + fsig(iv) * ftanh(gv);
      c_r[mi] = c;
      const unsigned short hn = f2bf(fsig(ov) * ftanh(c));
      __hip_atomic_store(&hx[(size_t)t * 65536 + b * 512 + d], hn,
                         __ATOMIC_RELAXED, __HIP_MEMORY_SCOPE_SYSTEM);
      hout[((size_t)b * 64 + t) * ldho + d] = hn;
    }

    asm volatile("s_waitcnt vmcnt(0)" ::: "memory");
    __syncthreads();
    if (tid == 0)
      __hip_atomic_fetch_add(ctr, 1, __ATOMIC_RELAXED, __HIP_MEMORY_SCOPE_SYSTEM);
  }
}

// ================= small helpers =================
struct CastJobs {
  const float* src[15];
  unsigned short* dst[15];
  long nreal[15];
  long cum[16];
  int n;
};

__global__ void cast_multi(CastJobs J) {
  const long total = J.cum[J.n];
  for (long i = (long)blockIdx.x * blockDim.x + threadIdx.x; i < total;
       i += (long)gridDim.x * blockDim.x) {
    int s = 0;
    while (i >= J.cum[s + 1]) ++s;
    const long off = i - J.cum[s];
    J.dst[s][off] = (off < J.nreal[s]) ? f2bf(J.src[s][off]) : (unsigned short)0;
  }
}

// gate-interleaved row permutation of W_ih (+ biases): dst row m = 4d+g <- src row g*512+d
__global__ void perm_wih(const float* __restrict__ W1, const float* __restrict__ W2,
                         const float* __restrict__ b1, const float* __restrict__ b2,
                         unsigned short* __restrict__ R1, unsigned short* __restrict__ R2,
                         float* __restrict__ bp1, float* __restrict__ bp2) {
  const long id = (long)blockIdx.x * blockDim.x + threadIdx.x;  // 3145728 total
  const long n1 = (long)2048 * 512;
  if (id < n1) {
    const int m = (int)(id >> 9), k = (int)(id & 511);
    R1[id] = f2bf(W1[(size_t)((m & 3) * 512 + (m >> 2)) * 512 + k]);
  } else {
    const long j = id - n1;
    const int m = (int)(j >> 10), k = (int)(j & 1023);
    R2[j] = f2bf(W2[(size_t)((m & 3) * 512 + (m >> 2)) * 1024 + k]);
  }
  if (id < 2048) bp1[id] = b1[(id & 3) * 512 + (id >> 2)];
  else if (id < 4096) { const int m = (int)id - 2048; bp2[m] = b2[(m & 3) * 512 + (m >> 2)]; }
}

// transposed bf16 cast of Wv1/Wv2: WvT[a,b] = Wv[b,a]
__global__ void transp_cast(const float* __restrict__ s1, const float* __restrict__ s2,
                            unsigned short* __restrict__ d1, unsigned short* __restrict__ d2) {
  const int e = blockIdx.x * blockDim.x + threadIdx.x;  // 2*262144
  const float* s = (e >> 18) ? s2 : s1;
  unsigned short* d = (e >> 18) ? d2 : d1;
  const int t = e & 262143, a = t >> 9, bb = t & 511;
  d[t] = f2bf(s[bb * 512 + a]);
}

// bc = Wo @ bv + bo  (combined attention bias)
__global__ void bias_comb(const float* __restrict__ Wo1, const float* __restrict__ bv1,
                          const float* __restrict__ bo1,
                          const float* __restrict__ Wo2, const float* __restrict__ bv2,
                          const float* __restrict__ bo2,
                          float* __restrict__ bc1, float* __restrict__ bc2) {
  const int i = threadIdx.x;  // 512 threads, 2 blocks
  const float* Wo = blockIdx.x ? Wo2 : Wo1;
  const float* bv = blockIdx.x ? bv2 : bv1;
  const float* bo = blockIdx.x ? bo2 : bo1;
  float* bc = blockIdx.x ? bc2 : bc1;
  float s = bo[i];
  for (int k = 0; k < 512; ++k) s += Wo[i * 512 + k] * bv[k];
  bc[i] = s;
}

__global__ void concat_bias(const float* a, const float* b, const float* c, const float* d,
                            float* o) {
  const int i = blockIdx.x * blockDim.x + threadIdx.x;  // 2048
  const float* s[4] = {a, b, c, d};
  o[i] = s[i >> 9][i & 511];
}

__global__ void gather_rows(const int* __restrict__ ix, const unsigned short* __restrict__ emb,
                            unsigned short* __restrict__ x) {
  const int row = blockIdx.x;
  const int e = ix[row];
  const uint4* s = (const uint4*)(emb + (size_t)e * 512);
  uint4* d = (uint4*)(x + (size_t)row * 512);
  d[threadIdx.x] = s[threadIdx.x];
}

// ================= host =================
extern "C" void kernel_launch(void* const* d_in, const int* in_sizes, int n_in,
                              void* d_out, int out_size, void* d_ws, size_t ws_size,
                              hipStream_t stream) {
  (void)in_sizes; (void)n_in; (void)out_size; (void)ws_size;
  const float* img    = (const float*)d_in[0];
  const int*   ix     = (const int*)d_in[1];
  const float* emb    = (const float*)d_in[2];
  const float* Wih1f  = (const float*)d_in[3];
  const float* bih1   = (const float*)d_in[4];
  const float* Wic1f  = (const float*)d_in[5];
  const float* bic1   = (const float*)d_in[6];
  const float* Wih2f  = (const float*)d_in[7];
  const float* bih2   = (const float*)d_in[8];
  const float* Wic2f  = (const float*)d_in[9];
  const float* bic2   = (const float*)d_in[10];
  const float* Wihl1  = (const float*)d_in[11];
  const float* Whhl1  = (const float*)d_in[12];
  const float* b1     = (const float*)d_in[13];
  const float* Wihl2  = (const float*)d_in[14];
  const float* Whhl2  = (const float*)d_in[15];
  const float* b2     = (const float*)d_in[16];
  const float* Wv1    = (const float*)d_in[17];
  const float* bv1    = (const float*)d_in[18];
  const float* Wo1    = (const float*)d_in[19];
  const float* bo1    = (const float*)d_in[20];
  const float* Wv2    = (const float*)d_in[21];
  const float* bv2    = (const float*)d_in[22];
  const float* Wo2    = (const float*)d_in[23];
  const float* bo2    = (const float*)d_in[24];
  const float* Wlog   = (const float*)d_in[25];
  const float* blog   = (const float*)d_in[26];
  float* out = (float*)d_out;

  char* p = (char*)d_ws;
  auto al = [&](size_t bytes) { char* r = p; p += (bytes + 255) & ~(size_t)255; return r; };
  unsigned short* emb_b  = (unsigned short*)al((size_t)10000 * 512 * 2);
  unsigned short* Wp1    = (unsigned short*)al((size_t)2048 * 512 * 2);   // perm W_ih1
  unsigned short* Whh1_b = (unsigned short*)al((size_t)2048 * 512 * 2);
  unsigned short* Wp2    = (unsigned short*)al((size_t)2048 * 1024 * 2);  // perm W_ih2
  unsigned short* Whh2_b = (unsigned short*)al((size_t)2048 * 512 * 2);
  unsigned short* WvT1   = (unsigned short*)al((size_t)512 * 512 * 2);
  unsigned short* Wo1_b  = (unsigned short*)al((size_t)512 * 512 * 2);
  unsigned short* WvT2   = (unsigned short*)al((size_t)512 * 512 * 2);
  unsigned short* Wo2_b  = (unsigned short*)al((size_t)512 * 512 * 2);
  unsigned short* Wc1    = (unsigned short*)al((size_t)512 * 512 * 2);    // Wo1@Wv1
  unsigned short* Wc2    = (unsigned short*)al((size_t)512 * 512 * 2);    // Wo2@Wv2
  unsigned short* Wlog_b = (unsigned short*)al((size_t)10240 * 1536 * 2); // zero-padded rows
  unsigned short* Wh1i_b = (unsigned short*)al((size_t)512 * 2048 * 2);   // contiguous 4x:
  unsigned short* Wc1i_b = (unsigned short*)al((size_t)512 * 2048 * 2);   // [2048,2048]
  unsigned short* Wh2i_b = (unsigned short*)al((size_t)512 * 2048 * 2);
  unsigned short* Wc2i_b = (unsigned short*)al((size_t)512 * 2048 * 2);
  unsigned short* img_b  = (unsigned short*)al((size_t)128 * 2048 * 2);
  unsigned short* x_b    = (unsigned short*)al((size_t)8192 * 512 * 2);
  float*          xpr    = (float*)al((size_t)8192 * 2048 * 4);           // 67 MB
  unsigned short* cat1   = (unsigned short*)al((size_t)8192 * 1024 * 2);  // [h1s | attn1]
  unsigned short* out3   = (unsigned short*)al((size_t)8192 * 1536 * 2);  // [h2s | attn1 | attn2]
  unsigned short* hx1    = (unsigned short*)al((size_t)64 * 128 * 512 * 2);
  unsigned short* hx2    = (unsigned short*)al((size_t)64 * 128 * 512 * 2);
  unsigned short* h01    = (unsigned short*)al((size_t)128 * 512 * 2);
  unsigned short* h02    = (unsigned short*)al((size_t)128 * 512 * 2);
  float*          c1st   = (float*)al((size_t)128 * 512 * 4);
  float*          c2st   = (float*)al((size_t)128 * 512 * 4);
  float*          bcat   = (float*)al((size_t)2048 * 4);
  float*          bp1    = (float*)al((size_t)2048 * 4);
  float*          bp2    = (float*)al((size_t)2048 * 4);
  float*          bc1    = (float*)al((size_t)512 * 4);
  float*          bc2    = (float*)al((size_t)512 * 4);
  int*            cnt    = (int*)al(1024);

  hipMemsetAsync(cnt, 0, 1024, stream);

  // ---- f32->bf16 casts ----
  CastJobs J = {};
  auto addjob = [&](const float* s, unsigned short* d, long nreal, long ntot) {
    J.src[J.n] = s; J.dst[J.n] = d; J.nreal[J.n] = nreal;
    J.cum[J.n + 1] = J.cum[J.n] + ntot; ++J.n;
  };
  addjob(img,   img_b,  (long)128 * 2048,   (long)128 * 2048);
  addjob(emb,   emb_b,  (long)10000 * 512,  (long)10000 * 512);
  addjob(Whhl1, Whh1_b, (long)2048 * 512,   (long)2048 * 512);
  addjob(Whhl2, Whh2_b, (long)2048 * 512,   (long)2048 * 512);
  addjob(Wo1,   Wo1_b,  (long)512 * 512,    (long)512 * 512);
  addjob(Wo2,   Wo2_b,  (long)512 * 512,    (long)512 * 512);
  addjob(Wih1f, Wh1i_b, (long)512 * 2048,   (long)512 * 2048);
  addjob(Wic1f, Wc1i_b, (long)512 * 2048,   (long)512 * 2048);
  addjob(Wih2f, Wh2i_b, (long)512 * 2048,   (long)512 * 2048);
  addjob(Wic2f, Wc2i_b, (long)512 * 2048,   (long)512 * 2048);
  addjob(Wlog,  Wlog_b, (long)10000 * 1536, (long)10240 * 1536);
  cast_multi<<<2048, 256, 0, stream>>>(J);

  transp_cast<<<2048, 256, 0, stream>>>(Wv1, Wv2, WvT1, WvT2);
  perm_wih<<<12288, 256, 0, stream>>>(Wihl1, Wihl2, b1, b2, Wp1, Wp2, bp1, bp2);
  concat_bias<<<8, 256, 0, stream>>>(bih1, bic1, bih2, bic2, bcat);
  bias_comb<<<2, 512, 0, stream>>>(Wo1, bv1, bo1, Wo2, bv2, bo2, bc1, bc2);

  // ---- combined attention weights: Wc = Wo @ Wv  (Wc[j,d] = sum_k Wo[j,k] Wv[k,d]) ----
  gemm_nt<1><<<dim3(4, 4), 256, 0, stream>>>(
      Wo1_b, 512, WvT1, 512, Wc1, nullptr, nullptr, nullptr, 512, 0, nullptr, 512, 512);
  gemm_nt<1><<<dim3(4, 4), 256, 0, stream>>>(
      Wo2_b, 512, WvT2, 512, Wc2, nullptr, nullptr, nullptr, 512, 0, nullptr, 512, 512);

  // ---- fused init states ----
  gemm_nt<3><<<dim3(1, 16), 256, 0, stream>>>(
      img_b, 2048, Wh1i_b, 2048, h01, c1st, h02, c2st, 0, 0, bcat, 2048, 2048);

  // ---- x = emb[captions_ix] ----
  gather_rows<<<8192, 64, 0, stream>>>(ix, emb_b, x_b);

  // ---- xp1 = Wp1 @ x^T (+bp1), straight into xpr layout ----
  gemm_nt<2><<<dim3(16, 64), 256, 0, stream>>>(
      Wp1, 512, x_b, 512, xpr, nullptr, nullptr, nullptr, 0, 0, bp1, 512, 8192);

  // ---- LSTM1 (one kernel) -> h1s into cat1 cols [0,512) ----
  lstm_seq<<<128, 256, 0, stream>>>(Whh1_b, h01, c1st, xpr, hx1, cat1, 1024, cnt);

  // ---- attn1 = h1s @ Wc1^T + bc1 -> cat1 cols [512,1024) and out3 cols [512,1024) ----
  gemm_nt<1><<<dim3(64, 4), 256, 0, stream>>>(
      cat1, 1024, Wc1, 512, cat1 + 512, out3 + 512, nullptr, nullptr, 1024, 1536, bc1, 512, 512);

  // ---- xp2 = Wp2 @ [h1s|attn1]^T (+bp2) ----
  gemm_nt<2><<<dim3(16, 64), 256, 0, stream>>>(
      Wp2, 1024, cat1, 1024, xpr, nullptr, nullptr, nullptr, 0, 0, bp2, 1024, 8192);

  // ---- LSTM2 -> h2s into out3 cols [0,512) ----
  lstm_seq<<<128, 256, 0, stream>>>(Whh2_b, h02, c2st, xpr, hx2, out3, 1536, cnt + 128);

  // ---- attn2 = h2s @ Wc2^T + bc2 -> out3 cols [1024,1536) ----
  gemm_nt<1><<<dim3(64, 4), 256, 0, stream>>>(
      out3, 1536, Wc2, 512, out3 + 1024, nullptr, nullptr, nullptr, 1536, 0, bc2, 512, 512);

  // ---- logits = out3 @ W_logits^T + b_logits  (256^2 pipelined GEMM) ----
  gemm256<<<dim3(32, 40), 512, 0, stream>>>(
      out3, 1536, Wlog_b, 1536, out, 10000, blog, 1536, 10000);
}

// Round 6
// 1164.379 us; speedup vs baseline: 3.8951x; 1.1661x over previous
//
#include <hip/hip_runtime.h>
#include <stdint.h>

#define DEV __device__ __forceinline__

typedef short bf16x8 __attribute__((ext_vector_type(8)));
typedef float f32x4 __attribute__((ext_vector_type(4)));

DEV unsigned short f2bf(float f) {
  union { float f; uint32_t u; } v; v.f = f;
  return (unsigned short)((v.u + 0x7fffu + ((v.u >> 16) & 1u)) >> 16);
}
DEV float bf2f(unsigned short u) {
  union { uint32_t u; float f; } v; v.u = (uint32_t)u << 16; return v.f;
}

DEV float fsig(float x) { return 1.f / (1.f + __expf(-x)); }
DEV float ftanh(float x) { float e = __expf(2.f * x); return 1.f - 2.f / (e + 1.f); }

DEV void gload16(const void* g, void* lds) {
  __builtin_amdgcn_global_load_lds(
      (const __attribute__((address_space(1))) int*)(uintptr_t)g,
      (__attribute__((address_space(3))) int*)(uintptr_t)lds, 16, 0, 0);
}

// ================= generic NT GEMM: C[M,N] = A[M,K] * B[N,K]^T + bias =================
// 128x128 tile, BK=32, 4 waves each 64x64.
// MODE 1: bf16 C (+optional C2).  MODE 2: xpr layout (gate-interleaved rows, bias/row).
// MODE 3: init states.  MODE 4: bf16 C = product + bf16 addend (P1, ld ldc2).
template <int MODE>
__global__ __launch_bounds__(256) void gemm_nt(
    const unsigned short* __restrict__ A, int lda,
    const unsigned short* __restrict__ B, int ldb,
    void* __restrict__ P0, void* __restrict__ P1,
    void* __restrict__ P2, void* __restrict__ P3,
    int ldc, int ldc2,
    const float* __restrict__ bias,
    int K, int Nreal)
{
  __shared__ alignas(16) unsigned short Asm[128 * 32];
  __shared__ alignas(16) unsigned short Bsm[128 * 32];
  const int tid = threadIdx.x;
  const int wave = tid >> 6, lane = tid & 63;

  const int gx = gridDim.x;
  const int lin = blockIdx.y * gx + blockIdx.x;
  const int nwg = gx * gridDim.y;
  const int q = nwg >> 3, r = nwg & 7;
  const int xcd = lin & 7, i2 = lin >> 3;
  const int wg = (xcd < r ? xcd * (q + 1) : r * (q + 1) + (xcd - r) * q) + i2;
  const int m0 = (wg % gx) * 128, n0 = (wg / gx) * 128;

  const int wr = wave >> 1, wc = wave & 1;
  f32x4 acc[4][4] = {};

  const int q0 = tid, q1 = tid + 256;
  const unsigned short* Ag0 = A + (size_t)(m0 + (q0 >> 2)) * lda + (q0 & 3) * 8;
  const unsigned short* Ag1 = A + (size_t)(m0 + (q1 >> 2)) * lda + (q1 & 3) * 8;
  const unsigned short* Bg0 = B + (size_t)(n0 + (q0 >> 2)) * ldb + (q0 & 3) * 8;
  const unsigned short* Bg1 = B + (size_t)(n0 + (q1 >> 2)) * ldb + (q1 & 3) * 8;
  char* As0 = (char*)Asm + wave * 1024;  char* As1 = As0 + 4096;
  char* Bs0 = (char*)Bsm + wave * 1024;  char* Bs1 = Bs0 + 4096;

  const int ra = wr * 64 + (lane & 15);
  const int rb = wc * 64 + (lane & 15);
  const int kb = (lane >> 4) * 16;

  for (int k0 = 0; k0 < K; k0 += 32) {
    gload16(Ag0 + k0, As0);
    gload16(Ag1 + k0, As1);
    gload16(Bg0 + k0, Bs0);
    gload16(Bg1 + k0, Bs1);
    __syncthreads();
    bf16x8 af[4], bfr[4];
#pragma unroll
    for (int i = 0; i < 4; ++i)
      af[i] = *(const bf16x8*)((const char*)Asm + (ra + i * 16) * 64 + kb);
#pragma unroll
    for (int i = 0; i < 4; ++i)
      bfr[i] = *(const bf16x8*)((const char*)Bsm + (rb + i * 16) * 64 + kb);
#pragma unroll
    for (int mi = 0; mi < 4; ++mi)
#pragma unroll
      for (int ni = 0; ni < 4; ++ni)
        acc[mi][ni] = __builtin_amdgcn_mfma_f32_16x16x32_bf16(af[mi], bfr[ni], acc[mi][ni], 0, 0, 0);
    __syncthreads();
  }

  const int row0 = m0 + wr * 64 + (lane >> 4) * 4;
  const int col0 = n0 + wc * 64 + (lane & 15);

  if constexpr (MODE == 2) {
#pragma unroll
    for (int mi = 0; mi < 4; ++mi) {
      const int rowb = row0 + mi * 16;       // multiple of 4
      const int dd = rowb >> 2;
      const float4 b4 = *(const float4*)&bias[rowb];
#pragma unroll
      for (int ni = 0; ni < 4; ++ni) {
        const int col = col0 + ni * 16;
        const int tt = col & 63, bb = col >> 6;
        float4 v;
        v.x = acc[mi][ni][0] + b4.x;
        v.y = acc[mi][ni][1] + b4.y;
        v.z = acc[mi][ni][2] + b4.z;
        v.w = acc[mi][ni][3] + b4.w;
        const int wgid = (bb >> 4) * 16 + (dd >> 5);
        const int ww = (dd >> 3) & 3, mi2 = (dd >> 2) & 1, ln = (dd & 3) * 16 + (bb & 15);
        ((float4*)P0)[((((size_t)tt * 128 + wgid) * 4 + ww) * 2 + mi2) * 64 + ln] = v;
      }
    }
    return;
  }

#pragma unroll
  for (int mi = 0; mi < 4; ++mi) {
#pragma unroll
    for (int ni = 0; ni < 4; ++ni) {
      const int col = col0 + ni * 16;
      if (col >= Nreal) continue;
      const float bs = bias ? bias[col] : 0.f;
#pragma unroll
      for (int rr = 0; rr < 4; ++rr) {
        const int row = row0 + mi * 16 + rr;
        const float v = acc[mi][ni][rr] + bs;
        if constexpr (MODE == 1) {
          ((unsigned short*)P0)[(size_t)row * ldc + col] = f2bf(v);
          if (P1) ((unsigned short*)P1)[(size_t)row * ldc2 + col] = f2bf(v);
        } else if constexpr (MODE == 4) {
          const unsigned short ad = ((const unsigned short*)P1)[(size_t)row * ldc2 + col];
          ((unsigned short*)P0)[(size_t)row * ldc + col] = f2bf(v + bf2f(ad));
        } else {  // MODE 3
          const int seg = col >> 9, cc = col & 511;
          if (seg == 0)      ((unsigned short*)P0)[(size_t)row * 512 + cc] = f2bf(v);
          else if (seg == 1) ((float*)P1)[(size_t)row * 512 + cc] = v;
          else if (seg == 2) ((unsigned short*)P2)[(size_t)row * 512 + cc] = f2bf(v);
          else               ((float*)P3)[(size_t)row * 512 + cc] = v;
        }
      }
    }
  }
}

// ============ 256x256 tile GEMM, BK=64, counted vmcnt pipeline, NT C-stores ============
__global__ __launch_bounds__(512, 2) void gemm256(
    const unsigned short* __restrict__ A, int lda,
    const unsigned short* __restrict__ B, int ldb,
    float* __restrict__ C, int ldc,
    const float* __restrict__ bias, int K, int Nreal)
{
  __shared__ alignas(16) unsigned short Lds[2][2][16384];
  const int tid = threadIdx.x;
  const int wave = tid >> 6, lane = tid & 63;
  const int fr = lane & 15, kq = lane >> 4;

  const int gx = gridDim.x;
  const int lin = blockIdx.y * gx + blockIdx.x;
  const int nwg = gx * gridDim.y;
  const int q8 = nwg >> 3, r8 = nwg & 7;
  const int xcd = lin & 7, i2 = lin >> 3;
  const int wg = (xcd < r8 ? xcd * (q8 + 1) : r8 * (q8 + 1) + (xcd - r8) * q8) + i2;
  const int m0 = (wg % gx) * 256, n0 = (wg / gx) * 256;

  const int wr = wave >> 2, wc = wave & 3;

  const unsigned short* srcA[4];
  const unsigned short* srcB[4];
  int dstO[4];
#pragma unroll
  for (int s = 0; s < 4; ++s) {
    const int c = tid + s * 512;
    const int row = c >> 3, qp = (c & 7) ^ (row & 7);
    srcA[s] = A + (size_t)(m0 + row) * lda + qp * 8;
    srcB[s] = B + (size_t)(n0 + row) * ldb + qp * 8;
    dstO[s] = (wave * 64 + s * 512) * 16;
  }

  const int NT = K >> 6;
#define STAGE256(kt, buf)                                            \
  {                                                                  \
    _Pragma("unroll")                                                \
    for (int s = 0; s < 4; ++s)                                      \
      gload16(srcA[s] + (kt) * 64, (char*)&Lds[buf][0][0] + dstO[s]);\
    _Pragma("unroll")                                                \
    for (int s = 0; s < 4; ++s)                                      \
      gload16(srcB[s] + (kt) * 64, (char*)&Lds[buf][1][0] + dstO[s]);\
  }
  STAGE256(0, 0);
  STAGE256(1, 1);

  f32x4 acc[8][4] = {};
  const int slot0 = (kq ^ (fr & 7)) * 16;

  for (int kt = 0; kt < NT; ++kt) {
    asm volatile("s_waitcnt vmcnt(8)" ::: "memory");
    __builtin_amdgcn_sched_barrier(0);
    __builtin_amdgcn_s_barrier();
    __builtin_amdgcn_sched_barrier(0);
    const char* bufA = (const char*)&Lds[kt & 1][0][0];
    const char* bufB = (const char*)&Lds[kt & 1][1][0];
    bf16x8 Bf[4][2];
#pragma unroll
    for (int n = 0; n < 4; ++n) {
      const char* bb = bufB + (wc * 64 + n * 16 + fr) * 128;
      Bf[n][0] = *(const bf16x8*)(bb + slot0);
      Bf[n][1] = *(const bf16x8*)(bb + (slot0 ^ 64));
    }
#pragma unroll
    for (int q = 0; q < 4; ++q) {
      bf16x8 Af[2][2];
#pragma unroll
      for (int m2 = 0; m2 < 2; ++m2) {
        const char* ab = bufA + (wr * 128 + q * 32 + m2 * 16 + fr) * 128;
        Af[m2][0] = *(const bf16x8*)(ab + slot0);
        Af[m2][1] = *(const bf16x8*)(ab + (slot0 ^ 64));
      }
      __builtin_amdgcn_s_setprio(1);
#pragma unroll
      for (int m2 = 0; m2 < 2; ++m2)
#pragma unroll
        for (int n = 0; n < 4; ++n) {
          acc[q * 2 + m2][n] = __builtin_amdgcn_mfma_f32_16x16x32_bf16(
              Af[m2][0], Bf[n][0], acc[q * 2 + m2][n], 0, 0, 0);
          acc[q * 2 + m2][n] = __builtin_amdgcn_mfma_f32_16x16x32_bf16(
              Af[m2][1], Bf[n][1], acc[q * 2 + m2][n], 0, 0, 0);
        }
      __builtin_amdgcn_s_setprio(0);
    }
    __builtin_amdgcn_sched_barrier(0);
    __builtin_amdgcn_s_barrier();
    __builtin_amdgcn_sched_barrier(0);
    const int kn = (kt + 2 < NT) ? kt + 2 : 0;
    STAGE256(kn, kt & 1);
  }

#pragma unroll
  for (int mf = 0; mf < 8; ++mf) {
    const int row = m0 + wr * 128 + mf * 16 + kq * 4;
#pragma unroll
    for (int n = 0; n < 4; ++n) {
      const int col = n0 + wc * 64 + n * 16 + fr;
      if (col < Nreal) {
        const float bs = bias[col];
#pragma unroll
        for (int rr = 0; rr < 4; ++rr)
          __builtin_nontemporal_store(acc[mf][n][rr] + bs,
                                      &C[(size_t)(row + rr) * ldc + col]);
      }
    }
  }
#undef STAGE256
}

// ================= fused persistent LSTM1+LSTM2 (256 WGs, 1/CU) =================
// WGs 0..127: LSTM1 (g=wg>>4 batch-group, s=wg&15 d-slice; Whh1 slice in LDS; xpr input).
// WGs 128..255: LSTM2 lagged 1 step: gates2 = Whh2@h2(t-1) [LDS] + Weff2@h1(t) [global
// A-frag stream, L2-resident] + beff2. h exchange via per-step LLC regions (system-scope
// stores, first-touch plain reads) + per-group system-scope counters. c in registers.
__global__ __launch_bounds__(256, 1) void lstm_fused(
    const unsigned short* __restrict__ Whh1, const unsigned short* __restrict__ Whh2,
    const unsigned short* __restrict__ Weff2r,  // [16 s][16 kk][2 mi][256 tid][8] bf16
    const unsigned short* __restrict__ h01, const unsigned short* __restrict__ h02,
    const float* __restrict__ c1st, const float* __restrict__ c2st,
    const float* __restrict__ xpr,              // [64][128][4][2][64][4] f32
    const float* __restrict__ beff2,            // [2048] gate-interleaved
    unsigned short* __restrict__ hx1, unsigned short* __restrict__ hx2,
    unsigned short* __restrict__ hcat,          // [8192][1024]: [h2s | h1s]
    int* __restrict__ cnt)                      // cnt1 = cnt, cnt2 = cnt + 128
{
  __shared__ unsigned short Wsm[8][128][64];
  const int tid = threadIdx.x;
  const bool role2 = blockIdx.x >= 128;
  const int wg = role2 ? blockIdx.x - 128 : blockIdx.x;
  const int g = wg >> 4, s = wg & 15;
  const int w = tid >> 6, lane = tid & 63, fr = lane & 15, kq = lane >> 4;

  // ---- stage Whh slice into LDS (slot = chunk ^ (m&7)) ----
  {
    const unsigned short* Whh = role2 ? Whh2 : Whh1;
    const int m = tid >> 1;
    const int row = (m & 3) * 512 + s * 32 + (m >> 2);
    const unsigned short* src = Whh + (size_t)row * 512 + (tid & 1) * 256;
#pragma unroll 4
    for (int cc = 0; cc < 32; ++cc) {
      const int k = (tid & 1) * 256 + cc * 8;
      uint4 v = *(const uint4*)(src + cc * 8);
      const int kblk = k >> 6, c = (k & 63) >> 3, sl = c ^ (m & 7);
      *(uint4*)((char*)&Wsm[kblk][m][0] + sl * 16) = v;
    }
  }

  const int b = g * 16 + fr;
  const int d0 = s * 32 + w * 8 + kq;
  const float* c0 = role2 ? c2st : c1st;
  float c_r[2];
  c_r[0] = c0[b * 512 + d0];
  c_r[1] = c0[b * 512 + d0 + 4];
  __syncthreads();

  int* ctr1 = cnt + g * 16;
  int* ctr2 = cnt + 128 + g * 16;
  const float4* xv = (const float4*)xpr + ((size_t)(wg * 4 + w) * 2) * 64 + lane;
  float4 be0 = {0, 0, 0, 0}, be1 = {0, 0, 0, 0};
  if (role2) {
    be0 = *(const float4*)(beff2 + s * 128 + w * 32 + kq * 4);
    be1 = *(const float4*)(beff2 + s * 128 + w * 32 + 16 + kq * 4);
  }
  unsigned short* hxown = role2 ? hx2 : hx1;
  unsigned short* hout = role2 ? hcat : hcat + 512;
  const unsigned short* hinit = role2 ? h02 : h01;

  for (int t = 0; t < 64; ++t) {
    float4 xg0, xg1;
    if (role2) { xg0 = be0; xg1 = be1; }
    else { xg0 = xv[(size_t)t * 65536]; xg1 = xv[(size_t)t * 65536 + 64]; }

    // ---- waits ----
    if (role2) {
      if (tid == 0) {
        while (__hip_atomic_load(ctr1, __ATOMIC_RELAXED, __HIP_MEMORY_SCOPE_SYSTEM) < 16 * (t + 1))
          __builtin_amdgcn_s_sleep(1);
        if (t)
          while (__hip_atomic_load(ctr2, __ATOMIC_RELAXED, __HIP_MEMORY_SCOPE_SYSTEM) < 16 * t)
            __builtin_amdgcn_s_sleep(1);
      }
      __syncthreads();
    } else if (t) {
      if (tid == 0) {
        while (__hip_atomic_load(ctr1, __ATOMIC_RELAXED, __HIP_MEMORY_SCOPE_SYSTEM) < 16 * t)
          __builtin_amdgcn_s_sleep(1);
      }
      __syncthreads();
    }

    // ---- own-h fragments (16 KB, fresh LLC lines) ----
    const unsigned short* hsrc = t ? hxown + (size_t)(t - 1) * 65536 : hinit;
    const unsigned short* hb = hsrc + (size_t)b * 512 + kq * 8;
    bf16x8 hf[16];
#pragma unroll
    for (int kk = 0; kk < 16; ++kk)
      hf[kk] = *(const bf16x8*)(hb + kk * 32);

    f32x4 acc[2] = {};
    // ---- phase A: Whh @ h_own (LDS) ----
#pragma unroll
    for (int kk = 0; kk < 16; ++kk) {
      const int kblk = kk >> 1, cbase = (kk & 1) * 4 + kq;
#pragma unroll
      for (int mi = 0; mi < 2; ++mi) {
        const int m = w * 32 + mi * 16 + fr;
        const int sl = cbase ^ (m & 7);
        const bf16x8 af = *(const bf16x8*)((const char*)&Wsm[kblk][m][0] + sl * 16);
        acc[mi] = __builtin_amdgcn_mfma_f32_16x16x32_bf16(af, hf[kk], acc[mi], 0, 0, 0);
      }
    }

    // ---- phase B (LSTM2 only): Weff2 @ h1(t) ----
    if (role2) {
      const unsigned short* h1b = hx1 + (size_t)t * 65536 + (size_t)b * 512 + kq * 8;
      bf16x8 hf1[16];
#pragma unroll
      for (int kk = 0; kk < 16; ++kk)
        hf1[kk] = *(const bf16x8*)(h1b + kk * 32);
      const bf16x8* wr = (const bf16x8*)Weff2r + (size_t)s * 32 * 256 + tid;
#pragma unroll
      for (int kk = 0; kk < 16; ++kk) {
#pragma unroll
        for (int mi = 0; mi < 2; ++mi) {
          const bf16x8 af = wr[(kk * 2 + mi) * 256];
          acc[mi] = __builtin_amdgcn_mfma_f32_16x16x32_bf16(af, hf1[kk], acc[mi], 0, 0, 0);
        }
      }
    }

    // ---- gates (lane-local) + stores ----
#pragma unroll
    for (int mi = 0; mi < 2; ++mi) {
      const int d = d0 + mi * 4;
      const float4 xg = mi ? xg1 : xg0;
      const float iv = acc[mi][0] + xg.x;
      const float fv = acc[mi][1] + xg.y;
      const float gv = acc[mi][2] + xg.z;
      const float ov = acc[mi][3] + xg.w;
      const float c = fsig(fv) * c_r[mi] + fsig(iv) * ftanh(gv);
      c_r[mi] = c;
      const unsigned short hn = f2bf(fsig(ov) * ftanh(c));
      __hip_atomic_store(&hxown[(size_t)t * 65536 + b * 512 + d], hn,
                         __ATOMIC_RELAXED, __HIP_MEMORY_SCOPE_SYSTEM);
      hout[((size_t)b * 64 + t) * 1024 + d] = hn;
    }

    asm volatile("s_waitcnt vmcnt(0)" ::: "memory");
    __syncthreads();
    if (tid == 0)
      __hip_atomic_fetch_add(role2 ? ctr2 : ctr1, 1,
                             __ATOMIC_RELAXED, __HIP_MEMORY_SCOPE_SYSTEM);
  }
}

// ================= small helpers =================
struct CastJobs {
  const float* src[15];
  unsigned short* dst[15];
  long nreal[15];
  long cum[16];
  int n;
};

__global__ void cast_multi(CastJobs J) {
  const long total = J.cum[J.n];
  for (long i = (long)blockIdx.x * blockDim.x + threadIdx.x; i < total;
       i += (long)gridDim.x * blockDim.x) {
    int s = 0;
    while (i >= J.cum[s + 1]) ++s;
    const long off = i - J.cum[s];
    J.dst[s][off] = (off < J.nreal[s]) ? f2bf(J.src[s][off]) : (unsigned short)0;
  }
}

// gate-interleaved row permutation of W_ih (+ biases): dst row m = 4d+g <- src row g*512+d
__global__ void perm_wih(const float* __restrict__ W1, const float* __restrict__ W2,
                         const float* __restrict__ b1, const float* __restrict__ b2,
                         unsigned short* __restrict__ R1, unsigned short* __restrict__ R2,
                         float* __restrict__ bp1, float* __restrict__ bp2) {
  const long id = (long)blockIdx.x * blockDim.x + threadIdx.x;
  const long n1 = (long)2048 * 512;
  if (id < n1) {
    const int m = (int)(id >> 9), k = (int)(id & 511);
    R1[id] = f2bf(W1[(size_t)((m & 3) * 512 + (m >> 2)) * 512 + k]);
  } else {
    const long j = id - n1;
    const int m = (int)(j >> 10), k = (int)(j & 1023);
    R2[j] = f2bf(W2[(size_t)((m & 3) * 512 + (m >> 2)) * 1024 + k]);
  }
  if (id < 2048) bp1[id] = b1[(id & 3) * 512 + (id >> 2)];
  else if (id < 4096) { const int m = (int)id - 2048; bp2[m] = b2[(m & 3) * 512 + (m >> 2)]; }
}

// transposed bf16 cast of Wv1/Wv2
__global__ void transp_cast(const float* __restrict__ s1, const float* __restrict__ s2,
                            unsigned short* __restrict__ d1, unsigned short* __restrict__ d2) {
  const int e = blockIdx.x * blockDim.x + threadIdx.x;
  const float* s = (e >> 18) ? s2 : s1;
  unsigned short* d = (e >> 18) ? d2 : d1;
  const int t = e & 262143, a = t >> 9, bb = t & 511;
  d[t] = f2bf(s[bb * 512 + a]);
}

// bc = Wo @ bv + bo
__global__ void bias_comb(const float* __restrict__ Wo1, const float* __restrict__ bv1,
                          const float* __restrict__ bo1,
                          const float* __restrict__ Wo2, const float* __restrict__ bv2,
                          const float* __restrict__ bo2,
                          float* __restrict__ bc1, float* __restrict__ bc2) {
  const int i = threadIdx.x;
  const float* Wo = blockIdx.x ? Wo2 : Wo1;
  const float* bv = blockIdx.x ? bv2 : bv1;
  const float* bo = blockIdx.x ? bo2 : bo1;
  float* bc = blockIdx.x ? bc2 : bc1;
  float s = bo[i];
  for (int k = 0; k < 512; ++k) s += Wo[i * 512 + k] * bv[k];
  bc[i] = s;
}

__global__ void concat_bias(const float* a, const float* b, const float* c, const float* d,
                            float* o) {
  const int i = blockIdx.x * blockDim.x + threadIdx.x;
  const float* s[4] = {a, b, c, d};
  o[i] = s[i >> 9][i & 511];
}

__global__ void gather_rows(const int* __restrict__ ix, const unsigned short* __restrict__ emb,
                            unsigned short* __restrict__ x) {
  const int row = blockIdx.x;
  const int e = ix[row];
  const uint4* s = (const uint4*)(emb + (size_t)e * 512);
  uint4* d = (uint4*)(x + (size_t)row * 512);
  d[threadIdx.x] = s[threadIdx.x];
}

// Weff2 [2048][512] bf16 -> A-frag stream [16 s][16 kk][2 mi][256 tid][8]
__global__ void reorder_wbf(const unsigned short* __restrict__ W,
                            unsigned short* __restrict__ R) {
  const int id = blockIdx.x * blockDim.x + threadIdx.x;  // 131072
  const int tid = id & 255, mi = (id >> 8) & 1, kk = (id >> 9) & 15, s = id >> 13;
  const int w = tid >> 6, lane = tid & 63, fr = lane & 15, kq = lane >> 4;
  const int row = s * 128 + w * 32 + mi * 16 + fr;
  const int col = kk * 32 + kq * 8;
  *((uint4*)R + id) = *(const uint4*)(W + (size_t)row * 512 + col);
}

// blcat[j] = blog[j] + Wl_a1[j,:]·bc1 + Wl_a2[j,:]·bc2   (bf16 Wlog rows)
__global__ void bias_blcat(const unsigned short* __restrict__ Wl, const float* __restrict__ blog,
                           const float* __restrict__ bc1, const float* __restrict__ bc2,
                           float* __restrict__ blcat) {
  const int j = blockIdx.x * 4 + (threadIdx.x >> 6);  // grid 2500 -> j < 10000
  const int lane = threadIdx.x & 63;
  const unsigned short* row = Wl + (size_t)j * 1536;
  float sum = 0.f;
  for (int k = lane; k < 512; k += 64) {
    sum += bf2f(row[512 + k]) * bc1[k];
    sum += bf2f(row[1024 + k]) * bc2[k];
  }
#pragma unroll
  for (int m = 32; m; m >>= 1) sum += __shfl_xor(sum, m, 64);
  if (lane == 0) blcat[j] = blog[j] + sum;
}

// beff2[m] = bp2[m] + Wp2a[m,:]·bc1
__global__ void bias_beff2(const unsigned short* __restrict__ Wp2, const float* __restrict__ bp2,
                           const float* __restrict__ bc1, float* __restrict__ beff2) {
  const int m = blockIdx.x * 4 + (threadIdx.x >> 6);  // grid 512 -> m < 2048
  const int lane = threadIdx.x & 63;
  const unsigned short* row = Wp2 + (size_t)m * 1024 + 512;
  float sum = 0.f;
  for (int k = lane; k < 512; k += 64) sum += bf2f(row[k]) * bc1[k];
#pragma unroll
  for (int mm = 32; mm; mm >>= 1) sum += __shfl_xor(sum, mm, 64);
  if (lane == 0) beff2[m] = bp2[m] + sum;
}

// ================= host =================
extern "C" void kernel_launch(void* const* d_in, const int* in_sizes, int n_in,
                              void* d_out, int out_size, void* d_ws, size_t ws_size,
                              hipStream_t stream) {
  (void)in_sizes; (void)n_in; (void)out_size; (void)ws_size;
  const float* img    = (const float*)d_in[0];
  const int*   ix     = (const int*)d_in[1];
  const float* emb    = (const float*)d_in[2];
  const float* Wih1f  = (const float*)d_in[3];
  const float* bih1   = (const float*)d_in[4];
  const float* Wic1f  = (const float*)d_in[5];
  const float* bic1   = (const float*)d_in[6];
  const float* Wih2f  = (const float*)d_in[7];
  const float* bih2   = (const float*)d_in[8];
  const float* Wic2f  = (const float*)d_in[9];
  const float* bic2   = (const float*)d_in[10];
  const float* Wihl1  = (const float*)d_in[11];
  const float* Whhl1  = (const float*)d_in[12];
  const float* b1     = (const float*)d_in[13];
  const float* Wihl2  = (const float*)d_in[14];
  const float* Whhl2  = (const float*)d_in[15];
  const float* b2     = (const float*)d_in[16];
  const float* Wv1    = (const float*)d_in[17];
  const float* bv1    = (const float*)d_in[18];
  const float* Wo1    = (const float*)d_in[19];
  const float* bo1    = (const float*)d_in[20];
  const float* Wv2    = (const float*)d_in[21];
  const float* bv2    = (const float*)d_in[22];
  const float* Wo2    = (const float*)d_in[23];
  const float* bo2    = (const float*)d_in[24];
  const float* Wlog   = (const float*)d_in[25];
  const float* blog   = (const float*)d_in[26];
  float* out = (float*)d_out;

  char* p = (char*)d_ws;
  auto al = [&](size_t bytes) { char* r = p; p += (bytes + 255) & ~(size_t)255; return r; };
  unsigned short* emb_b  = (unsigned short*)al((size_t)10000 * 512 * 2);
  unsigned short* Wp1    = (unsigned short*)al((size_t)2048 * 512 * 2);
  unsigned short* Whh1_b = (unsigned short*)al((size_t)2048 * 512 * 2);
  unsigned short* Wp2    = (unsigned short*)al((size_t)2048 * 1024 * 2);
  unsigned short* Whh2_b = (unsigned short*)al((size_t)2048 * 512 * 2);
  unsigned short* WvT1   = (unsigned short*)al((size_t)512 * 512 * 2);
  unsigned short* Wo1_b  = (unsigned short*)al((size_t)512 * 512 * 2);
  unsigned short* WvT2   = (unsigned short*)al((size_t)512 * 512 * 2);
  unsigned short* Wo2_b  = (unsigned short*)al((size_t)512 * 512 * 2);
  unsigned short* Wc1T   = (unsigned short*)al((size_t)512 * 512 * 2);   // (Wo1@Wv1)^T
  unsigned short* Wc2T   = (unsigned short*)al((size_t)512 * 512 * 2);   // (Wo2@Wv2)^T
  unsigned short* Wlog_b = (unsigned short*)al((size_t)10240 * 1536 * 2);
  unsigned short* Wcat   = (unsigned short*)al((size_t)10240 * 1024 * 2); // [Aeff|Beff]
  unsigned short* Weff2  = (unsigned short*)al((size_t)2048 * 512 * 2);
  unsigned short* Weff2r = (unsigned short*)al((size_t)2048 * 512 * 2);
  unsigned short* Wh1i_b = (unsigned short*)al((size_t)512 * 2048 * 2);
  unsigned short* Wc1i_b = (unsigned short*)al((size_t)512 * 2048 * 2);
  unsigned short* Wh2i_b = (unsigned short*)al((size_t)512 * 2048 * 2);
  unsigned short* Wc2i_b = (unsigned short*)al((size_t)512 * 2048 * 2);
  unsigned short* img_b  = (unsigned short*)al((size_t)128 * 2048 * 2);
  unsigned short* x_b    = (unsigned short*)al((size_t)8192 * 512 * 2);
  float*          xpr    = (float*)al((size_t)8192 * 2048 * 4);
  unsigned short* hcat   = (unsigned short*)al((size_t)8192 * 1024 * 2);  // [h2s | h1s]
  unsigned short* hx1    = (unsigned short*)al((size_t)64 * 128 * 512 * 2);
  unsigned short* hx2    = (unsigned short*)al((size_t)64 * 128 * 512 * 2);
  unsigned short* h01    = (unsigned short*)al((size_t)128 * 512 * 2);
  unsigned short* h02    = (unsigned short*)al((size_t)128 * 512 * 2);
  float*          c1st   = (float*)al((size_t)128 * 512 * 4);
  float*          c2st   = (float*)al((size_t)128 * 512 * 4);
  float*          bcat   = (float*)al((size_t)2048 * 4);
  float*          bp1    = (float*)al((size_t)2048 * 4);
  float*          bp2    = (float*)al((size_t)2048 * 4);
  float*          bc1    = (float*)al((size_t)512 * 4);
  float*          bc2    = (float*)al((size_t)512 * 4);
  float*          beff2  = (float*)al((size_t)2048 * 4);
  float*          blcat  = (float*)al((size_t)10240 * 4);
  int*            cnt    = (int*)al(2048);

  hipMemsetAsync(cnt, 0, 2048, stream);

  // ---- casts ----
  CastJobs J = {};
  auto addjob = [&](const float* s, unsigned short* d, long nreal, long ntot) {
    J.src[J.n] = s; J.dst[J.n] = d; J.nreal[J.n] = nreal;
    J.cum[J.n + 1] = J.cum[J.n] + ntot; ++J.n;
  };
  addjob(img,   img_b,  (long)128 * 2048,   (long)128 * 2048);
  addjob(emb,   emb_b,  (long)10000 * 512,  (long)10000 * 512);
  addjob(Whhl1, Whh1_b, (long)2048 * 512,   (long)2048 * 512);
  addjob(Whhl2, Whh2_b, (long)2048 * 512,   (long)2048 * 512);
  addjob(Wo1,   Wo1_b,  (long)512 * 512,    (long)512 * 512);
  addjob(Wo2,   Wo2_b,  (long)512 * 512,    (long)512 * 512);
  addjob(Wih1f, Wh1i_b, (long)512 * 2048,   (long)512 * 2048);
  addjob(Wic1f, Wc1i_b, (long)512 * 2048,   (long)512 * 2048);
  addjob(Wih2f, Wh2i_b, (long)512 * 2048,   (long)512 * 2048);
  addjob(Wic2f, Wc2i_b, (long)512 * 2048,   (long)512 * 2048);
  addjob(Wlog,  Wlog_b, (long)10000 * 1536, (long)10240 * 1536);
  cast_multi<<<2048, 256, 0, stream>>>(J);

  transp_cast<<<2048, 256, 0, stream>>>(Wv1, Wv2, WvT1, WvT2);
  perm_wih<<<12288, 256, 0, stream>>>(Wihl1, Wihl2, b1, b2, Wp1, Wp2, bp1, bp2);
  concat_bias<<<8, 256, 0, stream>>>(bih1, bic1, bih2, bic2, bcat);
  bias_comb<<<2, 512, 0, stream>>>(Wo1, bv1, bo1, Wo2, bv2, bo2, bc1, bc2);

  // ---- WcT = (Wo@Wv)^T : C[j2,j1] = sum_k Wv[k,j2] Wo[j1,k] ----
  gemm_nt<1><<<dim3(4, 4), 256, 0, stream>>>(
      WvT1, 512, Wo1_b, 512, Wc1T, nullptr, nullptr, nullptr, 512, 0, nullptr, 512, 512);
  gemm_nt<1><<<dim3(4, 4), 256, 0, stream>>>(
      WvT2, 512, Wo2_b, 512, Wc2T, nullptr, nullptr, nullptr, 512, 0, nullptr, 512, 512);

  // ---- Weff2 = Wp2[:, :512] + Wp2[:, 512:] @ WoWv1 ----
  gemm_nt<4><<<dim3(16, 4), 256, 0, stream>>>(
      Wp2 + 512, 1024, Wc1T, 512, Weff2, Wp2, nullptr, nullptr, 512, 1024, nullptr, 512, 512);
  reorder_wbf<<<512, 256, 0, stream>>>(Weff2, Weff2r);
  bias_beff2<<<512, 256, 0, stream>>>(Wp2, bp2, bc1, beff2);

  // ---- Wcat = [ Wl_h2 + Wl_a2@WoWv2 | Wl_a1@WoWv1 ] ----
  gemm_nt<4><<<dim3(80, 4), 256, 0, stream>>>(
      Wlog_b + 1024, 1536, Wc2T, 512, Wcat, Wlog_b, nullptr, nullptr, 1024, 1536,
      nullptr, 512, 512);
  gemm_nt<1><<<dim3(80, 4), 256, 0, stream>>>(
      Wlog_b + 512, 1536, Wc1T, 512, Wcat + 512, nullptr, nullptr, nullptr, 1024, 0,
      nullptr, 512, 512);
  bias_blcat<<<2500, 256, 0, stream>>>(Wlog_b, blog, bc1, bc2, blcat);

  // ---- init states ----
  gemm_nt<3><<<dim3(1, 16), 256, 0, stream>>>(
      img_b, 2048, Wh1i_b, 2048, h01, c1st, h02, c2st, 0, 0, bcat, 2048, 2048);

  // ---- x = emb[captions_ix]; xp1 = Wp1 @ x^T (+bp1) ----
  gather_rows<<<8192, 64, 0, stream>>>(ix, emb_b, x_b);
  gemm_nt<2><<<dim3(16, 64), 256, 0, stream>>>(
      Wp1, 512, x_b, 512, xpr, nullptr, nullptr, nullptr, 0, 0, bp1, 512, 8192);

  // ---- both LSTMs, fused & pipelined ----
  lstm_fused<<<256, 256, 0, stream>>>(
      Whh1_b, Whh2_b, Weff2r, h01, h02, c1st, c2st, xpr, beff2, hx1, hx2, hcat, cnt);

  // ---- logits = hcat @ Wcat^T + blcat ----
  gemm256<<<dim3(32, 40), 512, 0, stream>>>(
      hcat, 1024, Wcat, 1024, out, 10000, blcat, 1024, 10000);
}

// Round 7
// 1059.488 us; speedup vs baseline: 4.2807x; 1.0990x over previous
//
#include <hip/hip_runtime.h>
#include <stdint.h>

#define DEV __device__ __forceinline__

typedef short bf16x8 __attribute__((ext_vector_type(8)));
typedef float f32x4 __attribute__((ext_vector_type(4)));

DEV unsigned short f2bf(float f) {
  union { float f; uint32_t u; } v; v.f = f;
  return (unsigned short)((v.u + 0x7fffu + ((v.u >> 16) & 1u)) >> 16);
}
DEV float bf2f(unsigned short u) {
  union { uint32_t u; float f; } v; v.u = (uint32_t)u << 16; return v.f;
}

DEV float fsig(float x) { return 1.f / (1.f + __expf(-x)); }
DEV float ftanh(float x) { float e = __expf(2.f * x); return 1.f - 2.f / (e + 1.f); }

DEV void gload16(const void* g, void* lds) {
  __builtin_amdgcn_global_load_lds(
      (const __attribute__((address_space(1))) int*)(uintptr_t)g,
      (__attribute__((address_space(3))) int*)(uintptr_t)lds, 16, 0, 0);
}

// ================= generic NT GEMM: C[M,N] = A[M,K] * B[N,K]^T + bias =================
// 128x128 tile, BK=32, 4 waves each 64x64.
// MODE 1: bf16 C (+optional C2).  MODE 2: xpr layout (gate-interleaved rows, bias/row).
// MODE 3: init states.  MODE 4: bf16 C = product + bf16 addend (P1, ld ldc2).
template <int MODE>
__global__ __launch_bounds__(256) void gemm_nt(
    const unsigned short* __restrict__ A, int lda,
    const unsigned short* __restrict__ B, int ldb,
    void* __restrict__ P0, void* __restrict__ P1,
    void* __restrict__ P2, void* __restrict__ P3,
    int ldc, int ldc2,
    const float* __restrict__ bias,
    int K, int Nreal)
{
  __shared__ alignas(16) unsigned short Asm[128 * 32];
  __shared__ alignas(16) unsigned short Bsm[128 * 32];
  const int tid = threadIdx.x;
  const int wave = tid >> 6, lane = tid & 63;

  const int gx = gridDim.x;
  const int lin = blockIdx.y * gx + blockIdx.x;
  const int nwg = gx * gridDim.y;
  const int q = nwg >> 3, r = nwg & 7;
  const int xcd = lin & 7, i2 = lin >> 3;
  const int wg = (xcd < r ? xcd * (q + 1) : r * (q + 1) + (xcd - r) * q) + i2;
  const int m0 = (wg % gx) * 128, n0 = (wg / gx) * 128;

  const int wr = wave >> 1, wc = wave & 1;
  f32x4 acc[4][4] = {};

  const int q0 = tid, q1 = tid + 256;
  const unsigned short* Ag0 = A + (size_t)(m0 + (q0 >> 2)) * lda + (q0 & 3) * 8;
  const unsigned short* Ag1 = A + (size_t)(m0 + (q1 >> 2)) * lda + (q1 & 3) * 8;
  const unsigned short* Bg0 = B + (size_t)(n0 + (q0 >> 2)) * ldb + (q0 & 3) * 8;
  const unsigned short* Bg1 = B + (size_t)(n0 + (q1 >> 2)) * ldb + (q1 & 3) * 8;
  char* As0 = (char*)Asm + wave * 1024;  char* As1 = As0 + 4096;
  char* Bs0 = (char*)Bsm + wave * 1024;  char* Bs1 = Bs0 + 4096;

  const int ra = wr * 64 + (lane & 15);
  const int rb = wc * 64 + (lane & 15);
  const int kb = (lane >> 4) * 16;

  for (int k0 = 0; k0 < K; k0 += 32) {
    gload16(Ag0 + k0, As0);
    gload16(Ag1 + k0, As1);
    gload16(Bg0 + k0, Bs0);
    gload16(Bg1 + k0, Bs1);
    __syncthreads();
    bf16x8 af[4], bfr[4];
#pragma unroll
    for (int i = 0; i < 4; ++i)
      af[i] = *(const bf16x8*)((const char*)Asm + (ra + i * 16) * 64 + kb);
#pragma unroll
    for (int i = 0; i < 4; ++i)
      bfr[i] = *(const bf16x8*)((const char*)Bsm + (rb + i * 16) * 64 + kb);
#pragma unroll
    for (int mi = 0; mi < 4; ++mi)
#pragma unroll
      for (int ni = 0; ni < 4; ++ni)
        acc[mi][ni] = __builtin_amdgcn_mfma_f32_16x16x32_bf16(af[mi], bfr[ni], acc[mi][ni], 0, 0, 0);
    __syncthreads();
  }

  const int row0 = m0 + wr * 64 + (lane >> 4) * 4;
  const int col0 = n0 + wc * 64 + (lane & 15);

  if constexpr (MODE == 2) {
#pragma unroll
    for (int mi = 0; mi < 4; ++mi) {
      const int rowb = row0 + mi * 16;       // multiple of 4
      const int dd = rowb >> 2;
      const float4 b4 = *(const float4*)&bias[rowb];
#pragma unroll
      for (int ni = 0; ni < 4; ++ni) {
        const int col = col0 + ni * 16;
        const int tt = col & 63, bb = col >> 6;
        float4 v;
        v.x = acc[mi][ni][0] + b4.x;
        v.y = acc[mi][ni][1] + b4.y;
        v.z = acc[mi][ni][2] + b4.z;
        v.w = acc[mi][ni][3] + b4.w;
        const int wgid = (bb >> 4) * 16 + (dd >> 5);
        const int ww = (dd >> 3) & 3, mi2 = (dd >> 2) & 1, ln = (dd & 3) * 16 + (bb & 15);
        ((float4*)P0)[((((size_t)tt * 128 + wgid) * 4 + ww) * 2 + mi2) * 64 + ln] = v;
      }
    }
    return;
  }

#pragma unroll
  for (int mi = 0; mi < 4; ++mi) {
#pragma unroll
    for (int ni = 0; ni < 4; ++ni) {
      const int col = col0 + ni * 16;
      if (col >= Nreal) continue;
      const float bs = bias ? bias[col] : 0.f;
#pragma unroll
      for (int rr = 0; rr < 4; ++rr) {
        const int row = row0 + mi * 16 + rr;
        const float v = acc[mi][ni][rr] + bs;
        if constexpr (MODE == 1) {
          ((unsigned short*)P0)[(size_t)row * ldc + col] = f2bf(v);
          if (P1) ((unsigned short*)P1)[(size_t)row * ldc2 + col] = f2bf(v);
        } else if constexpr (MODE == 4) {
          const unsigned short ad = ((const unsigned short*)P1)[(size_t)row * ldc2 + col];
          ((unsigned short*)P0)[(size_t)row * ldc + col] = f2bf(v + bf2f(ad));
        } else {  // MODE 3
          const int seg = col >> 9, cc = col & 511;
          if (seg == 0)      ((unsigned short*)P0)[(size_t)row * 512 + cc] = f2bf(v);
          else if (seg == 1) ((float*)P1)[(size_t)row * 512 + cc] = v;
          else if (seg == 2) ((unsigned short*)P2)[(size_t)row * 512 + cc] = f2bf(v);
          else               ((float*)P3)[(size_t)row * 512 + cc] = v;
        }
      }
    }
  }
}

// ============ 256x256 tile GEMM, BK=64, counted vmcnt pipeline, NT C-stores ============
__global__ __launch_bounds__(512, 2) void gemm256(
    const unsigned short* __restrict__ A, int lda,
    const unsigned short* __restrict__ B, int ldb,
    float* __restrict__ C, int ldc,
    const float* __restrict__ bias, int K, int Nreal)
{
  __shared__ alignas(16) unsigned short Lds[2][2][16384];
  const int tid = threadIdx.x;
  const int wave = tid >> 6, lane = tid & 63;
  const int fr = lane & 15, kq = lane >> 4;

  const int gx = gridDim.x;
  const int lin = blockIdx.y * gx + blockIdx.x;
  const int nwg = gx * gridDim.y;
  const int q8 = nwg >> 3, r8 = nwg & 7;
  const int xcd = lin & 7, i2 = lin >> 3;
  const int wg = (xcd < r8 ? xcd * (q8 + 1) : r8 * (q8 + 1) + (xcd - r8) * q8) + i2;
  const int m0 = (wg % gx) * 256, n0 = (wg / gx) * 256;

  const int wr = wave >> 2, wc = wave & 3;

  const unsigned short* srcA[4];
  const unsigned short* srcB[4];
  int dstO[4];
#pragma unroll
  for (int s = 0; s < 4; ++s) {
    const int c = tid + s * 512;
    const int row = c >> 3, qp = (c & 7) ^ (row & 7);
    srcA[s] = A + (size_t)(m0 + row) * lda + qp * 8;
    srcB[s] = B + (size_t)(n0 + row) * ldb + qp * 8;
    dstO[s] = (wave * 64 + s * 512) * 16;
  }

  const int NT = K >> 6;
#define STAGE256(kt, buf)                                            \
  {                                                                  \
    _Pragma("unroll")                                                \
    for (int s = 0; s < 4; ++s)                                      \
      gload16(srcA[s] + (kt) * 64, (char*)&Lds[buf][0][0] + dstO[s]);\
    _Pragma("unroll")                                                \
    for (int s = 0; s < 4; ++s)                                      \
      gload16(srcB[s] + (kt) * 64, (char*)&Lds[buf][1][0] + dstO[s]);\
  }
  STAGE256(0, 0);
  STAGE256(1, 1);

  f32x4 acc[8][4] = {};
  const int slot0 = (kq ^ (fr & 7)) * 16;

  for (int kt = 0; kt < NT; ++kt) {
    asm volatile("s_waitcnt vmcnt(8)" ::: "memory");
    __builtin_amdgcn_sched_barrier(0);
    __builtin_amdgcn_s_barrier();
    __builtin_amdgcn_sched_barrier(0);
    const char* bufA = (const char*)&Lds[kt & 1][0][0];
    const char* bufB = (const char*)&Lds[kt & 1][1][0];
    bf16x8 Bf[4][2];
#pragma unroll
    for (int n = 0; n < 4; ++n) {
      const char* bb = bufB + (wc * 64 + n * 16 + fr) * 128;
      Bf[n][0] = *(const bf16x8*)(bb + slot0);
      Bf[n][1] = *(const bf16x8*)(bb + (slot0 ^ 64));
    }
#pragma unroll
    for (int q = 0; q < 4; ++q) {
      bf16x8 Af[2][2];
#pragma unroll
      for (int m2 = 0; m2 < 2; ++m2) {
        const char* ab = bufA + (wr * 128 + q * 32 + m2 * 16 + fr) * 128;
        Af[m2][0] = *(const bf16x8*)(ab + slot0);
        Af[m2][1] = *(const bf16x8*)(ab + (slot0 ^ 64));
      }
      __builtin_amdgcn_s_setprio(1);
#pragma unroll
      for (int m2 = 0; m2 < 2; ++m2)
#pragma unroll
        for (int n = 0; n < 4; ++n) {
          acc[q * 2 + m2][n] = __builtin_amdgcn_mfma_f32_16x16x32_bf16(
              Af[m2][0], Bf[n][0], acc[q * 2 + m2][n], 0, 0, 0);
          acc[q * 2 + m2][n] = __builtin_amdgcn_mfma_f32_16x16x32_bf16(
              Af[m2][1], Bf[n][1], acc[q * 2 + m2][n], 0, 0, 0);
        }
      __builtin_amdgcn_s_setprio(0);
    }
    __builtin_amdgcn_sched_barrier(0);
    __builtin_amdgcn_s_barrier();
    __builtin_amdgcn_sched_barrier(0);
    const int kn = (kt + 2 < NT) ? kt + 2 : 0;
    STAGE256(kn, kt & 1);
  }

#pragma unroll
  for (int mf = 0; mf < 8; ++mf) {
    const int row = m0 + wr * 128 + mf * 16 + kq * 4;
#pragma unroll
    for (int n = 0; n < 4; ++n) {
      const int col = n0 + wc * 64 + n * 16 + fr;
      if (col < Nreal) {
        const float bs = bias[col];
#pragma unroll
        for (int rr = 0; rr < 4; ++rr)
          __builtin_nontemporal_store(acc[mf][n][rr] + bs,
                                      &C[(size_t)(row + rr) * ldc + col]);
      }
    }
  }
#undef STAGE256
}

// ================= fused persistent LSTM1+LSTM2 (256 WGs, 1/CU) =================
// WGs 0..127: LSTM1; 128..255: LSTM2 lagged 1 step (gates2 = Whh2@h2(t-1) [LDS] +
// Weff2@h1(t) [L2 A-frag stream] + beff2). Exchange: d-linear packed hx regions,
// wave0 does 64x16B system-scope stores; flag ARRAY (no RMW), wave1 polls in
// parallel lanes. hcat written as 16B vector stores from the staged tile.
// hx layout: [t][g(8)][slice s(16)][b_local(16)][32 d] bf16  (1KB per slice block).
__global__ __launch_bounds__(256, 1) void lstm_fused(
    const unsigned short* __restrict__ Whh1, const unsigned short* __restrict__ Whh2,
    const unsigned short* __restrict__ Weff2r,  // [16 s][16 kk][2 mi][256 tid][8] bf16
    const unsigned short* __restrict__ h01, const unsigned short* __restrict__ h02,
    const float* __restrict__ c1st, const float* __restrict__ c2st,
    const float* __restrict__ xpr,              // [64][128][4][2][64][4] f32
    const float* __restrict__ beff2,            // [2048] gate-interleaved
    unsigned short* __restrict__ hx1, unsigned short* __restrict__ hx2,
    unsigned short* __restrict__ hcat,          // [8192][1024]: [h2s | h1s]
    int* __restrict__ flags)                    // [2][8][16] ints
{
  __shared__ unsigned short Wsm[8][128][64];
  __shared__ uint32_t Hst[16][16];              // packed h staging (1KB)
  const int tid = threadIdx.x;
  const bool role2 = blockIdx.x >= 128;
  const int wg = role2 ? blockIdx.x - 128 : blockIdx.x;
  const int g = wg >> 4, s = wg & 15;
  const int w = tid >> 6, lane = tid & 63, fr = lane & 15, kq = lane >> 4;

  // ---- stage Whh slice into LDS (slot = chunk ^ (m&7)) ----
  {
    const unsigned short* Whh = role2 ? Whh2 : Whh1;
    const int m = tid >> 1;
    const int row = (m & 3) * 512 + s * 32 + (m >> 2);
    const unsigned short* src = Whh + (size_t)row * 512 + (tid & 1) * 256;
#pragma unroll 4
    for (int cc = 0; cc < 32; ++cc) {
      const int k = (tid & 1) * 256 + cc * 8;
      uint4 v = *(const uint4*)(src + cc * 8);
      const int kblk = k >> 6, c = (k & 63) >> 3, sl = c ^ (m & 7);
      *(uint4*)((char*)&Wsm[kblk][m][0] + sl * 16) = v;
    }
  }

  const int b = g * 16 + fr;
  const int d0 = s * 32 + w * 8 + kq;
  const float* c0 = role2 ? c2st : c1st;
  float c_r[2];
  c_r[0] = c0[b * 512 + d0];
  c_r[1] = c0[b * 512 + d0 + 4];
  __syncthreads();

  int* fl1 = flags + g * 16;
  int* fl2 = flags + 128 + g * 16;
  int* flown = role2 ? fl2 : fl1;
  unsigned short* hxown = role2 ? hx2 : hx1;
  const unsigned short* hinit = role2 ? h02 : h01;
  const int colbase = (role2 ? 0 : 512) + s * 32;
  const float4* xv = (const float4*)xpr + ((size_t)(wg * 4 + w) * 2) * 64 + lane;
  float4 be0 = {0, 0, 0, 0}, be1 = {0, 0, 0, 0};
  if (role2) {
    be0 = *(const float4*)(beff2 + s * 128 + w * 32 + kq * 4);
    be1 = *(const float4*)(beff2 + s * 128 + w * 32 + 16 + kq * 4);
  }
  const size_t hxg = (size_t)g * 8192;           // elements per-t region offset for group

  for (int t = 0; t < 64; ++t) {
    float4 xg0, xg1;
    if (role2) { xg0 = be0; xg1 = be1; }
    else { xg0 = xv[(size_t)t * 65536]; xg1 = xv[(size_t)t * 65536 + 64]; }

    // ---- poll (wave 1; flag array, parallel lanes) ----
    if (role2 || t) {
      if (w == 1) {
        for (;;) {
          bool ok = true;
          if (role2) {
            if (lane < 16) {
              if (t) ok = __hip_atomic_load(fl2 + lane, __ATOMIC_RELAXED,
                                            __HIP_MEMORY_SCOPE_SYSTEM) >= t;
            } else if (lane < 32) {
              ok = __hip_atomic_load(fl1 + lane - 16, __ATOMIC_RELAXED,
                                     __HIP_MEMORY_SCOPE_SYSTEM) >= t + 1;
            }
          } else {
            if (lane < 16)
              ok = __hip_atomic_load(fl1 + lane, __ATOMIC_RELAXED,
                                     __HIP_MEMORY_SCOPE_SYSTEM) >= t;
          }
          if (__all(ok)) break;
          __builtin_amdgcn_s_sleep(2);
        }
      }
      __syncthreads();
    }

    // ---- own-h fragments ----
    bf16x8 hf[16];
    if (t == 0) {
#pragma unroll
      for (int kk = 0; kk < 16; ++kk)
        hf[kk] = *(const bf16x8*)(hinit + (size_t)b * 512 + kk * 32 + kq * 8);
    } else {
      const unsigned short* hb = hxown + (size_t)(t - 1) * 65536 + hxg + fr * 32 + kq * 8;
#pragma unroll
      for (int kk = 0; kk < 16; ++kk)
        hf[kk] = *(const bf16x8*)(hb + kk * 512);
    }

    f32x4 acc[2] = {};
    // ---- phase A: Whh @ h_own (LDS) ----
#pragma unroll
    for (int kk = 0; kk < 16; ++kk) {
      const int kblk = kk >> 1, cbase = (kk & 1) * 4 + kq;
#pragma unroll
      for (int mi = 0; mi < 2; ++mi) {
        const int m = w * 32 + mi * 16 + fr;
        const int sl = cbase ^ (m & 7);
        const bf16x8 af = *(const bf16x8*)((const char*)&Wsm[kblk][m][0] + sl * 16);
        acc[mi] = __builtin_amdgcn_mfma_f32_16x16x32_bf16(af, hf[kk], acc[mi], 0, 0, 0);
      }
    }

    // ---- phase B (LSTM2 only): Weff2 @ h1(t) ----
    if (role2) {
      const unsigned short* h1b = hx1 + (size_t)t * 65536 + hxg + fr * 32 + kq * 8;
      bf16x8 hf1[16];
#pragma unroll
      for (int kk = 0; kk < 16; ++kk)
        hf1[kk] = *(const bf16x8*)(h1b + kk * 512);
      const bf16x8* wr = (const bf16x8*)Weff2r + (size_t)s * 32 * 256 + tid;
#pragma unroll
      for (int kk = 0; kk < 16; ++kk) {
#pragma unroll
        for (int mi = 0; mi < 2; ++mi) {
          const bf16x8 af = wr[(kk * 2 + mi) * 256];
          acc[mi] = __builtin_amdgcn_mfma_f32_16x16x32_bf16(af, hf1[kk], acc[mi], 0, 0, 0);
        }
      }
    }

    // ---- gates (lane-local) ----
    unsigned short hn[2];
#pragma unroll
    for (int mi = 0; mi < 2; ++mi) {
      const float4 xg = mi ? xg1 : xg0;
      const float iv = acc[mi][0] + xg.x;
      const float fv = acc[mi][1] + xg.y;
      const float gv = acc[mi][2] + xg.z;
      const float ov = acc[mi][3] + xg.w;
      const float c = fsig(fv) * c_r[mi] + fsig(iv) * ftanh(gv);
      c_r[mi] = c;
      hn[mi] = f2bf(fsig(ov) * ftanh(c));
    }

    // ---- pack to d-linear order: shfl + perm, stage in LDS ----
    const uint32_t pk = (uint32_t)hn[0] | ((uint32_t)hn[1] << 16);   // (d, d+4)
    const uint32_t y = (uint32_t)__shfl_xor((int)pk, 16);            // partner kq^1
    const uint32_t word = (kq & 1) ? __builtin_amdgcn_perm(pk, y, 0x07060302)
                                   : __builtin_amdgcn_perm(y, pk, 0x05040100);
    Hst[fr][w * 4 + ((kq & 1) ? 2 + (kq >> 1) : (kq >> 1))] = word;
    __syncthreads();

    // ---- wave 0: wide exchange stores + flag + hcat ----
    if (w == 0) {
      const uint4 v = *(const uint4*)&Hst[lane >> 2][(lane & 3) * 4];
      unsigned short* dst = hxown + (size_t)t * 65536 + hxg + s * 512 + lane * 8;
      __hip_atomic_store((unsigned long long*)dst, ((const unsigned long long*)&v)[0],
                         __ATOMIC_RELAXED, __HIP_MEMORY_SCOPE_SYSTEM);
      __hip_atomic_store((unsigned long long*)(dst + 4), ((const unsigned long long*)&v)[1],
                         __ATOMIC_RELAXED, __HIP_MEMORY_SCOPE_SYSTEM);
      asm volatile("s_waitcnt vmcnt(0)" ::: "memory");
      if (lane == 0)
        __hip_atomic_store(flown + s, t + 1, __ATOMIC_RELAXED, __HIP_MEMORY_SCOPE_SYSTEM);
      const int row = (g * 16 + (lane >> 2)) * 64 + t;
      *(uint4*)(hcat + (size_t)row * 1024 + colbase + (lane & 3) * 8) = v;
    }
  }
}

// ================= small helpers =================
struct CastJobs {
  const float* src[15];
  unsigned short* dst[15];
  long nreal[15];
  long cum[16];
  int n;
};

__global__ void cast_multi(CastJobs J) {
  const long total = J.cum[J.n];
  for (long i = (long)blockIdx.x * blockDim.x + threadIdx.x; i < total;
       i += (long)gridDim.x * blockDim.x) {
    int s = 0;
    while (i >= J.cum[s + 1]) ++s;
    const long off = i - J.cum[s];
    J.dst[s][off] = (off < J.nreal[s]) ? f2bf(J.src[s][off]) : (unsigned short)0;
  }
}

// gate-interleaved row permutation of W_ih (+ biases): dst row m = 4d+g <- src row g*512+d
__global__ void perm_wih(const float* __restrict__ W1, const float* __restrict__ W2,
                         const float* __restrict__ b1, const float* __restrict__ b2,
                         unsigned short* __restrict__ R1, unsigned short* __restrict__ R2,
                         float* __restrict__ bp1, float* __restrict__ bp2) {
  const long id = (long)blockIdx.x * blockDim.x + threadIdx.x;
  const long n1 = (long)2048 * 512;
  if (id < n1) {
    const int m = (int)(id >> 9), k = (int)(id & 511);
    R1[id] = f2bf(W1[(size_t)((m & 3) * 512 + (m >> 2)) * 512 + k]);
  } else {
    const long j = id - n1;
    const int m = (int)(j >> 10), k = (int)(j & 1023);
    R2[j] = f2bf(W2[(size_t)((m & 3) * 512 + (m >> 2)) * 1024 + k]);
  }
  if (id < 2048) bp1[id] = b1[(id & 3) * 512 + (id >> 2)];
  else if (id < 4096) { const int m = (int)id - 2048; bp2[m] = b2[(m & 3) * 512 + (m >> 2)]; }
}

// transposed bf16 cast of Wv1/Wv2
__global__ void transp_cast(const float* __restrict__ s1, const float* __restrict__ s2,
                            unsigned short* __restrict__ d1, unsigned short* __restrict__ d2) {
  const int e = blockIdx.x * blockDim.x + threadIdx.x;
  const float* s = (e >> 18) ? s2 : s1;
  unsigned short* d = (e >> 18) ? d2 : d1;
  const int t = e & 262143, a = t >> 9, bb = t & 511;
  d[t] = f2bf(s[bb * 512 + a]);
}

// bc = Wo @ bv + bo
__global__ void bias_comb(const float* __restrict__ Wo1, const float* __restrict__ bv1,
                          const float* __restrict__ bo1,
                          const float* __restrict__ Wo2, const float* __restrict__ bv2,
                          const float* __restrict__ bo2,
                          float* __restrict__ bc1, float* __restrict__ bc2) {
  const int i = threadIdx.x;
  const float* Wo = blockIdx.x ? Wo2 : Wo1;
  const float* bv = blockIdx.x ? bv2 : bv1;
  const float* bo = blockIdx.x ? bo2 : bo1;
  float* bc = blockIdx.x ? bc2 : bc1;
  float s = bo[i];
  for (int k = 0; k < 512; ++k) s += Wo[i * 512 + k] * bv[k];
  bc[i] = s;
}

__global__ void concat_bias(const float* a, const float* b, const float* c, const float* d,
                            float* o) {
  const int i = blockIdx.x * blockDim.x + threadIdx.x;
  const float* s[4] = {a, b, c, d};
  o[i] = s[i >> 9][i & 511];
}

__global__ void gather_rows(const int* __restrict__ ix, const unsigned short* __restrict__ emb,
                            unsigned short* __restrict__ x) {
  const int row = blockIdx.x;
  const int e = ix[row];
  const uint4* s = (const uint4*)(emb + (size_t)e * 512);
  uint4* d = (uint4*)(x + (size_t)row * 512);
  d[threadIdx.x] = s[threadIdx.x];
}

// Weff2 [2048][512] bf16 -> A-frag stream [16 s][16 kk][2 mi][256 tid][8]
__global__ void reorder_wbf(const unsigned short* __restrict__ W,
                            unsigned short* __restrict__ R) {
  const int id = blockIdx.x * blockDim.x + threadIdx.x;  // 131072
  const int tid = id & 255, mi = (id >> 8) & 1, kk = (id >> 9) & 15, s = id >> 13;
  const int w = tid >> 6, lane = tid & 63, fr = lane & 15, kq = lane >> 4;
  const int row = s * 128 + w * 32 + mi * 16 + fr;
  const int col = kk * 32 + kq * 8;
  *((uint4*)R + id) = *(const uint4*)(W + (size_t)row * 512 + col);
}

// blcat[j] = blog[j] + Wl_a1[j,:]·bc1 + Wl_a2[j,:]·bc2   (bf16 Wlog rows)
__global__ void bias_blcat(const unsigned short* __restrict__ Wl, const float* __restrict__ blog,
                           const float* __restrict__ bc1, const float* __restrict__ bc2,
                           float* __restrict__ blcat) {
  const int j = blockIdx.x * 4 + (threadIdx.x >> 6);
  const int lane = threadIdx.x & 63;
  const unsigned short* row = Wl + (size_t)j * 1536;
  float sum = 0.f;
  for (int k = lane; k < 512; k += 64) {
    sum += bf2f(row[512 + k]) * bc1[k];
    sum += bf2f(row[1024 + k]) * bc2[k];
  }
#pragma unroll
  for (int m = 32; m; m >>= 1) sum += __shfl_xor(sum, m, 64);
  if (lane == 0) blcat[j] = blog[j] + sum;
}

// beff2[m] = bp2[m] + Wp2a[m,:]·bc1
__global__ void bias_beff2(const unsigned short* __restrict__ Wp2, const float* __restrict__ bp2,
                           const float* __restrict__ bc1, float* __restrict__ beff2) {
  const int m = blockIdx.x * 4 + (threadIdx.x >> 6);
  const int lane = threadIdx.x & 63;
  const unsigned short* row = Wp2 + (size_t)m * 1024 + 512;
  float sum = 0.f;
  for (int k = lane; k < 512; k += 64) sum += bf2f(row[k]) * bc1[k];
#pragma unroll
  for (int mm = 32; mm; mm >>= 1) sum += __shfl_xor(sum, mm, 64);
  if (lane == 0) beff2[m] = bp2[m] + sum;
}

// ================= host =================
extern "C" void kernel_launch(void* const* d_in, const int* in_sizes, int n_in,
                              void* d_out, int out_size, void* d_ws, size_t ws_size,
                              hipStream_t stream) {
  (void)in_sizes; (void)n_in; (void)out_size; (void)ws_size;
  const float* img    = (const float*)d_in[0];
  const int*   ix     = (const int*)d_in[1];
  const float* emb    = (const float*)d_in[2];
  const float* Wih1f  = (const float*)d_in[3];
  const float* bih1   = (const float*)d_in[4];
  const float* Wic1f  = (const float*)d_in[5];
  const float* bic1   = (const float*)d_in[6];
  const float* Wih2f  = (const float*)d_in[7];
  const float* bih2   = (const float*)d_in[8];
  const float* Wic2f  = (const float*)d_in[9];
  const float* bic2   = (const float*)d_in[10];
  const float* Wihl1  = (const float*)d_in[11];
  const float* Whhl1  = (const float*)d_in[12];
  const float* b1     = (const float*)d_in[13];
  const float* Wihl2  = (const float*)d_in[14];
  const float* Whhl2  = (const float*)d_in[15];
  const float* b2     = (const float*)d_in[16];
  const float* Wv1    = (const float*)d_in[17];
  const float* bv1    = (const float*)d_in[18];
  const float* Wo1    = (const float*)d_in[19];
  const float* bo1    = (const float*)d_in[20];
  const float* Wv2    = (const float*)d_in[21];
  const float* bv2    = (const float*)d_in[22];
  const float* Wo2    = (const float*)d_in[23];
  const float* bo2    = (const float*)d_in[24];
  const float* Wlog   = (const float*)d_in[25];
  const float* blog   = (const float*)d_in[26];
  float* out = (float*)d_out;

  char* p = (char*)d_ws;
  auto al = [&](size_t bytes) { char* r = p; p += (bytes + 255) & ~(size_t)255; return r; };
  unsigned short* emb_b  = (unsigned short*)al((size_t)10000 * 512 * 2);
  unsigned short* Wp1    = (unsigned short*)al((size_t)2048 * 512 * 2);
  unsigned short* Whh1_b = (unsigned short*)al((size_t)2048 * 512 * 2);
  unsigned short* Wp2    = (unsigned short*)al((size_t)2048 * 1024 * 2);
  unsigned short* Whh2_b = (unsigned short*)al((size_t)2048 * 512 * 2);
  unsigned short* WvT1   = (unsigned short*)al((size_t)512 * 512 * 2);
  unsigned short* Wo1_b  = (unsigned short*)al((size_t)512 * 512 * 2);
  unsigned short* WvT2   = (unsigned short*)al((size_t)512 * 512 * 2);
  unsigned short* Wo2_b  = (unsigned short*)al((size_t)512 * 512 * 2);
  unsigned short* Wc1T   = (unsigned short*)al((size_t)512 * 512 * 2);
  unsigned short* Wc2T   = (unsigned short*)al((size_t)512 * 512 * 2);
  unsigned short* Wlog_b = (unsigned short*)al((size_t)10240 * 1536 * 2);
  unsigned short* Wcat   = (unsigned short*)al((size_t)10240 * 1024 * 2);
  unsigned short* Weff2  = (unsigned short*)al((size_t)2048 * 512 * 2);
  unsigned short* Weff2r = (unsigned short*)al((size_t)2048 * 512 * 2);
  unsigned short* Wh1i_b = (unsigned short*)al((size_t)512 * 2048 * 2);
  unsigned short* Wc1i_b = (unsigned short*)al((size_t)512 * 2048 * 2);
  unsigned short* Wh2i_b = (unsigned short*)al((size_t)512 * 2048 * 2);
  unsigned short* Wc2i_b = (unsigned short*)al((size_t)512 * 2048 * 2);
  unsigned short* img_b  = (unsigned short*)al((size_t)128 * 2048 * 2);
  unsigned short* x_b    = (unsigned short*)al((size_t)8192 * 512 * 2);
  float*          xpr    = (float*)al((size_t)8192 * 2048 * 4);
  unsigned short* hcat   = (unsigned short*)al((size_t)8192 * 1024 * 2);
  unsigned short* hx1    = (unsigned short*)al((size_t)64 * 128 * 512 * 2);
  unsigned short* hx2    = (unsigned short*)al((size_t)64 * 128 * 512 * 2);
  unsigned short* h01    = (unsigned short*)al((size_t)128 * 512 * 2);
  unsigned short* h02    = (unsigned short*)al((size_t)128 * 512 * 2);
  float*          c1st   = (float*)al((size_t)128 * 512 * 4);
  float*          c2st   = (float*)al((size_t)128 * 512 * 4);
  float*          bcat   = (float*)al((size_t)2048 * 4);
  float*          bp1    = (float*)al((size_t)2048 * 4);
  float*          bp2    = (float*)al((size_t)2048 * 4);
  float*          bc1    = (float*)al((size_t)512 * 4);
  float*          bc2    = (float*)al((size_t)512 * 4);
  float*          beff2  = (float*)al((size_t)2048 * 4);
  float*          blcat  = (float*)al((size_t)10240 * 4);
  int*            flags  = (int*)al(2048);

  hipMemsetAsync(flags, 0, 2048, stream);

  // ---- casts ----
  CastJobs J = {};
  auto addjob = [&](const float* s, unsigned short* d, long nreal, long ntot) {
    J.src[J.n] = s; J.dst[J.n] = d; J.nreal[J.n] = nreal;
    J.cum[J.n + 1] = J.cum[J.n] + ntot; ++J.n;
  };
  addjob(img,   img_b,  (long)128 * 2048,   (long)128 * 2048);
  addjob(emb,   emb_b,  (long)10000 * 512,  (long)10000 * 512);
  addjob(Whhl1, Whh1_b, (long)2048 * 512,   (long)2048 * 512);
  addjob(Whhl2, Whh2_b, (long)2048 * 512,   (long)2048 * 512);
  addjob(Wo1,   Wo1_b,  (long)512 * 512,    (long)512 * 512);
  addjob(Wo2,   Wo2_b,  (long)512 * 512,    (long)512 * 512);
  addjob(Wih1f, Wh1i_b, (long)512 * 2048,   (long)512 * 2048);
  addjob(Wic1f, Wc1i_b, (long)512 * 2048,   (long)512 * 2048);
  addjob(Wih2f, Wh2i_b, (long)512 * 2048,   (long)512 * 2048);
  addjob(Wic2f, Wc2i_b, (long)512 * 2048,   (long)512 * 2048);
  addjob(Wlog,  Wlog_b, (long)10000 * 1536, (long)10240 * 1536);
  cast_multi<<<2048, 256, 0, stream>>>(J);

  transp_cast<<<2048, 256, 0, stream>>>(Wv1, Wv2, WvT1, WvT2);
  perm_wih<<<12288, 256, 0, stream>>>(Wihl1, Wihl2, b1, b2, Wp1, Wp2, bp1, bp2);
  concat_bias<<<8, 256, 0, stream>>>(bih1, bic1, bih2, bic2, bcat);
  bias_comb<<<2, 512, 0, stream>>>(Wo1, bv1, bo1, Wo2, bv2, bo2, bc1, bc2);

  // ---- WcT = (Wo@Wv)^T ----
  gemm_nt<1><<<dim3(4, 4), 256, 0, stream>>>(
      WvT1, 512, Wo1_b, 512, Wc1T, nullptr, nullptr, nullptr, 512, 0, nullptr, 512, 512);
  gemm_nt<1><<<dim3(4, 4), 256, 0, stream>>>(
      WvT2, 512, Wo2_b, 512, Wc2T, nullptr, nullptr, nullptr, 512, 0, nullptr, 512, 512);

  // ---- Weff2 = Wp2[:, :512] + Wp2[:, 512:] @ WoWv1 ----
  gemm_nt<4><<<dim3(16, 4), 256, 0, stream>>>(
      Wp2 + 512, 1024, Wc1T, 512, Weff2, Wp2, nullptr, nullptr, 512, 1024, nullptr, 512, 512);
  reorder_wbf<<<512, 256, 0, stream>>>(Weff2, Weff2r);
  bias_beff2<<<512, 256, 0, stream>>>(Wp2, bp2, bc1, beff2);

  // ---- Wcat = [ Wl_h2 + Wl_a2@WoWv2 | Wl_a1@WoWv1 ] ----
  gemm_nt<4><<<dim3(80, 4), 256, 0, stream>>>(
      Wlog_b + 1024, 1536, Wc2T, 512, Wcat, Wlog_b, nullptr, nullptr, 1024, 1536,
      nullptr, 512, 512);
  gemm_nt<1><<<dim3(80, 4), 256, 0, stream>>>(
      Wlog_b + 512, 1536, Wc1T, 512, Wcat + 512, nullptr, nullptr, nullptr, 1024, 0,
      nullptr, 512, 512);
  bias_blcat<<<2500, 256, 0, stream>>>(Wlog_b, blog, bc1, bc2, blcat);

  // ---- init states ----
  gemm_nt<3><<<dim3(1, 16), 256, 0, stream>>>(
      img_b, 2048, Wh1i_b, 2048, h01, c1st, h02, c2st, 0, 0, bcat, 2048, 2048);

  // ---- x = emb[captions_ix]; xp1 = Wp1 @ x^T (+bp1) ----
  gather_rows<<<8192, 64, 0, stream>>>(ix, emb_b, x_b);
  gemm_nt<2><<<dim3(16, 64), 256, 0, stream>>>(
      Wp1, 512, x_b, 512, xpr, nullptr, nullptr, nullptr, 0, 0, bp1, 512, 8192);

  // ---- both LSTMs, fused & pipelined ----
  lstm_fused<<<256, 256, 0, stream>>>(
      Whh1_b, Whh2_b, Weff2r, h01, h02, c1st, c2st, xpr, beff2, hx1, hx2, hcat, flags);

  // ---- logits = hcat @ Wcat^T + blcat ----
  gemm256<<<dim3(32, 40), 512, 0, stream>>>(
      hcat, 1024, Wcat, 1024, out, 10000, blcat, 1024, 10000);
}

// Round 8
// 1057.444 us; speedup vs baseline: 4.2890x; 1.0019x over previous
//
#include <hip/hip_runtime.h>
#include <stdint.h>

#define DEV __device__ __forceinline__

typedef short bf16x8 __attribute__((ext_vector_type(8)));
typedef float f32x4 __attribute__((ext_vector_type(4)));

DEV unsigned short f2bf(float f) {
  union { float f; uint32_t u; } v; v.f = f;
  return (unsigned short)((v.u + 0x7fffu + ((v.u >> 16) & 1u)) >> 16);
}
DEV float bf2f(unsigned short u) {
  union { uint32_t u; float f; } v; v.u = (uint32_t)u << 16; return v.f;
}

DEV float fsig(float x) { return 1.f / (1.f + __expf(-x)); }
DEV float ftanh(float x) { float e = __expf(2.f * x); return 1.f - 2.f / (e + 1.f); }

DEV void gload16(const void* g, void* lds) {
  __builtin_amdgcn_global_load_lds(
      (const __attribute__((address_space(1))) int*)(uintptr_t)g,
      (__attribute__((address_space(3))) int*)(uintptr_t)lds, 16, 0, 0);
}

// ================= generic NT GEMM: C[M,N] = A[M,K] * B[N,K]^T + bias =================
// 128x128 tile, BK=32, 4 waves each 64x64.
// MODE 1: bf16 C (+optional C2).  MODE 2: xpr layout (gate-interleaved rows, bias/row).
// MODE 3: init states.  MODE 4: bf16 C = product + bf16 addend (P1, ld ldc2).
template <int MODE>
__global__ __launch_bounds__(256) void gemm_nt(
    const unsigned short* __restrict__ A, int lda,
    const unsigned short* __restrict__ B, int ldb,
    void* __restrict__ P0, void* __restrict__ P1,
    void* __restrict__ P2, void* __restrict__ P3,
    int ldc, int ldc2,
    const float* __restrict__ bias,
    int K, int Nreal)
{
  __shared__ alignas(16) unsigned short Asm[128 * 32];
  __shared__ alignas(16) unsigned short Bsm[128 * 32];
  const int tid = threadIdx.x;
  const int wave = tid >> 6, lane = tid & 63;

  const int gx = gridDim.x;
  const int lin = blockIdx.y * gx + blockIdx.x;
  const int nwg = gx * gridDim.y;
  const int q = nwg >> 3, r = nwg & 7;
  const int xcd = lin & 7, i2 = lin >> 3;
  const int wg = (xcd < r ? xcd * (q + 1) : r * (q + 1) + (xcd - r) * q) + i2;
  const int m0 = (wg % gx) * 128, n0 = (wg / gx) * 128;

  const int wr = wave >> 1, wc = wave & 1;
  f32x4 acc[4][4] = {};

  const int q0 = tid, q1 = tid + 256;
  const unsigned short* Ag0 = A + (size_t)(m0 + (q0 >> 2)) * lda + (q0 & 3) * 8;
  const unsigned short* Ag1 = A + (size_t)(m0 + (q1 >> 2)) * lda + (q1 & 3) * 8;
  const unsigned short* Bg0 = B + (size_t)(n0 + (q0 >> 2)) * ldb + (q0 & 3) * 8;
  const unsigned short* Bg1 = B + (size_t)(n0 + (q1 >> 2)) * ldb + (q1 & 3) * 8;
  char* As0 = (char*)Asm + wave * 1024;  char* As1 = As0 + 4096;
  char* Bs0 = (char*)Bsm + wave * 1024;  char* Bs1 = Bs0 + 4096;

  const int ra = wr * 64 + (lane & 15);
  const int rb = wc * 64 + (lane & 15);
  const int kb = (lane >> 4) * 16;

  for (int k0 = 0; k0 < K; k0 += 32) {
    gload16(Ag0 + k0, As0);
    gload16(Ag1 + k0, As1);
    gload16(Bg0 + k0, Bs0);
    gload16(Bg1 + k0, Bs1);
    __syncthreads();
    bf16x8 af[4], bfr[4];
#pragma unroll
    for (int i = 0; i < 4; ++i)
      af[i] = *(const bf16x8*)((const char*)Asm + (ra + i * 16) * 64 + kb);
#pragma unroll
    for (int i = 0; i < 4; ++i)
      bfr[i] = *(const bf16x8*)((const char*)Bsm + (rb + i * 16) * 64 + kb);
#pragma unroll
    for (int mi = 0; mi < 4; ++mi)
#pragma unroll
      for (int ni = 0; ni < 4; ++ni)
        acc[mi][ni] = __builtin_amdgcn_mfma_f32_16x16x32_bf16(af[mi], bfr[ni], acc[mi][ni], 0, 0, 0);
    __syncthreads();
  }

  const int row0 = m0 + wr * 64 + (lane >> 4) * 4;
  const int col0 = n0 + wc * 64 + (lane & 15);

  if constexpr (MODE == 2) {
#pragma unroll
    for (int mi = 0; mi < 4; ++mi) {
      const int rowb = row0 + mi * 16;       // multiple of 4
      const int dd = rowb >> 2;
      const float4 b4 = *(const float4*)&bias[rowb];
#pragma unroll
      for (int ni = 0; ni < 4; ++ni) {
        const int col = col0 + ni * 16;
        const int tt = col & 63, bb = col >> 6;
        float4 v;
        v.x = acc[mi][ni][0] + b4.x;
        v.y = acc[mi][ni][1] + b4.y;
        v.z = acc[mi][ni][2] + b4.z;
        v.w = acc[mi][ni][3] + b4.w;
        const int wgid = (bb >> 4) * 16 + (dd >> 5);
        const int ww = (dd >> 3) & 3, mi2 = (dd >> 2) & 1, ln = (dd & 3) * 16 + (bb & 15);
        ((float4*)P0)[((((size_t)tt * 128 + wgid) * 4 + ww) * 2 + mi2) * 64 + ln] = v;
      }
    }
    return;
  }

#pragma unroll
  for (int mi = 0; mi < 4; ++mi) {
#pragma unroll
    for (int ni = 0; ni < 4; ++ni) {
      const int col = col0 + ni * 16;
      if (col >= Nreal) continue;
      const float bs = bias ? bias[col] : 0.f;
#pragma unroll
      for (int rr = 0; rr < 4; ++rr) {
        const int row = row0 + mi * 16 + rr;
        const float v = acc[mi][ni][rr] + bs;
        if constexpr (MODE == 1) {
          ((unsigned short*)P0)[(size_t)row * ldc + col] = f2bf(v);
          if (P1) ((unsigned short*)P1)[(size_t)row * ldc2 + col] = f2bf(v);
        } else if constexpr (MODE == 4) {
          const unsigned short ad = ((const unsigned short*)P1)[(size_t)row * ldc2 + col];
          ((unsigned short*)P0)[(size_t)row * ldc + col] = f2bf(v + bf2f(ad));
        } else {  // MODE 3
          const int seg = col >> 9, cc = col & 511;
          if (seg == 0)      ((unsigned short*)P0)[(size_t)row * 512 + cc] = f2bf(v);
          else if (seg == 1) ((float*)P1)[(size_t)row * 512 + cc] = v;
          else if (seg == 2) ((unsigned short*)P2)[(size_t)row * 512 + cc] = f2bf(v);
          else               ((float*)P3)[(size_t)row * 512 + cc] = v;
        }
      }
    }
  }
}

// ============ 256x256 tile GEMM, BK=64, counted vmcnt pipeline, NT C-stores ============
__global__ __launch_bounds__(512, 2) void gemm256(
    const unsigned short* __restrict__ A, int lda,
    const unsigned short* __restrict__ B, int ldb,
    float* __restrict__ C, int ldc,
    const float* __restrict__ bias, int K, int Nreal)
{
  __shared__ alignas(16) unsigned short Lds[2][2][16384];
  const int tid = threadIdx.x;
  const int wave = tid >> 6, lane = tid & 63;
  const int fr = lane & 15, kq = lane >> 4;

  const int gx = gridDim.x;
  const int lin = blockIdx.y * gx + blockIdx.x;
  const int nwg = gx * gridDim.y;
  const int q8 = nwg >> 3, r8 = nwg & 7;
  const int xcd = lin & 7, i2 = lin >> 3;
  const int wg = (xcd < r8 ? xcd * (q8 + 1) : r8 * (q8 + 1) + (xcd - r8) * q8) + i2;
  const int m0 = (wg % gx) * 256, n0 = (wg / gx) * 256;

  const int wr = wave >> 2, wc = wave & 3;

  const unsigned short* srcA[4];
  const unsigned short* srcB[4];
  int dstO[4];
#pragma unroll
  for (int s = 0; s < 4; ++s) {
    const int c = tid + s * 512;
    const int row = c >> 3, qp = (c & 7) ^ (row & 7);
    srcA[s] = A + (size_t)(m0 + row) * lda + qp * 8;
    srcB[s] = B + (size_t)(n0 + row) * ldb + qp * 8;
    dstO[s] = (wave * 64 + s * 512) * 16;
  }

  const int NT = K >> 6;
#define STAGE256(kt, buf)                                            \
  {                                                                  \
    _Pragma("unroll")                                                \
    for (int s = 0; s < 4; ++s)                                      \
      gload16(srcA[s] + (kt) * 64, (char*)&Lds[buf][0][0] + dstO[s]);\
    _Pragma("unroll")                                                \
    for (int s = 0; s < 4; ++s)                                      \
      gload16(srcB[s] + (kt) * 64, (char*)&Lds[buf][1][0] + dstO[s]);\
  }
  STAGE256(0, 0);
  STAGE256(1, 1);

  f32x4 acc[8][4] = {};
  const int slot0 = (kq ^ (fr & 7)) * 16;

  for (int kt = 0; kt < NT; ++kt) {
    asm volatile("s_waitcnt vmcnt(8)" ::: "memory");
    __builtin_amdgcn_sched_barrier(0);
    __builtin_amdgcn_s_barrier();
    __builtin_amdgcn_sched_barrier(0);
    const char* bufA = (const char*)&Lds[kt & 1][0][0];
    const char* bufB = (const char*)&Lds[kt & 1][1][0];
    bf16x8 Bf[4][2];
#pragma unroll
    for (int n = 0; n < 4; ++n) {
      const char* bb = bufB + (wc * 64 + n * 16 + fr) * 128;
      Bf[n][0] = *(const bf16x8*)(bb + slot0);
      Bf[n][1] = *(const bf16x8*)(bb + (slot0 ^ 64));
    }
#pragma unroll
    for (int q = 0; q < 4; ++q) {
      bf16x8 Af[2][2];
#pragma unroll
      for (int m2 = 0; m2 < 2; ++m2) {
        const char* ab = bufA + (wr * 128 + q * 32 + m2 * 16 + fr) * 128;
        Af[m2][0] = *(const bf16x8*)(ab + slot0);
        Af[m2][1] = *(const bf16x8*)(ab + (slot0 ^ 64));
      }
      __builtin_amdgcn_s_setprio(1);
#pragma unroll
      for (int m2 = 0; m2 < 2; ++m2)
#pragma unroll
        for (int n = 0; n < 4; ++n) {
          acc[q * 2 + m2][n] = __builtin_amdgcn_mfma_f32_16x16x32_bf16(
              Af[m2][0], Bf[n][0], acc[q * 2 + m2][n], 0, 0, 0);
          acc[q * 2 + m2][n] = __builtin_amdgcn_mfma_f32_16x16x32_bf16(
              Af[m2][1], Bf[n][1], acc[q * 2 + m2][n], 0, 0, 0);
        }
      __builtin_amdgcn_s_setprio(0);
    }
    __builtin_amdgcn_sched_barrier(0);
    __builtin_amdgcn_s_barrier();
    __builtin_amdgcn_sched_barrier(0);
    const int kn = (kt + 2 < NT) ? kt + 2 : 0;
    STAGE256(kn, kt & 1);
  }

#pragma unroll
  for (int mf = 0; mf < 8; ++mf) {
    const int row = m0 + wr * 128 + mf * 16 + kq * 4;
#pragma unroll
    for (int n = 0; n < 4; ++n) {
      const int col = n0 + wc * 64 + n * 16 + fr;
      if (col < Nreal) {
        const float bs = bias[col];
#pragma unroll
        for (int rr = 0; rr < 4; ++rr)
          __builtin_nontemporal_store(acc[mf][n][rr] + bs,
                                      &C[(size_t)(row + rr) * ldc + col]);
      }
    }
  }
#undef STAGE256
}

// ================= fused persistent LSTM1+LSTM2 (256 WGs, 1/CU) =================
// Exchange via AGENT-scope relaxed atomics: stores write through to the shared LLC
// (no L2 invalidation -- RELAXED has no fence), loads bypass L1/L2 to LLC. SYSTEM
// scope (used before) is fine-grained/uncached -> HBM round trips (~7 us/step).
// hx layout: [t][g(8)][slice s(16)][b_local(16)][32 d] bf16  (1KB per slice block).
__global__ __launch_bounds__(256, 1) void lstm_fused(
    const unsigned short* __restrict__ Whh1, const unsigned short* __restrict__ Whh2,
    const unsigned short* __restrict__ Weff2r,  // [16 s][16 kk][2 mi][256 tid][8] bf16
    const unsigned short* __restrict__ h01, const unsigned short* __restrict__ h02,
    const float* __restrict__ c1st, const float* __restrict__ c2st,
    const float* __restrict__ xpr,              // [64][128][4][2][64][4] f32
    const float* __restrict__ beff2,            // [2048] gate-interleaved
    unsigned short* __restrict__ hx1, unsigned short* __restrict__ hx2,
    unsigned short* __restrict__ hcat,          // [8192][1024]: [h2s | h1s]
    int* __restrict__ flags)                    // [2][8][16] ints
{
  __shared__ unsigned short Wsm[8][128][64];
  __shared__ uint32_t Hst[16][16];              // packed h staging (1KB)
  const int tid = threadIdx.x;
  const bool role2 = blockIdx.x >= 128;
  const int wg = role2 ? blockIdx.x - 128 : blockIdx.x;
  const int g = wg >> 4, s = wg & 15;
  const int w = tid >> 6, lane = tid & 63, fr = lane & 15, kq = lane >> 4;

  // ---- stage Whh slice into LDS (slot = chunk ^ (m&7)) ----
  {
    const unsigned short* Whh = role2 ? Whh2 : Whh1;
    const int m = tid >> 1;
    const int row = (m & 3) * 512 + s * 32 + (m >> 2);
    const unsigned short* src = Whh + (size_t)row * 512 + (tid & 1) * 256;
#pragma unroll 4
    for (int cc = 0; cc < 32; ++cc) {
      const int k = (tid & 1) * 256 + cc * 8;
      uint4 v = *(const uint4*)(src + cc * 8);
      const int kblk = k >> 6, c = (k & 63) >> 3, sl = c ^ (m & 7);
      *(uint4*)((char*)&Wsm[kblk][m][0] + sl * 16) = v;
    }
  }

  const int b = g * 16 + fr;
  const int d0 = s * 32 + w * 8 + kq;
  const float* c0 = role2 ? c2st : c1st;
  float c_r[2];
  c_r[0] = c0[b * 512 + d0];
  c_r[1] = c0[b * 512 + d0 + 4];
  __syncthreads();

  int* fl1 = flags + g * 16;
  int* fl2 = flags + 128 + g * 16;
  int* flown = role2 ? fl2 : fl1;
  unsigned short* hxown = role2 ? hx2 : hx1;
  const unsigned short* hinit = role2 ? h02 : h01;
  const int colbase = (role2 ? 0 : 512) + s * 32;
  const float4* xv = (const float4*)xpr + ((size_t)(wg * 4 + w) * 2) * 64 + lane;
  float4 be0 = {0, 0, 0, 0}, be1 = {0, 0, 0, 0};
  if (role2) {
    be0 = *(const float4*)(beff2 + s * 128 + w * 32 + kq * 4);
    be1 = *(const float4*)(beff2 + s * 128 + w * 32 + 16 + kq * 4);
  }
  const size_t hxg = (size_t)g * 8192;           // per-t region offset for group

  for (int t = 0; t < 64; ++t) {
    float4 xg0, xg1;
    if (role2) { xg0 = be0; xg1 = be1; }
    else { xg0 = xv[(size_t)t * 65536]; xg1 = xv[(size_t)t * 65536 + 64]; }

    // ---- poll (wave 1; flag array, parallel lanes; AGENT-scope = LLC) ----
    if (role2 || t) {
      if (w == 1) {
        for (;;) {
          bool ok = true;
          if (role2) {
            if (lane < 16) {
              if (t) ok = __hip_atomic_load(fl2 + lane, __ATOMIC_RELAXED,
                                            __HIP_MEMORY_SCOPE_AGENT) >= t;
            } else if (lane < 32) {
              ok = __hip_atomic_load(fl1 + lane - 16, __ATOMIC_RELAXED,
                                     __HIP_MEMORY_SCOPE_AGENT) >= t + 1;
            }
          } else {
            if (lane < 16)
              ok = __hip_atomic_load(fl1 + lane, __ATOMIC_RELAXED,
                                     __HIP_MEMORY_SCOPE_AGENT) >= t;
          }
          if (__all(ok)) break;
          __builtin_amdgcn_s_sleep(1);
        }
      }
      __syncthreads();
    }

    // ---- own-h fragments ----
    bf16x8 hf[16];
    if (t == 0) {
#pragma unroll
      for (int kk = 0; kk < 16; ++kk)
        hf[kk] = *(const bf16x8*)(hinit + (size_t)b * 512 + kk * 32 + kq * 8);
    } else {
      const unsigned short* hb = hxown + (size_t)(t - 1) * 65536 + hxg + fr * 32 + kq * 8;
#pragma unroll
      for (int kk = 0; kk < 16; ++kk)
        hf[kk] = *(const bf16x8*)(hb + kk * 512);
    }

    f32x4 acc[2] = {};
    // ---- phase A: Whh @ h_own (LDS) ----
#pragma unroll
    for (int kk = 0; kk < 16; ++kk) {
      const int kblk = kk >> 1, cbase = (kk & 1) * 4 + kq;
#pragma unroll
      for (int mi = 0; mi < 2; ++mi) {
        const int m = w * 32 + mi * 16 + fr;
        const int sl = cbase ^ (m & 7);
        const bf16x8 af = *(const bf16x8*)((const char*)&Wsm[kblk][m][0] + sl * 16);
        acc[mi] = __builtin_amdgcn_mfma_f32_16x16x32_bf16(af, hf[kk], acc[mi], 0, 0, 0);
      }
    }

    // ---- phase B (LSTM2 only): Weff2 @ h1(t) ----
    if (role2) {
      const unsigned short* h1b = hx1 + (size_t)t * 65536 + hxg + fr * 32 + kq * 8;
      bf16x8 hf1[16];
#pragma unroll
      for (int kk = 0; kk < 16; ++kk)
        hf1[kk] = *(const bf16x8*)(h1b + kk * 512);
      const bf16x8* wr = (const bf16x8*)Weff2r + (size_t)s * 32 * 256 + tid;
#pragma unroll
      for (int kk = 0; kk < 16; ++kk) {
#pragma unroll
        for (int mi = 0; mi < 2; ++mi) {
          const bf16x8 af = wr[(kk * 2 + mi) * 256];
          acc[mi] = __builtin_amdgcn_mfma_f32_16x16x32_bf16(af, hf1[kk], acc[mi], 0, 0, 0);
        }
      }
    }

    // ---- gates (lane-local) ----
    unsigned short hn[2];
#pragma unroll
    for (int mi = 0; mi < 2; ++mi) {
      const float4 xg = mi ? xg1 : xg0;
      const float iv = acc[mi][0] + xg.x;
      const float fv = acc[mi][1] + xg.y;
      const float gv = acc[mi][2] + xg.z;
      const float ov = acc[mi][3] + xg.w;
      const float c = fsig(fv) * c_r[mi] + fsig(iv) * ftanh(gv);
      c_r[mi] = c;
      hn[mi] = f2bf(fsig(ov) * ftanh(c));
    }

    // ---- pack to d-linear order: shfl + perm, stage in LDS ----
    const uint32_t pk = (uint32_t)hn[0] | ((uint32_t)hn[1] << 16);   // (d, d+4)
    const uint32_t y = (uint32_t)__shfl_xor((int)pk, 16);            // partner kq^1
    const uint32_t word = (kq & 1) ? __builtin_amdgcn_perm(pk, y, 0x07060302)
                                   : __builtin_amdgcn_perm(y, pk, 0x05040100);
    Hst[fr][w * 4 + ((kq & 1) ? 2 + (kq >> 1) : (kq >> 1))] = word;
    __syncthreads();

    // ---- wave 0: wide exchange stores (AGENT) + flag + hcat ----
    if (w == 0) {
      const uint4 v = *(const uint4*)&Hst[lane >> 2][(lane & 3) * 4];
      unsigned short* dst = hxown + (size_t)t * 65536 + hxg + s * 512 + lane * 8;
      __hip_atomic_store((unsigned long long*)dst, ((const unsigned long long*)&v)[0],
                         __ATOMIC_RELAXED, __HIP_MEMORY_SCOPE_AGENT);
      __hip_atomic_store((unsigned long long*)(dst + 4), ((const unsigned long long*)&v)[1],
                         __ATOMIC_RELAXED, __HIP_MEMORY_SCOPE_AGENT);
      asm volatile("s_waitcnt vmcnt(0)" ::: "memory");
      if (lane == 0)
        __hip_atomic_store(flown + s, t + 1, __ATOMIC_RELAXED, __HIP_MEMORY_SCOPE_AGENT);
      const int row = (g * 16 + (lane >> 2)) * 64 + t;
      *(uint4*)(hcat + (size_t)row * 1024 + colbase + (lane & 3) * 8) = v;
    }
  }
}

// ================= small helpers =================
struct CastJobs {
  const float* src[15];
  unsigned short* dst[15];
  long nreal[15];
  long cum[16];
  int n;
};

__global__ void cast_multi(CastJobs J) {
  const long total = J.cum[J.n];
  for (long i = (long)blockIdx.x * blockDim.x + threadIdx.x; i < total;
       i += (long)gridDim.x * blockDim.x) {
    int s = 0;
    while (i >= J.cum[s + 1]) ++s;
    const long off = i - J.cum[s];
    J.dst[s][off] = (off < J.nreal[s]) ? f2bf(J.src[s][off]) : (unsigned short)0;
  }
}

// gate-interleaved row permutation of W_ih (+ biases): dst row m = 4d+g <- src row g*512+d
__global__ void perm_wih(const float* __restrict__ W1, const float* __restrict__ W2,
                         const float* __restrict__ b1, const float* __restrict__ b2,
                         unsigned short* __restrict__ R1, unsigned short* __restrict__ R2,
                         float* __restrict__ bp1, float* __restrict__ bp2) {
  const long id = (long)blockIdx.x * blockDim.x + threadIdx.x;
  const long n1 = (long)2048 * 512;
  if (id < n1) {
    const int m = (int)(id >> 9), k = (int)(id & 511);
    R1[id] = f2bf(W1[(size_t)((m & 3) * 512 + (m >> 2)) * 512 + k]);
  } else {
    const long j = id - n1;
    const int m = (int)(j >> 10), k = (int)(j & 1023);
    R2[j] = f2bf(W2[(size_t)((m & 3) * 512 + (m >> 2)) * 1024 + k]);
  }
  if (id < 2048) bp1[id] = b1[(id & 3) * 512 + (id >> 2)];
  else if (id < 4096) { const int m = (int)id - 2048; bp2[m] = b2[(m & 3) * 512 + (m >> 2)]; }
}

// transposed bf16 cast of Wv1/Wv2
__global__ void transp_cast(const float* __restrict__ s1, const float* __restrict__ s2,
                            unsigned short* __restrict__ d1, unsigned short* __restrict__ d2) {
  const int e = blockIdx.x * blockDim.x + threadIdx.x;
  const float* s = (e >> 18) ? s2 : s1;
  unsigned short* d = (e >> 18) ? d2 : d1;
  const int t = e & 262143, a = t >> 9, bb = t & 511;
  d[t] = f2bf(s[bb * 512 + a]);
}

// bc = Wo @ bv + bo
__global__ void bias_comb(const float* __restrict__ Wo1, const float* __restrict__ bv1,
                          const float* __restrict__ bo1,
                          const float* __restrict__ Wo2, const float* __restrict__ bv2,
                          const float* __restrict__ bo2,
                          float* __restrict__ bc1, float* __restrict__ bc2) {
  const int i = threadIdx.x;
  const float* Wo = blockIdx.x ? Wo2 : Wo1;
  const float* bv = blockIdx.x ? bv2 : bv1;
  const float* bo = blockIdx.x ? bo2 : bo1;
  float* bc = blockIdx.x ? bc2 : bc1;
  float s = bo[i];
  for (int k = 0; k < 512; ++k) s += Wo[i * 512 + k] * bv[k];
  bc[i] = s;
}

__global__ void concat_bias(const float* a, const float* b, const float* c, const float* d,
                            float* o) {
  const int i = blockIdx.x * blockDim.x + threadIdx.x;
  const float* s[4] = {a, b, c, d};
  o[i] = s[i >> 9][i & 511];
}

__global__ void gather_rows(const int* __restrict__ ix, const unsigned short* __restrict__ emb,
                            unsigned short* __restrict__ x) {
  const int row = blockIdx.x;
  const int e = ix[row];
  const uint4* s = (const uint4*)(emb + (size_t)e * 512);
  uint4* d = (uint4*)(x + (size_t)row * 512);
  d[threadIdx.x] = s[threadIdx.x];
}

// Weff2 [2048][512] bf16 -> A-frag stream [16 s][16 kk][2 mi][256 tid][8]
__global__ void reorder_wbf(const unsigned short* __restrict__ W,
                            unsigned short* __restrict__ R) {
  const int id = blockIdx.x * blockDim.x + threadIdx.x;  // 131072
  const int tid = id & 255, mi = (id >> 8) & 1, kk = (id >> 9) & 15, s = id >> 13;
  const int w = tid >> 6, lane = tid & 63, fr = lane & 15, kq = lane >> 4;
  const int row = s * 128 + w * 32 + mi * 16 + fr;
  const int col = kk * 32 + kq * 8;
  *((uint4*)R + id) = *(const uint4*)(W + (size_t)row * 512 + col);
}

// blcat[j] = blog[j] + Wl_a1[j,:]·bc1 + Wl_a2[j,:]·bc2   (bf16 Wlog rows)
__global__ void bias_blcat(const unsigned short* __restrict__ Wl, const float* __restrict__ blog,
                           const float* __restrict__ bc1, const float* __restrict__ bc2,
                           float* __restrict__ blcat) {
  const int j = blockIdx.x * 4 + (threadIdx.x >> 6);
  const int lane = threadIdx.x & 63;
  const unsigned short* row = Wl + (size_t)j * 1536;
  float sum = 0.f;
  for (int k = lane; k < 512; k += 64) {
    sum += bf2f(row[512 + k]) * bc1[k];
    sum += bf2f(row[1024 + k]) * bc2[k];
  }
#pragma unroll
  for (int m = 32; m; m >>= 1) sum += __shfl_xor(sum, m, 64);
  if (lane == 0) blcat[j] = blog[j] + sum;
}

// beff2[m] = bp2[m] + Wp2a[m,:]·bc1
__global__ void bias_beff2(const unsigned short* __restrict__ Wp2, const float* __restrict__ bp2,
                           const float* __restrict__ bc1, float* __restrict__ beff2) {
  const int m = blockIdx.x * 4 + (threadIdx.x >> 6);
  const int lane = threadIdx.x & 63;
  const unsigned short* row = Wp2 + (size_t)m * 1024 + 512;
  float sum = 0.f;
  for (int k = lane; k < 512; k += 64) sum += bf2f(row[k]) * bc1[k];
#pragma unroll
  for (int mm = 32; mm; mm >>= 1) sum += __shfl_xor(sum, mm, 64);
  if (lane == 0) beff2[m] = bp2[m] + sum;
}

// ================= host =================
extern "C" void kernel_launch(void* const* d_in, const int* in_sizes, int n_in,
                              void* d_out, int out_size, void* d_ws, size_t ws_size,
                              hipStream_t stream) {
  (void)in_sizes; (void)n_in; (void)out_size; (void)ws_size;
  const float* img    = (const float*)d_in[0];
  const int*   ix     = (const int*)d_in[1];
  const float* emb    = (const float*)d_in[2];
  const float* Wih1f  = (const float*)d_in[3];
  const float* bih1   = (const float*)d_in[4];
  const float* Wic1f  = (const float*)d_in[5];
  const float* bic1   = (const float*)d_in[6];
  const float* Wih2f  = (const float*)d_in[7];
  const float* bih2   = (const float*)d_in[8];
  const float* Wic2f  = (const float*)d_in[9];
  const float* bic2   = (const float*)d_in[10];
  const float* Wihl1  = (const float*)d_in[11];
  const float* Whhl1  = (const float*)d_in[12];
  const float* b1     = (const float*)d_in[13];
  const float* Wihl2  = (const float*)d_in[14];
  const float* Whhl2  = (const float*)d_in[15];
  const float* b2     = (const float*)d_in[16];
  const float* Wv1    = (const float*)d_in[17];
  const float* bv1    = (const float*)d_in[18];
  const float* Wo1    = (const float*)d_in[19];
  const float* bo1    = (const float*)d_in[20];
  const float* Wv2    = (const float*)d_in[21];
  const float* bv2    = (const float*)d_in[22];
  const float* Wo2    = (const float*)d_in[23];
  const float* bo2    = (const float*)d_in[24];
  const float* Wlog   = (const float*)d_in[25];
  const float* blog   = (const float*)d_in[26];
  float* out = (float*)d_out;

  char* p = (char*)d_ws;
  auto al = [&](size_t bytes) { char* r = p; p += (bytes + 255) & ~(size_t)255; return r; };
  unsigned short* emb_b  = (unsigned short*)al((size_t)10000 * 512 * 2);
  unsigned short* Wp1    = (unsigned short*)al((size_t)2048 * 512 * 2);
  unsigned short* Whh1_b = (unsigned short*)al((size_t)2048 * 512 * 2);
  unsigned short* Wp2    = (unsigned short*)al((size_t)2048 * 1024 * 2);
  unsigned short* Whh2_b = (unsigned short*)al((size_t)2048 * 512 * 2);
  unsigned short* WvT1   = (unsigned short*)al((size_t)512 * 512 * 2);
  unsigned short* Wo1_b  = (unsigned short*)al((size_t)512 * 512 * 2);
  unsigned short* WvT2   = (unsigned short*)al((size_t)512 * 512 * 2);
  unsigned short* Wo2_b  = (unsigned short*)al((size_t)512 * 512 * 2);
  unsigned short* Wc1T   = (unsigned short*)al((size_t)512 * 512 * 2);
  unsigned short* Wc2T   = (unsigned short*)al((size_t)512 * 512 * 2);
  unsigned short* Wlog_b = (unsigned short*)al((size_t)10240 * 1536 * 2);
  unsigned short* Wcat   = (unsigned short*)al((size_t)10240 * 1024 * 2);
  unsigned short* Weff2  = (unsigned short*)al((size_t)2048 * 512 * 2);
  unsigned short* Weff2r = (unsigned short*)al((size_t)2048 * 512 * 2);
  unsigned short* Wh1i_b = (unsigned short*)al((size_t)512 * 2048 * 2);
  unsigned short* Wc1i_b = (unsigned short*)al((size_t)512 * 2048 * 2);
  unsigned short* Wh2i_b = (unsigned short*)al((size_t)512 * 2048 * 2);
  unsigned short* Wc2i_b = (unsigned short*)al((size_t)512 * 2048 * 2);
  unsigned short* img_b  = (unsigned short*)al((size_t)128 * 2048 * 2);
  unsigned short* x_b    = (unsigned short*)al((size_t)8192 * 512 * 2);
  float*          xpr    = (float*)al((size_t)8192 * 2048 * 4);
  unsigned short* hcat   = (unsigned short*)al((size_t)8192 * 1024 * 2);
  unsigned short* hx1    = (unsigned short*)al((size_t)64 * 128 * 512 * 2);
  unsigned short* hx2    = (unsigned short*)al((size_t)64 * 128 * 512 * 2);
  unsigned short* h01    = (unsigned short*)al((size_t)128 * 512 * 2);
  unsigned short* h02    = (unsigned short*)al((size_t)128 * 512 * 2);
  float*          c1st   = (float*)al((size_t)128 * 512 * 4);
  float*          c2st   = (float*)al((size_t)128 * 512 * 4);
  float*          bcat   = (float*)al((size_t)2048 * 4);
  float*          bp1    = (float*)al((size_t)2048 * 4);
  float*          bp2    = (float*)al((size_t)2048 * 4);
  float*          bc1    = (float*)al((size_t)512 * 4);
  float*          bc2    = (float*)al((size_t)512 * 4);
  float*          beff2  = (float*)al((size_t)2048 * 4);
  float*          blcat  = (float*)al((size_t)10240 * 4);
  int*            flags  = (int*)al(2048);

  hipMemsetAsync(flags, 0, 2048, stream);

  // ---- casts ----
  CastJobs J = {};
  auto addjob = [&](const float* s, unsigned short* d, long nreal, long ntot) {
    J.src[J.n] = s; J.dst[J.n] = d; J.nreal[J.n] = nreal;
    J.cum[J.n + 1] = J.cum[J.n] + ntot; ++J.n;
  };
  addjob(img,   img_b,  (long)128 * 2048,   (long)128 * 2048);
  addjob(emb,   emb_b,  (long)10000 * 512,  (long)10000 * 512);
  addjob(Whhl1, Whh1_b, (long)2048 * 512,   (long)2048 * 512);
  addjob(Whhl2, Whh2_b, (long)2048 * 512,   (long)2048 * 512);
  addjob(Wo1,   Wo1_b,  (long)512 * 512,    (long)512 * 512);
  addjob(Wo2,   Wo2_b,  (long)512 * 512,    (long)512 * 512);
  addjob(Wih1f, Wh1i_b, (long)512 * 2048,   (long)512 * 2048);
  addjob(Wic1f, Wc1i_b, (long)512 * 2048,   (long)512 * 2048);
  addjob(Wih2f, Wh2i_b, (long)512 * 2048,   (long)512 * 2048);
  addjob(Wic2f, Wc2i_b, (long)512 * 2048,   (long)512 * 2048);
  addjob(Wlog,  Wlog_b, (long)10000 * 1536, (long)10240 * 1536);
  cast_multi<<<2048, 256, 0, stream>>>(J);

  transp_cast<<<2048, 256, 0, stream>>>(Wv1, Wv2, WvT1, WvT2);
  perm_wih<<<12288, 256, 0, stream>>>(Wihl1, Wihl2, b1, b2, Wp1, Wp2, bp1, bp2);
  concat_bias<<<8, 256, 0, stream>>>(bih1, bic1, bih2, bic2, bcat);
  bias_comb<<<2, 512, 0, stream>>>(Wo1, bv1, bo1, Wo2, bv2, bo2, bc1, bc2);

  // ---- WcT = (Wo@Wv)^T ----
  gemm_nt<1><<<dim3(4, 4), 256, 0, stream>>>(
      WvT1, 512, Wo1_b, 512, Wc1T, nullptr, nullptr, nullptr, 512, 0, nullptr, 512, 512);
  gemm_nt<1><<<dim3(4, 4), 256, 0, stream>>>(
      WvT2, 512, Wo2_b, 512, Wc2T, nullptr, nullptr, nullptr, 512, 0, nullptr, 512, 512);

  // ---- Weff2 = Wp2[:, :512] + Wp2[:, 512:] @ WoWv1 ----
  gemm_nt<4><<<dim3(16, 4), 256, 0, stream>>>(
      Wp2 + 512, 1024, Wc1T, 512, Weff2, Wp2, nullptr, nullptr, 512, 1024, nullptr, 512, 512);
  reorder_wbf<<<512, 256, 0, stream>>>(Weff2, Weff2r);
  bias_beff2<<<512, 256, 0, stream>>>(Wp2, bp2, bc1, beff2);

  // ---- Wcat = [ Wl_h2 + Wl_a2@WoWv2 | Wl_a1@WoWv1 ] ----
  gemm_nt<4><<<dim3(80, 4), 256, 0, stream>>>(
      Wlog_b + 1024, 1536, Wc2T, 512, Wcat, Wlog_b, nullptr, nullptr, 1024, 1536,
      nullptr, 512, 512);
  gemm_nt<1><<<dim3(80, 4), 256, 0, stream>>>(
      Wlog_b + 512, 1536, Wc1T, 512, Wcat + 512, nullptr, nullptr, nullptr, 1024, 0,
      nullptr, 512, 512);
  bias_blcat<<<2500, 256, 0, stream>>>(Wlog_b, blog, bc1, bc2, blcat);

  // ---- init states ----
  gemm_nt<3><<<dim3(1, 16), 256, 0, stream>>>(
      img_b, 2048, Wh1i_b, 2048, h01, c1st, h02, c2st, 0, 0, bcat, 2048, 2048);

  // ---- x = emb[captions_ix]; xp1 = Wp1 @ x^T (+bp1) ----
  gather_rows<<<8192, 64, 0, stream>>>(ix, emb_b, x_b);
  gemm_nt<2><<<dim3(16, 64), 256, 0, stream>>>(
      Wp1, 512, x_b, 512, xpr, nullptr, nullptr, nullptr, 0, 0, bp1, 512, 8192);

  // ---- both LSTMs, fused & pipelined ----
  lstm_fused<<<256, 256, 0, stream>>>(
      Whh1_b, Whh2_b, Weff2r, h01, h02, c1st, c2st, xpr, beff2, hx1, hx2, hcat, flags);

  // ---- logits = hcat @ Wcat^T + blcat ----
  gemm256<<<dim3(32, 40), 512, 0, stream>>>(
      hcat, 1024, Wcat, 1024, out, 10000, blcat, 1024, 10000);
}

// Round 10
// 838.332 us; speedup vs baseline: 5.4100x; 1.2614x over previous
//
#include <hip/hip_runtime.h>
#include <stdint.h>

#define DEV __device__ __forceinline__

typedef short bf16x8 __attribute__((ext_vector_type(8)));
typedef float f32x4 __attribute__((ext_vector_type(4)));

DEV unsigned short f2bf(float f) {
  union { float f; uint32_t u; } v; v.f = f;
  return (unsigned short)((v.u + 0x7fffu + ((v.u >> 16) & 1u)) >> 16);
}
DEV float bf2f(unsigned short u) {
  union { uint32_t u; float f; } v; v.u = (uint32_t)u << 16; return v.f;
}

DEV float fsig(float x) { return 1.f / (1.f + __expf(-x)); }
DEV float ftanh(float x) { float e = __expf(2.f * x); return 1.f - 2.f / (e + 1.f); }

DEV void gload16(const void* g, void* lds) {
  __builtin_amdgcn_global_load_lds(
      (const __attribute__((address_space(1))) int*)(uintptr_t)g,
      (__attribute__((address_space(3))) int*)(uintptr_t)lds, 16, 0, 0);
}

// ================= generic NT GEMM: C[M,N] = A[M,K] * B[N,K]^T + bias =================
// 128x128 tile, BK=32, 4 waves each 64x64.
// MODE 1: bf16 C (+optional C2).  MODE 2: xpr layout (gate-interleaved rows, bias/row).
// MODE 3: init states.  MODE 4: bf16 C = product + bf16 addend (P1, ld ldc2).
template <int MODE>
__global__ __launch_bounds__(256) void gemm_nt(
    const unsigned short* __restrict__ A, int lda,
    const unsigned short* __restrict__ B, int ldb,
    void* __restrict__ P0, void* __restrict__ P1,
    void* __restrict__ P2, void* __restrict__ P3,
    int ldc, int ldc2,
    const float* __restrict__ bias,
    int K, int Nreal)
{
  __shared__ alignas(16) unsigned short Asm[128 * 32];
  __shared__ alignas(16) unsigned short Bsm[128 * 32];
  const int tid = threadIdx.x;
  const int wave = tid >> 6, lane = tid & 63;

  const int gx = gridDim.x;
  const int lin = blockIdx.y * gx + blockIdx.x;
  const int nwg = gx * gridDim.y;
  const int q = nwg >> 3, r = nwg & 7;
  const int xcd = lin & 7, i2 = lin >> 3;
  const int wg = (xcd < r ? xcd * (q + 1) : r * (q + 1) + (xcd - r) * q) + i2;
  const int m0 = (wg % gx) * 128, n0 = (wg / gx) * 128;

  const int wr = wave >> 1, wc = wave & 1;
  f32x4 acc[4][4] = {};

  const int q0 = tid, q1 = tid + 256;
  const unsigned short* Ag0 = A + (size_t)(m0 + (q0 >> 2)) * lda + (q0 & 3) * 8;
  const unsigned short* Ag1 = A + (size_t)(m0 + (q1 >> 2)) * lda + (q1 & 3) * 8;
  const unsigned short* Bg0 = B + (size_t)(n0 + (q0 >> 2)) * ldb + (q0 & 3) * 8;
  const unsigned short* Bg1 = B + (size_t)(n0 + (q1 >> 2)) * ldb + (q1 & 3) * 8;
  char* As0 = (char*)Asm + wave * 1024;  char* As1 = As0 + 4096;
  char* Bs0 = (char*)Bsm + wave * 1024;  char* Bs1 = Bs0 + 4096;

  const int ra = wr * 64 + (lane & 15);
  const int rb = wc * 64 + (lane & 15);
  const int kb = (lane >> 4) * 16;

  for (int k0 = 0; k0 < K; k0 += 32) {
    gload16(Ag0 + k0, As0);
    gload16(Ag1 + k0, As1);
    gload16(Bg0 + k0, Bs0);
    gload16(Bg1 + k0, Bs1);
    __syncthreads();
    bf16x8 af[4], bfr[4];
#pragma unroll
    for (int i = 0; i < 4; ++i)
      af[i] = *(const bf16x8*)((const char*)Asm + (ra + i * 16) * 64 + kb);
#pragma unroll
    for (int i = 0; i < 4; ++i)
      bfr[i] = *(const bf16x8*)((const char*)Bsm + (rb + i * 16) * 64 + kb);
#pragma unroll
    for (int mi = 0; mi < 4; ++mi)
#pragma unroll
      for (int ni = 0; ni < 4; ++ni)
        acc[mi][ni] = __builtin_amdgcn_mfma_f32_16x16x32_bf16(af[mi], bfr[ni], acc[mi][ni], 0, 0, 0);
    __syncthreads();
  }

  const int row0 = m0 + wr * 64 + (lane >> 4) * 4;
  const int col0 = n0 + wc * 64 + (lane & 15);

  if constexpr (MODE == 2) {
#pragma unroll
    for (int mi = 0; mi < 4; ++mi) {
      const int rowb = row0 + mi * 16;       // multiple of 4
      const int dd = rowb >> 2;
      const float4 b4 = *(const float4*)&bias[rowb];
#pragma unroll
      for (int ni = 0; ni < 4; ++ni) {
        const int col = col0 + ni * 16;
        const int tt = col & 63, bb = col >> 6;
        float4 v;
        v.x = acc[mi][ni][0] + b4.x;
        v.y = acc[mi][ni][1] + b4.y;
        v.z = acc[mi][ni][2] + b4.z;
        v.w = acc[mi][ni][3] + b4.w;
        const int wgid = (bb >> 4) * 16 + (dd >> 5);
        const int ww = (dd >> 3) & 3, mi2 = (dd >> 2) & 1, ln = (dd & 3) * 16 + (bb & 15);
        ((float4*)P0)[((((size_t)tt * 128 + wgid) * 4 + ww) * 2 + mi2) * 64 + ln] = v;
      }
    }
    return;
  }

#pragma unroll
  for (int mi = 0; mi < 4; ++mi) {
#pragma unroll
    for (int ni = 0; ni < 4; ++ni) {
      const int col = col0 + ni * 16;
      if (col >= Nreal) continue;
      const float bs = bias ? bias[col] : 0.f;
#pragma unroll
      for (int rr = 0; rr < 4; ++rr) {
        const int row = row0 + mi * 16 + rr;
        const float v = acc[mi][ni][rr] + bs;
        if constexpr (MODE == 1) {
          ((unsigned short*)P0)[(size_t)row * ldc + col] = f2bf(v);
          if (P1) ((unsigned short*)P1)[(size_t)row * ldc2 + col] = f2bf(v);
        } else if constexpr (MODE == 4) {
          const unsigned short ad = ((const unsigned short*)P1)[(size_t)row * ldc2 + col];
          ((unsigned short*)P0)[(size_t)row * ldc + col] = f2bf(v + bf2f(ad));
        } else {  // MODE 3
          const int seg = col >> 9, cc = col & 511;
          if (seg == 0)      ((unsigned short*)P0)[(size_t)row * 512 + cc] = f2bf(v);
          else if (seg == 1) ((float*)P1)[(size_t)row * 512 + cc] = v;
          else if (seg == 2) ((unsigned short*)P2)[(size_t)row * 512 + cc] = f2bf(v);
          else               ((float*)P3)[(size_t)row * 512 + cc] = v;
        }
      }
    }
  }
}

// ============ 256x256 tile GEMM, BK=64, counted vmcnt pipeline, NT C-stores ============
__global__ __launch_bounds__(512, 2) void gemm256(
    const unsigned short* __restrict__ A, int lda,
    const unsigned short* __restrict__ B, int ldb,
    float* __restrict__ C, int ldc,
    const float* __restrict__ bias, int K, int Nreal)
{
  __shared__ alignas(16) unsigned short Lds[2][2][16384];
  const int tid = threadIdx.x;
  const int wave = tid >> 6, lane = tid & 63;
  const int fr = lane & 15, kq = lane >> 4;

  const int gx = gridDim.x;
  const int lin = blockIdx.y * gx + blockIdx.x;
  const int nwg = gx * gridDim.y;
  const int q8 = nwg >> 3, r8 = nwg & 7;
  const int xcd = lin & 7, i2 = lin >> 3;
  const int wg = (xcd < r8 ? xcd * (q8 + 1) : r8 * (q8 + 1) + (xcd - r8) * q8) + i2;
  const int m0 = (wg % gx) * 256, n0 = (wg / gx) * 256;

  const int wr = wave >> 2, wc = wave & 3;

  const unsigned short* srcA[4];
  const unsigned short* srcB[4];
  int dstO[4];
#pragma unroll
  for (int s = 0; s < 4; ++s) {
    const int c = tid + s * 512;
    const int row = c >> 3, qp = (c & 7) ^ (row & 7);
    srcA[s] = A + (size_t)(m0 + row) * lda + qp * 8;
    srcB[s] = B + (size_t)(n0 + row) * ldb + qp * 8;
    dstO[s] = (wave * 64 + s * 512) * 16;
  }

  const int NT = K >> 6;
#define STAGE256(kt, buf)                                            \
  {                                                                  \
    _Pragma("unroll")                                                \
    for (int s = 0; s < 4; ++s)                                      \
      gload16(srcA[s] + (kt) * 64, (char*)&Lds[buf][0][0] + dstO[s]);\
    _Pragma("unroll")                                                \
    for (int s = 0; s < 4; ++s)                                      \
      gload16(srcB[s] + (kt) * 64, (char*)&Lds[buf][1][0] + dstO[s]);\
  }
  STAGE256(0, 0);
  STAGE256(1, 1);

  f32x4 acc[8][4] = {};
  const int slot0 = (kq ^ (fr & 7)) * 16;

  for (int kt = 0; kt < NT; ++kt) {
    asm volatile("s_waitcnt vmcnt(8)" ::: "memory");
    __builtin_amdgcn_sched_barrier(0);
    __builtin_amdgcn_s_barrier();
    __builtin_amdgcn_sched_barrier(0);
    const char* bufA = (const char*)&Lds[kt & 1][0][0];
    const char* bufB = (const char*)&Lds[kt & 1][1][0];
    bf16x8 Bf[4][2];
#pragma unroll
    for (int n = 0; n < 4; ++n) {
      const char* bb = bufB + (wc * 64 + n * 16 + fr) * 128;
      Bf[n][0] = *(const bf16x8*)(bb + slot0);
      Bf[n][1] = *(const bf16x8*)(bb + (slot0 ^ 64));
    }
#pragma unroll
    for (int q = 0; q < 4; ++q) {
      bf16x8 Af[2][2];
#pragma unroll
      for (int m2 = 0; m2 < 2; ++m2) {
        const char* ab = bufA + (wr * 128 + q * 32 + m2 * 16 + fr) * 128;
        Af[m2][0] = *(const bf16x8*)(ab + slot0);
        Af[m2][1] = *(const bf16x8*)(ab + (slot0 ^ 64));
      }
      __builtin_amdgcn_s_setprio(1);
#pragma unroll
      for (int m2 = 0; m2 < 2; ++m2)
#pragma unroll
        for (int n = 0; n < 4; ++n) {
          acc[q * 2 + m2][n] = __builtin_amdgcn_mfma_f32_16x16x32_bf16(
              Af[m2][0], Bf[n][0], acc[q * 2 + m2][n], 0, 0, 0);
          acc[q * 2 + m2][n] = __builtin_amdgcn_mfma_f32_16x16x32_bf16(
              Af[m2][1], Bf[n][1], acc[q * 2 + m2][n], 0, 0, 0);
        }
      __builtin_amdgcn_s_setprio(0);
    }
    __builtin_amdgcn_sched_barrier(0);
    __builtin_amdgcn_s_barrier();
    __builtin_amdgcn_sched_barrier(0);
    const int kn = (kt + 2 < NT) ? kt + 2 : 0;
    STAGE256(kn, kt & 1);
  }

#pragma unroll
  for (int mf = 0; mf < 8; ++mf) {
    const int row = m0 + wr * 128 + mf * 16 + kq * 4;
#pragma unroll
    for (int n = 0; n < 4; ++n) {
      const int col = n0 + wc * 64 + n * 16 + fr;
      if (col < Nreal) {
        const float bs = bias[col];
#pragma unroll
        for (int rr = 0; rr < 4; ++rr)
          __builtin_nontemporal_store(acc[mf][n][rr] + bs,
                                      &C[(size_t)(row + rr) * ldc + col]);
      }
    }
  }
#undef STAGE256
}

// ================= fused persistent LSTM1+LSTM2 (256 WGs, 1/CU) =================
// R8-proven AGENT-scope LLC exchange (R9's cached-L2 variant deadlocked -- co-location
// cannot be assumed). Change vs R8: role2 computes phase B (Weff2@h1(t), available
// early since role1 runs ahead) BEFORE polling for h2(t-1) -- the own-cohort flag
// wait and h2 fetch overlap the weight stream instead of serializing after it.
// hx layout: [t][g(8)][slice s(16)][b_local(16)][32 d] bf16.
__global__ __launch_bounds__(256, 1) void lstm_fused(
    const unsigned short* __restrict__ Whh1, const unsigned short* __restrict__ Whh2,
    const unsigned short* __restrict__ Weff2r,  // [16 s][16 kk][2 mi][256 tid][8] bf16
    const unsigned short* __restrict__ h01, const unsigned short* __restrict__ h02,
    const float* __restrict__ c1st, const float* __restrict__ c2st,
    const float* __restrict__ xpr,              // [64][128][4][2][64][4] f32
    const float* __restrict__ beff2,            // [2048] gate-interleaved
    unsigned short* __restrict__ hx1, unsigned short* __restrict__ hx2,
    unsigned short* __restrict__ hcat,          // [8192][1024]: [h2s | h1s]
    int* __restrict__ flags)                    // [2][8][16] ints
{
  __shared__ unsigned short Wsm[8][128][64];
  __shared__ uint32_t Hst[16][16];              // packed h staging (1KB)
  const int tid = threadIdx.x;
  const bool role2 = blockIdx.x >= 128;
  const int wg = role2 ? blockIdx.x - 128 : blockIdx.x;
  const int g = wg >> 4, s = wg & 15;
  const int w = tid >> 6, lane = tid & 63, fr = lane & 15, kq = lane >> 4;

  // ---- stage Whh slice into LDS (slot = chunk ^ (m&7)) ----
  {
    const unsigned short* Whh = role2 ? Whh2 : Whh1;
    const int m = tid >> 1;
    const int row = (m & 3) * 512 + s * 32 + (m >> 2);
    const unsigned short* src = Whh + (size_t)row * 512 + (tid & 1) * 256;
#pragma unroll 4
    for (int cc = 0; cc < 32; ++cc) {
      const int k = (tid & 1) * 256 + cc * 8;
      uint4 v = *(const uint4*)(src + cc * 8);
      const int kblk = k >> 6, c = (k & 63) >> 3, sl = c ^ (m & 7);
      *(uint4*)((char*)&Wsm[kblk][m][0] + sl * 16) = v;
    }
  }

  const int b = g * 16 + fr;
  const int d0 = s * 32 + w * 8 + kq;
  const float* c0 = role2 ? c2st : c1st;
  float c_r[2];
  c_r[0] = c0[b * 512 + d0];
  c_r[1] = c0[b * 512 + d0 + 4];
  __syncthreads();

  int* fl1 = flags + g * 16;
  int* fl2 = flags + 128 + g * 16;
  int* flown = role2 ? fl2 : fl1;
  unsigned short* hxown = role2 ? hx2 : hx1;
  const unsigned short* hinit = role2 ? h02 : h01;
  const int colbase = (role2 ? 0 : 512) + s * 32;
  const float4* xv = (const float4*)xpr + ((size_t)(wg * 4 + w) * 2) * 64 + lane;
  float4 be0 = {0, 0, 0, 0}, be1 = {0, 0, 0, 0};
  if (role2) {
    be0 = *(const float4*)(beff2 + s * 128 + w * 32 + kq * 4);
    be1 = *(const float4*)(beff2 + s * 128 + w * 32 + 16 + kq * 4);
  }
  const size_t hxg = (size_t)g * 8192;           // per-t region offset for group

  for (int t = 0; t < 64; ++t) {
    f32x4 acc[2] = {};
    float4 xg0, xg1;

    if (!role2) {
      xg0 = xv[(size_t)t * 65536];               // HBM prefetch before poll
      xg1 = xv[(size_t)t * 65536 + 64];
      // ---- poll: own group's h1(t-1) posted ----
      if (t) {
        if (w == 1) {
          for (;;) {
            bool ok = true;
            if (lane < 16)
              ok = __hip_atomic_load(fl1 + lane, __ATOMIC_RELAXED,
                                     __HIP_MEMORY_SCOPE_AGENT) >= t;
            if (__all(ok)) break;
            __builtin_amdgcn_s_sleep(1);
          }
        }
        __syncthreads();
      }
      // ---- own-h fragments ----
      bf16x8 hf[16];
      if (t == 0) {
#pragma unroll
        for (int kk = 0; kk < 16; ++kk)
          hf[kk] = *(const bf16x8*)(hinit + (size_t)b * 512 + kk * 32 + kq * 8);
      } else {
        const unsigned short* hb = hx1 + (size_t)(t - 1) * 65536 + hxg + fr * 32 + kq * 8;
#pragma unroll
        for (int kk = 0; kk < 16; ++kk)
          hf[kk] = *(const bf16x8*)(hb + kk * 512);
      }
      // ---- phase A: Whh1 @ h1 (LDS) ----
#pragma unroll
      for (int kk = 0; kk < 16; ++kk) {
        const int kblk = kk >> 1, cbase = (kk & 1) * 4 + kq;
#pragma unroll
        for (int mi = 0; mi < 2; ++mi) {
          const int m = w * 32 + mi * 16 + fr;
          const int sl = cbase ^ (m & 7);
          const bf16x8 af = *(const bf16x8*)((const char*)&Wsm[kblk][m][0] + sl * 16);
          acc[mi] = __builtin_amdgcn_mfma_f32_16x16x32_bf16(af, hf[kk], acc[mi], 0, 0, 0);
        }
      }
    } else {
      xg0 = be0; xg1 = be1;
      // ---- poll: h1(t) posted (role1 runs ahead -> usually instant) ----
      if (w == 1) {
        for (;;) {
          bool ok = true;
          if (lane < 16)
            ok = __hip_atomic_load(fl1 + lane, __ATOMIC_RELAXED,
                                   __HIP_MEMORY_SCOPE_AGENT) >= t + 1;
          if (__all(ok)) break;
          __builtin_amdgcn_s_sleep(1);
        }
      }
      __syncthreads();
      // ---- phase B FIRST: Weff2 @ h1(t) (overlaps h2 flag wait + fetch) ----
      {
        const unsigned short* h1b = hx1 + (size_t)t * 65536 + hxg + fr * 32 + kq * 8;
        bf16x8 hf1[16];
#pragma unroll
        for (int kk = 0; kk < 16; ++kk)
          hf1[kk] = *(const bf16x8*)(h1b + kk * 512);
        const bf16x8* wr = (const bf16x8*)Weff2r + (size_t)s * 32 * 256 + tid;
#pragma unroll
        for (int kk = 0; kk < 16; ++kk) {
#pragma unroll
          for (int mi = 0; mi < 2; ++mi) {
            const bf16x8 af = wr[(kk * 2 + mi) * 256];
            acc[mi] = __builtin_amdgcn_mfma_f32_16x16x32_bf16(af, hf1[kk], acc[mi], 0, 0, 0);
          }
        }
      }
      // ---- poll: own group's h2(t-1) posted ----
      if (t) {
        if (w == 1) {
          for (;;) {
            bool ok = true;
            if (lane < 16)
              ok = __hip_atomic_load(fl2 + lane, __ATOMIC_RELAXED,
                                     __HIP_MEMORY_SCOPE_AGENT) >= t;
            if (__all(ok)) break;
            __builtin_amdgcn_s_sleep(1);
          }
        }
        __syncthreads();
      }
      bf16x8 hf[16];
      if (t == 0) {
#pragma unroll
        for (int kk = 0; kk < 16; ++kk)
          hf[kk] = *(const bf16x8*)(hinit + (size_t)b * 512 + kk * 32 + kq * 8);
      } else {
        const unsigned short* hb = hx2 + (size_t)(t - 1) * 65536 + hxg + fr * 32 + kq * 8;
#pragma unroll
        for (int kk = 0; kk < 16; ++kk)
          hf[kk] = *(const bf16x8*)(hb + kk * 512);
      }
      // ---- phase A: Whh2 @ h2 (LDS), accumulate ----
#pragma unroll
      for (int kk = 0; kk < 16; ++kk) {
        const int kblk = kk >> 1, cbase = (kk & 1) * 4 + kq;
#pragma unroll
        for (int mi = 0; mi < 2; ++mi) {
          const int m = w * 32 + mi * 16 + fr;
          const int sl = cbase ^ (m & 7);
          const bf16x8 af = *(const bf16x8*)((const char*)&Wsm[kblk][m][0] + sl * 16);
          acc[mi] = __builtin_amdgcn_mfma_f32_16x16x32_bf16(af, hf[kk], acc[mi], 0, 0, 0);
        }
      }
    }

    // ---- gates (lane-local) ----
    unsigned short hn[2];
#pragma unroll
    for (int mi = 0; mi < 2; ++mi) {
      const float4 xg = mi ? xg1 : xg0;
      const float iv = acc[mi][0] + xg.x;
      const float fv = acc[mi][1] + xg.y;
      const float gv = acc[mi][2] + xg.z;
      const float ov = acc[mi][3] + xg.w;
      const float c = fsig(fv) * c_r[mi] + fsig(iv) * ftanh(gv);
      c_r[mi] = c;
      hn[mi] = f2bf(fsig(ov) * ftanh(c));
    }

    // ---- pack to d-linear order: shfl + perm, stage in LDS ----
    const uint32_t pk = (uint32_t)hn[0] | ((uint32_t)hn[1] << 16);   // (d, d+4)
    const uint32_t y = (uint32_t)__shfl_xor((int)pk, 16);            // partner kq^1
    const uint32_t word = (kq & 1) ? __builtin_amdgcn_perm(pk, y, 0x07060302)
                                   : __builtin_amdgcn_perm(y, pk, 0x05040100);
    Hst[fr][w * 4 + ((kq & 1) ? 2 + (kq >> 1) : (kq >> 1))] = word;
    __syncthreads();

    // ---- wave 0: wide exchange stores (AGENT) + flag + hcat ----
    if (w == 0) {
      const uint4 v = *(const uint4*)&Hst[lane >> 2][(lane & 3) * 4];
      unsigned short* dst = hxown + (size_t)t * 65536 + hxg + s * 512 + lane * 8;
      __hip_atomic_store((unsigned long long*)dst, ((const unsigned long long*)&v)[0],
                         __ATOMIC_RELAXED, __HIP_MEMORY_SCOPE_AGENT);
      __hip_atomic_store((unsigned long long*)(dst + 4), ((const unsigned long long*)&v)[1],
                         __ATOMIC_RELAXED, __HIP_MEMORY_SCOPE_AGENT);
      asm volatile("s_waitcnt vmcnt(0)" ::: "memory");
      if (lane == 0)
        __hip_atomic_store(flown + s, t + 1, __ATOMIC_RELAXED, __HIP_MEMORY_SCOPE_AGENT);
      const int row = (g * 16 + (lane >> 2)) * 64 + t;
      *(uint4*)(hcat + (size_t)row * 1024 + colbase + (lane & 3) * 8) = v;
    }
  }
}

// ================= fused prep =================
struct CastJobs {
  const float* src[12];
  unsigned short* dst[12];
  long nreal4[12];   // 4-elem units
  long cum4[13];     // 4-elem units
  int n;
};

__global__ void cast_multi4(CastJobs J) {
  const long total = J.cum4[J.n];
  for (long i = (long)blockIdx.x * blockDim.x + threadIdx.x; i < total;
       i += (long)gridDim.x * blockDim.x) {
    int s = 0;
    while (i >= J.cum4[s + 1]) ++s;
    const long off = i - J.cum4[s];
    float4 v = {0.f, 0.f, 0.f, 0.f};
    if (off < J.nreal4[s]) v = ((const float4*)J.src[s])[off];
    ushort4 o;
    o.x = f2bf(v.x); o.y = f2bf(v.y); o.z = f2bf(v.z); o.w = f2bf(v.w);
    ((ushort4*)J.dst[s])[off] = o;
  }
}

// Fused small prep: perm_wih (vec8) + transp_cast + bias perms + concat + bias_comb.
__global__ void prep1(const float* __restrict__ Wv1, const float* __restrict__ Wv2,
                      const float* __restrict__ Wihl1, const float* __restrict__ Wihl2,
                      const float* __restrict__ b1, const float* __restrict__ b2,
                      const float* __restrict__ bih1, const float* __restrict__ bic1,
                      const float* __restrict__ bih2, const float* __restrict__ bic2,
                      const float* __restrict__ Wo1, const float* __restrict__ bv1,
                      const float* __restrict__ bo1,
                      const float* __restrict__ Wo2, const float* __restrict__ bv2,
                      const float* __restrict__ bo2,
                      unsigned short* __restrict__ WvT1, unsigned short* __restrict__ WvT2,
                      unsigned short* __restrict__ Wp1, unsigned short* __restrict__ Wp2,
                      float* __restrict__ bp1, float* __restrict__ bp2,
                      float* __restrict__ bcat,
                      float* __restrict__ bc1, float* __restrict__ bc2)
{
  const long NTOT = 924672;
  for (long id = (long)blockIdx.x * blockDim.x + threadIdx.x; id < NTOT;
       id += (long)gridDim.x * blockDim.x) {
    if (id < 131072) {              // perm W_ih1 by-8
      const int m = (int)(id >> 6), kb = (int)(id & 63) * 8;
      const float* sp = Wihl1 + (size_t)((m & 3) * 512 + (m >> 2)) * 512 + kb;
      unsigned short o[8];
#pragma unroll
      for (int e = 0; e < 8; ++e) o[e] = f2bf(sp[e]);
      *(uint4*)(Wp1 + (size_t)m * 512 + kb) = *(const uint4*)o;
    } else if (id < 393216) {       // perm W_ih2 by-8
      const long j = id - 131072;
      const int m = (int)(j >> 7), kb = (int)(j & 127) * 8;
      const float* sp = Wihl2 + (size_t)((m & 3) * 512 + (m >> 2)) * 1024 + kb;
      unsigned short o[8];
#pragma unroll
      for (int e = 0; e < 8; ++e) o[e] = f2bf(sp[e]);
      *(uint4*)(Wp2 + (size_t)m * 1024 + kb) = *(const uint4*)o;
    } else if (id < 917504) {       // transposed cast of Wv1/Wv2
      const long t = id - 393216;
      const int which = (int)(t >> 18);
      const int u = (int)(t & 262143), a = u >> 9, bb = u & 511;
      (which ? WvT2 : WvT1)[u] = f2bf((which ? Wv2 : Wv1)[(size_t)bb * 512 + a]);
    } else if (id < 921600) {       // bias perms
      const int t = (int)(id - 917504);
      if (t < 2048) bp1[t] = b1[(t & 3) * 512 + (t >> 2)];
      else { const int m = t - 2048; bp2[m] = b2[(m & 3) * 512 + (m >> 2)]; }
    } else if (id < 923648) {       // bcat concat
      const int i = (int)(id - 921600);
      const float* sarr[4] = {bih1, bic1, bih2, bic2};
      bcat[i] = sarr[i >> 9][i & 511];
    } else {                        // bc = Wo @ bv + bo (1024 rows)
      const int i = (int)(id - 923648);
      const float* Wo = (i >= 512) ? Wo2 : Wo1;
      const float* bv = (i >= 512) ? bv2 : bv1;
      const float* bo = (i >= 512) ? bo2 : bo1;
      float* bc = (i >= 512) ? bc2 : bc1;
      const int r = i & 511;
      float sacc = bo[r];
      for (int k = 0; k < 512; k += 4) {
        const float4 wv = *(const float4*)(Wo + (size_t)r * 512 + k);
        const float4 bb = *(const float4*)(bv + k);
        sacc += wv.x * bb.x + wv.y * bb.y + wv.z * bb.z + wv.w * bb.w;
      }
      bc[r] = sacc;
    }
  }
}

// gather + on-the-fly cast: x[row] = bf16(emb_f32[ix[row]])
__global__ void gather_rows(const int* __restrict__ ix, const float* __restrict__ emb,
                            unsigned short* __restrict__ x) {
  const int row = blockIdx.x;
  const int e = ix[row];
  const float4* s = (const float4*)(emb + (size_t)e * 512) + threadIdx.x * 2;
  const float4 a = s[0], b = s[1];
  unsigned short o[8] = {f2bf(a.x), f2bf(a.y), f2bf(a.z), f2bf(a.w),
                         f2bf(b.x), f2bf(b.y), f2bf(b.z), f2bf(b.w)};
  *(uint4*)(x + (size_t)row * 512 + threadIdx.x * 8) = *(const uint4*)o;
}

// Weff2 [2048][512] bf16 -> A-frag stream [16 s][16 kk][2 mi][256 tid][8]
__global__ void reorder_wbf(const unsigned short* __restrict__ W,
                            unsigned short* __restrict__ R) {
  const int id = blockIdx.x * blockDim.x + threadIdx.x;  // 131072
  const int tid = id & 255, mi = (id >> 8) & 1, kk = (id >> 9) & 15, s = id >> 13;
  const int w = tid >> 6, lane = tid & 63, fr = lane & 15, kq = lane >> 4;
  const int row = s * 128 + w * 32 + mi * 16 + fr;
  const int col = kk * 32 + kq * 8;
  *((uint4*)R + id) = *(const uint4*)(W + (size_t)row * 512 + col);
}

// Fused: beff2 (blocks [0,512)) + blcat (blocks [512,3012))
__global__ void bias2(const unsigned short* __restrict__ Wl, const float* __restrict__ blog,
                      const unsigned short* __restrict__ Wp2, const float* __restrict__ bp2,
                      const float* __restrict__ bc1, const float* __restrict__ bc2,
                      float* __restrict__ blcat, float* __restrict__ beff2) {
  const int lane = threadIdx.x & 63;
  if (blockIdx.x < 512) {
    const int m = blockIdx.x * 4 + (threadIdx.x >> 6);
    const unsigned short* row = Wp2 + (size_t)m * 1024 + 512;
    float sum = 0.f;
    for (int k = lane; k < 512; k += 64) sum += bf2f(row[k]) * bc1[k];
#pragma unroll
    for (int mm = 32; mm; mm >>= 1) sum += __shfl_xor(sum, mm, 64);
    if (lane == 0) beff2[m] = bp2[m] + sum;
  } else {
    const int j = (blockIdx.x - 512) * 4 + (threadIdx.x >> 6);
    const unsigned short* row = Wl + (size_t)j * 1536;
    float sum = 0.f;
    for (int k = lane; k < 512; k += 64) {
      sum += bf2f(row[512 + k]) * bc1[k];
      sum += bf2f(row[1024 + k]) * bc2[k];
    }
#pragma unroll
    for (int mm = 32; mm; mm >>= 1) sum += __shfl_xor(sum, mm, 64);
    if (lane == 0) blcat[j] = blog[j] + sum;
  }
}

// ================= host =================
extern "C" void kernel_launch(void* const* d_in, const int* in_sizes, int n_in,
                              void* d_out, int out_size, void* d_ws, size_t ws_size,
                              hipStream_t stream) {
  (void)in_sizes; (void)n_in; (void)out_size; (void)ws_size;
  const float* img    = (const float*)d_in[0];
  const int*   ix     = (const int*)d_in[1];
  const float* emb    = (const float*)d_in[2];
  const float* Wih1f  = (const float*)d_in[3];
  const float* bih1   = (const float*)d_in[4];
  const float* Wic1f  = (const float*)d_in[5];
  const float* bic1   = (const float*)d_in[6];
  const float* Wih2f  = (const float*)d_in[7];
  const float* bih2   = (const float*)d_in[8];
  const float* Wic2f  = (const float*)d_in[9];
  const float* bic2   = (const float*)d_in[10];
  const float* Wihl1  = (const float*)d_in[11];
  const float* Whhl1  = (const float*)d_in[12];
  const float* b1     = (const float*)d_in[13];
  const float* Wihl2  = (const float*)d_in[14];
  const float* Whhl2  = (const float*)d_in[15];
  const float* b2     = (const float*)d_in[16];
  const float* Wv1    = (const float*)d_in[17];
  const float* bv1    = (const float*)d_in[18];
  const float* Wo1    = (const float*)d_in[19];
  const float* bo1    = (const float*)d_in[20];
  const float* Wv2    = (const float*)d_in[21];
  const float* bv2    = (const float*)d_in[22];
  const float* Wo2    = (const float*)d_in[23];
  const float* bo2    = (const float*)d_in[24];
  const float* Wlog   = (const float*)d_in[25];
  const float* blog   = (const float*)d_in[26];
  float* out = (float*)d_out;

  char* p = (char*)d_ws;
  auto al = [&](size_t bytes) { char* r = p; p += (bytes + 255) & ~(size_t)255; return r; };
  unsigned short* Wp1    = (unsigned short*)al((size_t)2048 * 512 * 2);
  unsigned short* Whh1_b = (unsigned short*)al((size_t)2048 * 512 * 2);
  unsigned short* Wp2    = (unsigned short*)al((size_t)2048 * 1024 * 2);
  unsigned short* Whh2_b = (unsigned short*)al((size_t)2048 * 512 * 2);
  unsigned short* WvT1   = (unsigned short*)al((size_t)512 * 512 * 2);
  unsigned short* Wo1_b  = (unsigned short*)al((size_t)512 * 512 * 2);
  unsigned short* WvT2   = (unsigned short*)al((size_t)512 * 512 * 2);
  unsigned short* Wo2_b  = (unsigned short*)al((size_t)512 * 512 * 2);
  unsigned short* Wc1T   = (unsigned short*)al((size_t)512 * 512 * 2);
  unsigned short* Wc2T   = (unsigned short*)al((size_t)512 * 512 * 2);
  unsigned short* Wlog_b = (unsigned short*)al((size_t)10240 * 1536 * 2);
  unsigned short* Wcat   = (unsigned short*)al((size_t)10240 * 1024 * 2);
  unsigned short* Weff2  = (unsigned short*)al((size_t)2048 * 512 * 2);
  unsigned short* Weff2r = (unsigned short*)al((size_t)2048 * 512 * 2);
  unsigned short* Wh1i_b = (unsigned short*)al((size_t)512 * 2048 * 2);
  unsigned short* Wc1i_b = (unsigned short*)al((size_t)512 * 2048 * 2);
  unsigned short* Wh2i_b = (unsigned short*)al((size_t)512 * 2048 * 2);
  unsigned short* Wc2i_b = (unsigned short*)al((size_t)512 * 2048 * 2);
  unsigned short* img_b  = (unsigned short*)al((size_t)128 * 2048 * 2);
  unsigned short* x_b    = (unsigned short*)al((size_t)8192 * 512 * 2);
  float*          xpr    = (float*)al((size_t)8192 * 2048 * 4);
  unsigned short* hcat   = (unsigned short*)al((size_t)8192 * 1024 * 2);
  unsigned short* hx1    = (unsigned short*)al((size_t)64 * 128 * 512 * 2);
  unsigned short* hx2    = (unsigned short*)al((size_t)64 * 128 * 512 * 2);
  unsigned short* h01    = (unsigned short*)al((size_t)128 * 512 * 2);
  unsigned short* h02    = (unsigned short*)al((size_t)128 * 512 * 2);
  float*          c1st   = (float*)al((size_t)128 * 512 * 4);
  float*          c2st   = (float*)al((size_t)128 * 512 * 4);
  float*          bcat   = (float*)al((size_t)2048 * 4);
  float*          bp1    = (float*)al((size_t)2048 * 4);
  float*          bp2    = (float*)al((size_t)2048 * 4);
  float*          bc1    = (float*)al((size_t)512 * 4);
  float*          bc2    = (float*)al((size_t)512 * 4);
  float*          beff2  = (float*)al((size_t)2048 * 4);
  float*          blcat  = (float*)al((size_t)10240 * 4);
  int*            flags  = (int*)al(2048);

  hipMemsetAsync(flags, 0, 2048, stream);

  // ---- casts (vec4; emb handled by gather_rows) ----
  CastJobs J = {};
  auto addjob = [&](const float* s, unsigned short* d, long nreal, long ntot) {
    J.src[J.n] = s; J.dst[J.n] = d; J.nreal4[J.n] = nreal / 4;
    J.cum4[J.n + 1] = J.cum4[J.n] + ntot / 4; ++J.n;
  };
  addjob(img,   img_b,  (long)128 * 2048,   (long)128 * 2048);
  addjob(Whhl1, Whh1_b, (long)2048 * 512,   (long)2048 * 512);
  addjob(Whhl2, Whh2_b, (long)2048 * 512,   (long)2048 * 512);
  addjob(Wo1,   Wo1_b,  (long)512 * 512,    (long)512 * 512);
  addjob(Wo2,   Wo2_b,  (long)512 * 512,    (long)512 * 512);
  addjob(Wih1f, Wh1i_b, (long)512 * 2048,   (long)512 * 2048);
  addjob(Wic1f, Wc1i_b, (long)512 * 2048,   (long)512 * 2048);
  addjob(Wih2f, Wh2i_b, (long)512 * 2048,   (long)512 * 2048);
  addjob(Wic2f, Wc2i_b, (long)512 * 2048,   (long)512 * 2048);
  addjob(Wlog,  Wlog_b, (long)10000 * 1536, (long)10240 * 1536);
  cast_multi4<<<2048, 256, 0, stream>>>(J);

  prep1<<<1024, 256, 0, stream>>>(Wv1, Wv2, Wihl1, Wihl2, b1, b2,
                                  bih1, bic1, bih2, bic2,
                                  Wo1, bv1, bo1, Wo2, bv2, bo2,
                                  WvT1, WvT2, Wp1, Wp2, bp1, bp2, bcat, bc1, bc2);

  gather_rows<<<8192, 64, 0, stream>>>(ix, emb, x_b);

  // ---- WcT = (Wo@Wv)^T ----
  gemm_nt<1><<<dim3(4, 4), 256, 0, stream>>>(
      WvT1, 512, Wo1_b, 512, Wc1T, nullptr, nullptr, nullptr, 512, 0, nullptr, 512, 512);
  gemm_nt<1><<<dim3(4, 4), 256, 0, stream>>>(
      WvT2, 512, Wo2_b, 512, Wc2T, nullptr, nullptr, nullptr, 512, 0, nullptr, 512, 512);

  // ---- Weff2 = Wp2[:, :512] + Wp2[:, 512:] @ WoWv1 ----
  gemm_nt<4><<<dim3(16, 4), 256, 0, stream>>>(
      Wp2 + 512, 1024, Wc1T, 512, Weff2, Wp2, nullptr, nullptr, 512, 1024, nullptr, 512, 512);
  reorder_wbf<<<512, 256, 0, stream>>>(Weff2, Weff2r);
  bias2<<<3012, 256, 0, stream>>>(Wlog_b, blog, Wp2, bp2, bc1, bc2, blcat, beff2);

  // ---- Wcat = [ Wl_h2 + Wl_a2@WoWv2 | Wl_a1@WoWv1 ] ----
  gemm_nt<4><<<dim3(80, 4), 256, 0, stream>>>(
      Wlog_b + 1024, 1536, Wc2T, 512, Wcat, Wlog_b, nullptr, nullptr, 1024, 1536,
      nullptr, 512, 512);
  gemm_nt<1><<<dim3(80, 4), 256, 0, stream>>>(
      Wlog_b + 512, 1536, Wc1T, 512, Wcat + 512, nullptr, nullptr, nullptr, 1024, 0,
      nullptr, 512, 512);

  // ---- init states ----
  gemm_nt<3><<<dim3(1, 16), 256, 0, stream>>>(
      img_b, 2048, Wh1i_b, 2048, h01, c1st, h02, c2st, 0, 0, bcat, 2048, 2048);

  // ---- xp1 = Wp1 @ x^T (+bp1) ----
  gemm_nt<2><<<dim3(16, 64), 256, 0, stream>>>(
      Wp1, 512, x_b, 512, xpr, nullptr, nullptr, nullptr, 0, 0, bp1, 512, 8192);

  // ---- both LSTMs, fused & pipelined (proven AGENT-scope LLC exchange) ----
  lstm_fused<<<256, 256, 0, stream>>>(
      Whh1_b, Whh2_b, Weff2r, h01, h02, c1st, c2st, xpr, beff2, hx1, hx2, hcat, flags);

  // ---- logits = hcat @ Wcat^T + blcat ----
  gemm256<<<dim3(32, 40), 512, 0, stream>>>(
      hcat, 1024, Wcat, 1024, out, 10000, blcat, 1024, 10000);
}